// Round 7
// baseline (401.713 us; speedup 1.0000x reference)
//
#include <hip/hip_runtime.h>
#include <math.h>

#define NN 100000
#define NE 1000000
#define H 64
#define EB 128        // edges per msg block
#define MBT 256       // msg block threads (4 waves; each wave does 32 edges)
#define MSTRIDE 130   // ushorts per channel row in msg LDS (128 edges + 2 pad)
#define NSH 8         // atomic shards for rank (line-contention probe, round 6)

typedef _Float16 f16x8 __attribute__((ext_vector_type(8)));
typedef _Float16 f16x2 __attribute__((ext_vector_type(2)));
typedef float f32x4  __attribute__((ext_vector_type(4)));

static __device__ __forceinline__ float relu_(float x){ return fmaxf(x, 0.0f); }

static __device__ __forceinline__ unsigned short f2h_(float f){
  union { _Float16 h; unsigned short u; } x; x.h = (_Float16)f; return x.u;
}
static __device__ __forceinline__ float h2f_(unsigned short u){
  union { unsigned short u; _Float16 h; } x; x.u = u; return (float)x.h;
}
static __device__ __forceinline__ unsigned int pkh_(float lo, float hi){
  union { f16x2 v; unsigned int u; } x;
  x.v[0] = (_Float16)lo; x.v[1] = (_Float16)hi;
  return x.u;
}
// packed fp16: relu(a + b) on 2 lanes (lowers to v_pk_add_f16 + v_pk_max_f16)
static __device__ __forceinline__ unsigned int addrelu2_(unsigned int a, unsigned int b){
  union { unsigned int u; f16x2 v; } x, y, r;
  x.u = a; y.u = b;
  f16x2 s = x.v + y.v;
  _Float16 z = (_Float16)0.0f;
  r.v[0] = (s[0] > z) ? s[0] : z;
  r.v[1] = (s[1] > z) ? s[1] : z;
  return r.u;
}
// packed fp16 multiply by broadcast scale (v_pk_mul_f16)
static __device__ __forceinline__ unsigned int mulpk_(unsigned int a, f16x2 s){
  union { unsigned int u; f16x2 v; } x;
  x.u = a; x.v = x.v * s;
  return x.u;
}
static __device__ __forceinline__ void fma32(float* o, float a, const float* wr){
  #pragma unroll
  for (int j=0;j<32;j++) o[j] = fmaf(a, wr[j], o[j]);
}

// ---------------- fused encoder: hbf(fp16) = relu(relu(x@w1+b1)@w2+b2) ----------------
// Round 0 fix: hidden t[64] with runtime index -> scratch (51 MB traffic). Now the
// hidden unit t_k is recomputed inline per k (5 FMAs) and o[64] is static-indexed.
__global__ __launch_bounds__(256, 2) void enc_full_kernel(
    const float* __restrict__ x,
    const float* __restrict__ w1, const float* __restrict__ b1,
    const float* __restrict__ w2, const float* __restrict__ b2,
    unsigned short* __restrict__ hbf)
{
  int v = blockIdx.x*256 + threadIdx.x;
  if (v >= NN) return;
  float in0[5];
  #pragma unroll
  for (int k=0;k<5;k++) in0[k] = x[(size_t)v*5 + k];
  float o[64];
  #pragma unroll
  for (int j=0;j<64;j++) o[j] = b2[j];
  #pragma unroll 4
  for (int k=0;k<64;k++){
    float tk = b1[k];
    #pragma unroll
    for (int kk=0;kk<5;kk++) tk = fmaf(in0[kk], w1[kk*H + k], tk);
    tk = relu_(tk);
    const float* wr = w2 + k*H;
    #pragma unroll
    for (int j=0;j<64;j++) o[j] = fmaf(tk, wr[j], o[j]);
  }
  unsigned int u[32];
  #pragma unroll
  for (int j=0;j<32;j++) u[j] = pkh_(relu_(o[2*j]), relu_(o[2*j+1]));
  uint4* dp = (uint4*)(hbf + (size_t)v*H);
  #pragma unroll
  for (int j=0;j<8;j++) dp[j] = *(uint4*)&u[4*j];
}

// ---------------- sharded in-degree counts + per-edge shard-rank ----------------
// Round-6 experiment: rank is invariant at 43us across 2x occupancy change =>
// throughput wall. Hypothesis: cache-line contention (1M atomics over 6250 lines
// of counts[], ~160 serialized ops/line). Shard counts 8 ways by blockIdx&7 ->
// ~20 ops/line. Same atomic count; if dur collapses, (a) confirmed.
// Block b covers edges [b*1024, (b+1)*1024) -> fill recomputes sh = (e>>10)&7.
__global__ __launch_bounds__(256) void rank_kernel(const int* __restrict__ dst,
                                                   int* __restrict__ counts8,
                                                   int* __restrict__ rank)
{
  int t = blockIdx.x*256 + threadIdx.x;
  int e0 = t*4;
  int* cs = counts8 + (size_t)(blockIdx.x & (NSH-1))*NN;
  if (e0 + 3 < NE){
    int4 d4 = *(const int4*)(dst + e0);
    int r0 = atomicAdd(&cs[d4.x], 1);
    int r1 = atomicAdd(&cs[d4.y], 1);
    int r2 = atomicAdd(&cs[d4.z], 1);
    int r3 = atomicAdd(&cs[d4.w], 1);
    *(int4*)(rank + e0) = make_int4(r0, r1, r2, r3);
  } else {
    for (int e = e0; e < NE; ++e) rank[e] = atomicAdd(&cs[dst[e]], 1);
  }
}

// ---------------- scan phase 1: shuffle-based; sums 8 shard copies ----------------
// Writes per-node total (counts, for degree denominator), per-(shard,node)
// exclusive prefix (pfx, for fill), intra-block node scan (row_excl), block sum.
__global__ __launch_bounds__(1024) void scan1_kernel(const int* __restrict__ counts8,
                                                     int* __restrict__ counts,
                                                     int* __restrict__ pfx,
                                                     int* __restrict__ row_excl,
                                                     int* __restrict__ part)
{
  __shared__ int wsum[16];
  int tid = threadIdx.x;
  int i = blockIdx.x*1024 + tid;
  int v = 0;
  if (i < NN){
    int run = 0;
    #pragma unroll
    for (int sh=0; sh<NSH; sh++){
      int c = counts8[(size_t)sh*NN + i];
      pfx[(size_t)sh*NN + i] = run;
      run += c;
    }
    v = run;
    counts[i] = run;
  }
  int lane = tid & 63, w = tid >> 6;
  int s = v;                       // inclusive wave scan
  #pragma unroll
  for (int off=1; off<64; off<<=1){
    int t = __shfl_up(s, off, 64);
    if (lane >= off) s += t;
  }
  if (lane == 63) wsum[w] = s;
  __syncthreads();
  if (w == 0 && lane < 16){
    int t = wsum[lane];
    #pragma unroll
    for (int off=1; off<16; off<<=1){
      int u = __shfl_up(t, off, 64);
      if (lane >= off) t += u;
    }
    wsum[lane] = t;                // inclusive wave partials
  }
  __syncthreads();
  int base = (w > 0) ? wsum[w-1] : 0;
  int incl = base + s;
  if (i < NN) row_excl[i] = incl - v;
  if (tid == 1023) part[blockIdx.x] = incl;
}

// ---------------- scan phase 2 ----------------
__global__ __launch_bounds__(128) void scan2_kernel(int* __restrict__ part, int nparts)
{
  __shared__ int buf[128];
  int tid = threadIdx.x;
  int v = (tid < nparts) ? part[tid] : 0;
  buf[tid] = v;
  __syncthreads();
  for (int off=1; off<128; off<<=1){
    int t = (tid >= off) ? buf[tid-off] : 0;
    __syncthreads();
    buf[tid] += t;
    __syncthreads();
  }
  if (tid < nparts) part[tid] = buf[tid] - v;
}

// ---------------- fill sorted edge records (no atomics; shard-rank precomputed) ------
// p = global base of dst + shard prefix + rank within shard. Within-run order is
// shard-major (already non-deterministic pre-sharding -- blocks run in any order).
__global__ __launch_bounds__(256) void fill_kernel(
    const int* __restrict__ src, const int* __restrict__ dst,
    const int* __restrict__ row_excl, const int* __restrict__ part,
    const int* __restrict__ pfx,
    const int* __restrict__ rank, int2* __restrict__ sedge)
{
  int e = blockIdx.x*256 + threadIdx.x;
  if (e >= NE) return;
  int d = dst[e];
  int sh = (e >> 10) & (NSH-1);
  int p = row_excl[d] + part[d >> 10] + pfx[(size_t)sh*NN + d] + rank[e];
  sedge[p] = make_int2(src[e], d);
}

// ---------------- plain count (fallback path only) ----------------
__global__ __launch_bounds__(256) void count_kernel(const int* __restrict__ dst,
                                                    int* __restrict__ counts)
{
  int e = blockIdx.x*256 + threadIdx.x;
  if (e < NE) atomicAdd(&counts[dst[e]], 1);
}

// ---------------- preswizzle ALL weights to fp16 MFMA B-fragment order -------------
// frag index within a K x N weight: idx = ((kb*4+quad)*N + col)*8 + j,  k = kb*32+quad*8+j
// layout (ushort elems): [0,24576) uw1p | [24576,36864) uw2p |
// [36864,61440) pprojp | [61440,65536) ow1p | [65536,77824) msgw2p   (all fp16)
__global__ __launch_bounds__(256) void prep_all_kernel(
    const float* __restrict__ uw1, const float* __restrict__ uw2,
    const float* __restrict__ mw1, const float* __restrict__ mw2,
    const float* __restrict__ ow1, unsigned short* __restrict__ wp)
{
  int i = blockIdx.x*256 + threadIdx.x;
  if (i >= 77824) return;
  float val;
  if (i < 24576){
    int l = i / 8192, r = i & 8191;
    int j = r & 7, col = (r >> 3) & 63, g = r >> 9;
    int k = (g >> 2)*32 + (g & 3)*8 + j;
    val = uw1[(size_t)l*8192 + k*64 + col];
  } else if (i < 36864){
    int t = i - 24576; int l = t / 4096, r = t & 4095;
    int j = r & 7, col = (r >> 3) & 63, g = r >> 9;
    int k = (g >> 2)*32 + (g & 3)*8 + j;
    val = uw2[(size_t)l*4096 + k*64 + col];
  } else if (i < 61440){
    int t = i - 36864; int l = t / 8192, r = t & 8191;
    int j = r & 7, col = (r >> 3) & 127, g = r >> 10;
    int k = (g >> 2)*32 + (g & 3)*8 + j;
    val = mw1[(size_t)l*8192 + ((col >> 6)*64 + k)*64 + (col & 63)];
  } else if (i < 65536){
    int r = i - 61440;
    int j = r & 7, col = (r >> 3) & 63, g = r >> 9;
    int k = (g >> 2)*32 + (g & 3)*8 + j;
    val = ow1[k*64 + col];
  } else {
    int t = i - 65536; int l = t / 4096, r = t & 4095;
    int j = r & 7, col = (r >> 3) & 63, g = r >> 9;
    int k = (g >> 2)*32 + (g & 3)*8 + j;
    val = mw2[(size_t)l*4096 + k*64 + col];
  }
  wp[i] = f2h_(val);
}

// ---------------- MFMA message kernel v13: v10 base + mask-driven walk (round-4 win:
// boundary bitmask via __ballot, scalar ctz per RUN, counted pipelineable sum loop).
// Round-5: staged int2 edge records (single coalesced load). ----
__global__ __launch_bounds__(MBT, 4) void msg_mfma_kernel(
    const unsigned short* __restrict__ P,
    const unsigned short* __restrict__ w2p,
    const float* __restrict__ b2,
    const int2* __restrict__ sedge,
    unsigned short* __restrict__ aggh,
    float* __restrict__ bval, int* __restrict__ bdst)
{
  __shared__ unsigned short mlds[64*MSTRIDE];
  __shared__ int2 sdl[EB];
  const int tid  = threadIdx.x;
  const int wave = tid >> 6, lane = tid & 63, quad = lane >> 4, c = lane & 15;

  // XCD-contiguous swizzle
  int bid = blockIdx.x;
  int ng = gridDim.x >> 3;
  int lb = (bid < (ng << 3)) ? ((bid & 7)*ng + (bid >> 3)) : bid;
  const int base = lb*EB;

  if (tid < EB){
    int p = base + tid;
    int2 sv = make_int2(0, -1);
    if (p < NE) sv = sedge[p];
    sdl[tid] = sv;
  }

  // B fragments (fp16) + bias
  f16x8 bfr[4][2];
  #pragma unroll
  for (int n=0;n<4;n++)
    #pragma unroll
    for (int kb=0;kb<2;kb++)
      bfr[n][kb] = *(const f16x8*)(w2p + (((kb*4 + quad)*64 + n*16 + c) << 3));
  float bv[4];
  #pragma unroll
  for (int n=0;n<4;n++) bv[n] = b2[n*16 + c];

  __syncthreads();

  const int ebase = wave*32;
  #pragma unroll
  for (int t=0;t<2;t++){
    int2 sd = sdl[ebase + t*16 + c];
    int s = sd.x;
    int d = sd.y < 0 ? 0 : sd.y;
    const unsigned short* p1 = P + (size_t)s*128 + quad*8;
    const unsigned short* p2 = P + (size_t)d*128 + 64 + quad*8;
    f16x8 af[2];
    #pragma unroll
    for (int kb=0;kb<2;kb++){
      uint4 u1 = *(const uint4*)(p1 + kb*32);
      uint4 u2 = *(const uint4*)(p2 + kb*32);
      union { unsigned int u[4]; f16x8 v; } A;
      A.u[0] = addrelu2_(u1.x, u2.x);
      A.u[1] = addrelu2_(u1.y, u2.y);
      A.u[2] = addrelu2_(u1.z, u2.z);
      A.u[3] = addrelu2_(u1.w, u2.w);
      af[kb] = A.v;
    }

    f32x4 acc4[4];
    #pragma unroll
    for (int n=0;n<4;n++) acc4[n] = (f32x4){0.f, 0.f, 0.f, 0.f};
    #pragma unroll
    for (int n=0;n<4;n++){
      acc4[n] = __builtin_amdgcn_mfma_f32_16x16x32_f16(af[0], bfr[n][0], acc4[n], 0, 0, 0);
      acc4[n] = __builtin_amdgcn_mfma_f32_16x16x32_f16(af[1], bfr[n][1], acc4[n], 0, 0, 0);
    }

    int e0 = ebase + t*16 + quad*4;
    #pragma unroll
    for (int n=0;n<4;n++){
      int ch = n*16 + c;
      float v0 = relu_(acc4[n][0] + bv[n]);
      float v1 = relu_(acc4[n][1] + bv[n]);
      float v2 = relu_(acc4[n][2] + bv[n]);
      float v3 = relu_(acc4[n][3] + bv[n]);
      *(unsigned int*)&mlds[ch*MSTRIDE + e0]     = pkh_(v0, v1);
      *(unsigned int*)&mlds[ch*MSTRIDE + e0 + 2] = pkh_(v2, v3);
    }
  }
  __syncthreads();

  // ---- mask-driven segmented reduce (single owner per run) ----
  {
    const int g = wave;
    const int ch = lane;
    int dA  = sdl[lane].y;
    int dAm = (lane == 0) ? ~dA : sdl[lane-1].y;     // force boundary at 0
    unsigned long long m0 = __ballot(dA != dAm);
    int dB  = sdl[64+lane].y;
    int dBm = sdl[63+lane].y;
    unsigned long long m1 = __ballot(dB != dBm);

    auto isb = [&](int p)->bool{
      return (p < 64) ? ((m0 >> p) & 1ull) : ((m1 >> (p-64)) & 1ull);
    };
    auto nextb = [&](int p)->int{
      int q = p + 1;
      if (q < 64){
        unsigned long long t = m0 >> q;
        if (t) return q + __builtin_ctzll(t);
        q = 64;
      }
      int off = q - 64;
      if (off < 64){
        unsigned long long t = m1 >> off;
        if (t) return q + __builtin_ctzll(t);
      }
      return EB;
    };

    int r = g*32;
    if (g > 0 && !isb(r)) r = nextb(r);   // skip run continuing from prev window
    const int myEnd = (g+1)*32;
    while (r < myEnd){
      int nb = nextb(r);                  // run end (exclusive), may cross windows
      int cur = sdl[r].y;
      float s2 = 0.f;
      for (int rr = r; rr < nb; ++rr)
        s2 += h2f_(mlds[ch*MSTRIDE + rr]);
      if (cur >= 0){
        bool headB = (r == 0);
        bool tailB = (nb == EB);
        if (headB){
          bval[(size_t)(2*lb)*64 + ch] = s2;
          if (ch == 0) bdst[2*lb] = cur;
          if (tailB){
            bval[(size_t)(2*lb+1)*64 + ch] = 0.f;   // contiguity filler
            if (ch == 0) bdst[2*lb+1] = cur;
          }
        } else if (tailB){
          bval[(size_t)(2*lb+1)*64 + ch] = s2;
          if (ch == 0) bdst[2*lb+1] = cur;
        } else {
          aggh[(size_t)cur*H + ch] = f2h_(s2);
        }
      }
      r = nb;
    }
  }
}

// ---------------- second-level boundary merge: zero atomics, plain stores ----------
// Round-3: ownership window 64 -> 16 entries (won ~63us). Semantics identical.
#define BW 16
__global__ __launch_bounds__(256) void bnd_fixup_kernel(
    const int* __restrict__ bdst, const float* __restrict__ bval,
    unsigned short* __restrict__ aggh, int nbnd)
{
  const int wave = threadIdx.x >> 6, ch = threadIdx.x & 63;
  int g = blockIdx.x*4 + wave;
  int r0 = g*BW;
  if (r0 >= nbnd) return;
  int r = r0;
  if (r0 > 0){
    int prev = bdst[r0-1];
    while (r < nbnd && bdst[r] == prev) r++;
  }
  int rlim = r0 + BW;
  while (r < nbnd){
    int runstart = r;
    if (runstart >= rlim) break;
    int cur = bdst[r];
    float s = 0.f;
    while (r < nbnd && bdst[r] == cur){
      s += bval[(size_t)r*64 + ch];
      r++;
    }
    if (cur >= 0) aggh[(size_t)cur*H + ch] = f2h_(s);
  }
}

// ---------------- fused node-side layer kernel (fp16 MFMA, fp16 agg in) -------------
// mode 0 (l=0,1): h' = relu-MLP2([h||agg/deg]) -> hout(fp16) ; P_next = h'@W3 (+b3 top) -> Pout
// mode 1 (l=2):   h' as above; out = 2pi*sigmoid(relu(h'@ow1+b3)@ow2+ob2) -> outp
// mode 2 (pproj only): P = hbf@W3 (+b3 top) -> Pout
// Zero-degree nodes: agg never written (no memset) -> masked via invd=0.
__global__ __launch_bounds__(256) void node_fused_kernel(
    const unsigned short* __restrict__ hbf,
    const unsigned short* __restrict__ aggh, const int* __restrict__ counts,
    const unsigned short* __restrict__ uw1p, const float* __restrict__ ub1,
    const unsigned short* __restrict__ uw2p, const float* __restrict__ ub2,
    const unsigned short* __restrict__ w3p,  const float* __restrict__ b3,
    const float* __restrict__ ow2, const float* __restrict__ ob2,
    unsigned short* __restrict__ hout,
    unsigned short* __restrict__ Pout,
    float* __restrict__ outp,
    int mode)
{
  __shared__ __align__(16) unsigned short act[64*72];
  __shared__ __align__(16) unsigned short pst[64*136];
  const int tid = threadIdx.x, wave = tid >> 6, lane = tid & 63;
  const int quad = lane >> 4, c = lane & 15;
  const int vb = blockIdx.x*64;
  int myv = vb + wave*16 + c;
  int vld = myv < NN ? myv : NN-1;

  if (mode != 2){
    int cntv = counts[vld];
    float invf = (cntv > 0) ? (1.0f / (float)cntv) : 0.0f;   // masks unwritten agg
    f16x2 invd2; invd2[0] = (_Float16)invf; invd2[1] = (_Float16)invf;
    f16x8 a1[4];
    a1[0] = *(const f16x8*)(hbf + (size_t)vld*H + quad*8);
    a1[1] = *(const f16x8*)(hbf + (size_t)vld*H + 32 + quad*8);
    #pragma unroll
    for (int kb2=0; kb2<2; kb2++){
      uint4 u = *(const uint4*)(aggh + (size_t)vld*H + kb2*32 + quad*8);
      union { unsigned int u[4]; f16x8 v; } A;
      A.u[0] = mulpk_(u.x, invd2);
      A.u[1] = mulpk_(u.y, invd2);
      A.u[2] = mulpk_(u.z, invd2);
      A.u[3] = mulpk_(u.w, invd2);
      a1[2+kb2] = A.v;
    }
    f32x4 acc1[4];
    #pragma unroll
    for (int n=0;n<4;n++) acc1[n] = (f32x4){0.f,0.f,0.f,0.f};
    #pragma unroll
    for (int n=0;n<4;n++){
      #pragma unroll
      for (int kb=0;kb<4;kb++){
        f16x8 b = *(const f16x8*)(uw1p + (((kb*4 + quad)*64 + n*16 + c) << 3));
        acc1[n] = __builtin_amdgcn_mfma_f32_16x16x32_f16(a1[kb], b, acc1[n], 0, 0, 0);
      }
    }
    #pragma unroll
    for (int n=0;n<4;n++){
      float bb = ub1[n*16 + c];
      #pragma unroll
      for (int r=0;r<4;r++)
        act[(wave*16 + quad*4 + r)*72 + n*16 + c] = f2h_(relu_(acc1[n][r] + bb));
    }

    f16x8 a2[2];
    a2[0] = *(const f16x8*)(act + (wave*16 + c)*72 + quad*8);
    a2[1] = *(const f16x8*)(act + (wave*16 + c)*72 + 32 + quad*8);
    f32x4 acc2[4];
    #pragma unroll
    for (int n=0;n<4;n++) acc2[n] = (f32x4){0.f,0.f,0.f,0.f};
    #pragma unroll
    for (int n=0;n<4;n++){
      #pragma unroll
      for (int kb=0;kb<2;kb++){
        f16x8 b = *(const f16x8*)(uw2p + (((kb*4 + quad)*64 + n*16 + c) << 3));
        acc2[n] = __builtin_amdgcn_mfma_f32_16x16x32_f16(a2[kb], b, acc2[n], 0, 0, 0);
      }
    }
    #pragma unroll
    for (int n=0;n<4;n++){
      float bb = ub2[n*16 + c];
      #pragma unroll
      for (int r=0;r<4;r++)
        act[(wave*16 + quad*4 + r)*72 + n*16 + c] = f2h_(relu_(acc2[n][r] + bb));
    }
  }

  f16x8 a3[2];
  if (mode == 2){
    a3[0] = *(const f16x8*)(hbf + (size_t)vld*H + quad*8);
    a3[1] = *(const f16x8*)(hbf + (size_t)vld*H + 32 + quad*8);
  } else {
    a3[0] = *(const f16x8*)(act + (wave*16 + c)*72 + quad*8);
    a3[1] = *(const f16x8*)(act + (wave*16 + c)*72 + 32 + quad*8);
  }

  if (mode == 1){
    f32x4 acc3[4];
    #pragma unroll
    for (int n=0;n<4;n++) acc3[n] = (f32x4){0.f,0.f,0.f,0.f};
    #pragma unroll
    for (int n=0;n<4;n++){
      #pragma unroll
      for (int kb=0;kb<2;kb++){
        f16x8 b = *(const f16x8*)(w3p + (((kb*4 + quad)*64 + n*16 + c) << 3));
        acc3[n] = __builtin_amdgcn_mfma_f32_16x16x32_f16(a3[kb], b, acc3[n], 0, 0, 0);
      }
    }
    #pragma unroll
    for (int n=0;n<4;n++){
      float bb = b3[n*16 + c];
      #pragma unroll
      for (int r=0;r<4;r++)
        act[(wave*16 + quad*4 + r)*72 + n*16 + c] = f2h_(relu_(acc3[n][r] + bb));
    }
  } else {
    f32x4 acc3[8];
    #pragma unroll
    for (int n=0;n<8;n++) acc3[n] = (f32x4){0.f,0.f,0.f,0.f};
    #pragma unroll
    for (int n=0;n<8;n++){
      #pragma unroll
      for (int kb=0;kb<2;kb++){
        f16x8 b = *(const f16x8*)(w3p + (((kb*4 + quad)*128 + n*16 + c) << 3));
        acc3[n] = __builtin_amdgcn_mfma_f32_16x16x32_f16(a3[kb], b, acc3[n], 0, 0, 0);
      }
    }
    #pragma unroll
    for (int n=0;n<8;n++){
      int ch = n*16 + c;
      float bb = (ch >= 64) ? b3[ch - 64] : 0.0f;
      #pragma unroll
      for (int r=0;r<4;r++)
        pst[(wave*16 + quad*4 + r)*136 + ch] = f2h_(acc3[n][r] + bb);
    }
  }

  __syncthreads();

  if (mode == 0){
    #pragma unroll
    for (int rr=0; rr<2; rr++){
      int idx = tid + rr*256;
      int node = idx >> 3, ko = (idx & 7)*8;
      int v = vb + node;
      if (v < NN) *(uint4*)(hout + (size_t)v*H + ko) = *(const uint4*)(act + node*72 + ko);
    }
  }
  if (mode == 0 || mode == 2){
    #pragma unroll
    for (int rr=0; rr<4; rr++){
      int idx = tid + rr*256;
      int node = idx >> 4, cho = (idx & 15)*8;
      int v = vb + node;
      if (v < NN) *(uint4*)(Pout + (size_t)v*128 + cho) = *(const uint4*)(pst + node*136 + cho);
    }
  }
  if (mode == 1){
    if (tid < 192){
      int node = tid / 3;
      int v = vb + node;
      if (v < NN){
        int cm = tid - node*3;
        float s = ob2[cm];
        #pragma unroll 8
        for (int k=0;k<64;k++)
          s = fmaf(h2f_(act[node*72 + k]), ow2[k*3 + cm], s);
        outp[(size_t)v*3 + cm] = 6.283185307179586f / (1.0f + __expf(-s));
      }
    }
  }
}

// ================= legacy fallback kernels (known correct; small ws) =================
__global__ __launch_bounds__(256) void enc_kernel_legacy(
    const float* __restrict__ x,
    const float* __restrict__ w1, const float* __restrict__ b1,
    const float* __restrict__ w2, const float* __restrict__ b2,
    float* __restrict__ h)
{
  int v = blockIdx.x*256 + threadIdx.x;
  if (v >= NN) return;
  float in0[5];
  #pragma unroll
  for (int k=0;k<5;k++) in0[k] = x[v*5+k];
  float hid[H];
  #pragma unroll
  for (int j=0;j<H;j++) hid[j] = b1[j];
  #pragma unroll
  for (int k=0;k<5;k++){
    #pragma unroll
    for (int j=0;j<H;j++) hid[j] = fmaf(in0[k], w1[k*H+j], hid[j]);
  }
  float o[H];
  #pragma unroll
  for (int j=0;j<H;j++) o[j] = b2[j];
  #pragma unroll
  for (int k=0;k<H;k++){
    float hk = relu_(hid[k]);
    #pragma unroll
    for (int j=0;j<H;j++) o[j] = fmaf(hk, w2[k*H+j], o[j]);
  }
  float4* hw = (float4*)(h + (size_t)v*H);
  #pragma unroll
  for (int j4=0;j4<H/4;j4++){
    float4 t;
    t.x = relu_(o[4*j4+0]); t.y = relu_(o[4*j4+1]);
    t.z = relu_(o[4*j4+2]); t.w = relu_(o[4*j4+3]);
    hw[j4] = t;
  }
}

__global__ __launch_bounds__(256) void msg_kernel_atomic(
    const float* __restrict__ h,
    const int* __restrict__ src, const int* __restrict__ dst,
    const float* __restrict__ w1, const float* __restrict__ b1,
    const float* __restrict__ w2, const float* __restrict__ b2,
    float* __restrict__ agg)
{
  int e = blockIdx.x*256 + threadIdx.x;
  if (e >= NE) return;
  int s = src[e], d = dst[e];
  const float4* hs = (const float4*)(h + (size_t)s*H);
  const float4* hd = (const float4*)(h + (size_t)d*H);
  float hid[H];
  #pragma unroll
  for (int j=0;j<H;j++) hid[j] = b1[j];
  #pragma unroll 4
  for (int k4=0;k4<16;k4++){
    float4 a = hs[k4];
    const float* wr = w1 + (size_t)(4*k4)*H;
    #pragma unroll
    for (int j=0;j<H;j++) hid[j] = fmaf(a.x, wr[j], hid[j]);
    #pragma unroll
    for (int j=0;j<H;j++) hid[j] = fmaf(a.y, wr[H+j], hid[j]);
    #pragma unroll
    for (int j=0;j<H;j++) hid[j] = fmaf(a.z, wr[2*H+j], hid[j]);
    #pragma unroll
    for (int j=0;j<H;j++) hid[j] = fmaf(a.w, wr[3*H+j], hid[j]);
  }
  #pragma unroll 4
  for (int k4=0;k4<16;k4++){
    float4 a = hd[k4];
    const float* wr = w1 + (size_t)(64 + 4*k4)*H;
    #pragma unroll
    for (int j=0;j<H;j++) hid[j] = fmaf(a.x, wr[j], hid[j]);
    #pragma unroll
    for (int j=0;j<H;j++) hid[j] = fmaf(a.y, wr[H+j], hid[j]);
    #pragma unroll
    for (int j=0;j<H;j++) hid[j] = fmaf(a.z, wr[2*H+j], hid[j]);
    #pragma unroll
    for (int j=0;j<H;j++) hid[j] = fmaf(a.w, wr[3*H+j], hid[j]);
  }
  float o[H];
  #pragma unroll
  for (int j=0;j<H;j++) o[j] = b2[j];
  #pragma unroll
  for (int k=0;k<H;k++){
    float hk = relu_(hid[k]);
    #pragma unroll
    for (int j=0;j<H;j++) o[j] = fmaf(hk, w2[k*H+j], o[j]);
  }
  float* arow = agg + (size_t)d*H;
  #pragma unroll
  for (int j=0;j<H;j++) atomicAdd(arow + j, relu_(o[j]));
}

__global__ __launch_bounds__(256) void div_kernel(float* __restrict__ agg,
                                                  const int* __restrict__ counts)
{
  int i = blockIdx.x*256 + threadIdx.x;
  if (i >= NN*H/4) return;
  int v = i / (H/4);
  float invd = 1.0f / fmaxf((float)counts[v], 1.0f);
  float4* a = (float4*)agg + i;
  float4 t = *a;
  t.x *= invd; t.y *= invd; t.z *= invd; t.w *= invd;
  *a = t;
}

__global__ __launch_bounds__(256) void upd_kernel_legacy(
    float* __restrict__ h, const float* __restrict__ agg,
    const float* __restrict__ w1, const float* __restrict__ b1,
    const float* __restrict__ w2, const float* __restrict__ b2)
{
  int v = blockIdx.x*256 + threadIdx.x;
  if (v >= NN) return;
  const float4* hv = (const float4*)(h + (size_t)v*H);
  const float4* av = (const float4*)(agg + (size_t)v*H);
  float hid[H];
  #pragma unroll
  for (int j=0;j<H;j++) hid[j] = b1[j];
  #pragma unroll 4
  for (int k4=0;k4<16;k4++){
    float4 a = hv[k4];
    const float* wr = w1 + (size_t)(4*k4)*H;
    #pragma unroll
    for (int j=0;j<H;j++) hid[j] = fmaf(a.x, wr[j], hid[j]);
    #pragma unroll
    for (int j=0;j<H;j++) hid[j] = fmaf(a.y, wr[H+j], hid[j]);
    #pragma unroll
    for (int j=0;j<H;j++) hid[j] = fmaf(a.z, wr[2*H+j], hid[j]);
    #pragma unroll
    for (int j=0;j<H;j++) hid[j] = fmaf(a.w, wr[3*H+j], hid[j]);
  }
  #pragma unroll 4
  for (int k4=0;k4<16;k4++){
    float4 a = av[k4];
    const float* wr = w1 + (size_t)(64 + 4*k4)*H;
    #pragma unroll
    for (int j=0;j<H;j++) hid[j] = fmaf(a.x, wr[j], hid[j]);
    #pragma unroll
    for (int j=0;j<H;j++) hid[j] = fmaf(a.y, wr[H+j], hid[j]);
    #pragma unroll
    for (int j=0;j<H;j++) hid[j] = fmaf(a.z, wr[2*H+j], hid[j]);
    #pragma unroll
    for (int j=0;j<H;j++) hid[j] = fmaf(a.w, wr[3*H+j], hid[j]);
  }
  float o[H];
  #pragma unroll
  for (int j=0;j<H;j++) o[j] = b2[j];
  #pragma unroll
  for (int k=0;k<H;k++){
    float hk = relu_(hid[k]);
    #pragma unroll
    for (int j=0;j<H;j++) o[j] = fmaf(hk, w2[k*H+j], o[j]);
  }
  float4* hw = (float4*)(h + (size_t)v*H);
  #pragma unroll
  for (int j4=0;j4<H/4;j4++){
    float4 t;
    t.x = relu_(o[4*j4+0]); t.y = relu_(o[4*j4+1]);
    t.z = relu_(o[4*j4+2]); t.w = relu_(o[4*j4+3]);
    hw[j4] = t;
  }
}

__global__ __launch_bounds__(256) void out_kernel2(
    const float* __restrict__ h,
    const float* __restrict__ w1, const float* __restrict__ b1,
    const float* __restrict__ w2, const float* __restrict__ b2,
    float* __restrict__ out)
{
  int v = blockIdx.x*256 + threadIdx.x;
  if (v >= NN) return;
  const float4* hv = (const float4*)(h + (size_t)v*H);
  float pr[3] = { b2[0], b2[1], b2[2] };
  #pragma unroll 1
  for (int half=0; half<2; half++){
    float o[32];
    #pragma unroll
    for (int j=0;j<32;j++) o[j] = b1[half*32 + j];
    #pragma unroll 4
    for (int k4=0;k4<16;k4++){
      float4 a = hv[k4];
      const float* wr = w1 + (4*k4)*H + half*32;
      fma32(o, a.x, wr); fma32(o, a.y, wr+H); fma32(o, a.z, wr+2*H); fma32(o, a.w, wr+3*H);
    }
    #pragma unroll
    for (int j=0;j<32;j++){
      float hk = relu_(o[j]);
      int k = half*32 + j;
      pr[0] = fmaf(hk, w2[k*3+0], pr[0]);
      pr[1] = fmaf(hk, w2[k*3+1], pr[1]);
      pr[2] = fmaf(hk, w2[k*3+2], pr[2]);
    }
  }
  #pragma unroll
  for (int c=0;c<3;c++)
    out[(size_t)v*3 + c] = 6.283185307179586f / (1.0f + __expf(-pr[c]));
}

// =====================================================================

extern "C" void kernel_launch(void* const* d_in, const int* in_sizes, int n_in,
                              void* d_out, int out_size, void* d_ws, size_t ws_size,
                              hipStream_t stream)
{
  const float* x      = (const float*)d_in[0];
  const int*   ei     = (const int*)  d_in[1];
  const float* enc_w1 = (const float*)d_in[2];
  const float* enc_b1 = (const float*)d_in[3];
  const float* enc_w2 = (const float*)d_in[4];
  const float* enc_b2 = (const float*)d_in[5];
  const float* msg_w1 = (const float*)d_in[6];
  const float* msg_b1 = (const float*)d_in[7];
  const float* msg_w2 = (const float*)d_in[8];
  const float* msg_b2 = (const float*)d_in[9];
  const float* upd_w1 = (const float*)d_in[10];
  const float* upd_b1 = (const float*)d_in[11];
  const float* upd_w2 = (const float*)d_in[12];
  const float* upd_b2 = (const float*)d_in[13];
  const float* out_w1 = (const float*)d_in[14];
  const float* out_b1 = (const float*)d_in[15];
  const float* out_w2 = (const float*)d_in[16];
  const float* out_b2 = (const float*)d_in[17];
  float* out = (float*)d_out;

  const int* srcp = ei;
  const int* dstp = ei + NE;

  const int nodeBlocks  = (NN + 255)/256;
  const int edgeBlocks  = (NE + 255)/256;
  const int rankBlocks  = (NE + 1023)/1024;          // 4 edges/thread
  const int msgBlocks   = (NE + EB - 1)/EB;          // 7813
  const int nbnd        = 2*msgBlocks;               // 15626
  const int fixBlocks   = ((nbnd + BW - 1)/BW + 3)/4; // 245
  const int scanBlocks  = (NN + 1023)/1024;
  const int fusedBlocks = (NN + 63)/64;              // 1563

  // ---- workspace layout ----
  char* wp_ = (char*)d_ws;
  auto take = [&wp_](size_t bytes) -> char* {
    char* r = wp_;
    wp_ += (bytes + 255) & ~(size_t)255;
    return r;
  };
  unsigned short* hbf = (unsigned short*)take((size_t)NN*H*sizeof(unsigned short)); // 12.8 MB fp16
  unsigned short* P   = (unsigned short*)take((size_t)NN*128*sizeof(unsigned short)); // 25.6 MB fp16
  unsigned short* aggh= (unsigned short*)take((size_t)NN*H*sizeof(unsigned short)); // 12.8 MB fp16
  int* counts         = (int*)take((size_t)NN*sizeof(int));
  int* counts8        = (int*)take((size_t)NSH*NN*sizeof(int));                    // 3.2 MB
  int* pfx            = (int*)take((size_t)NSH*NN*sizeof(int));                    // 3.2 MB
  int* row_excl       = (int*)take((size_t)NN*sizeof(int));
  int* part           = (int*)take(1024);
  int* rank           = (int*)take((size_t)NE*sizeof(int));                        // 4 MB
  int2* sedge         = (int2*)take((size_t)NE*sizeof(int2));                      // 8 MB
  float* bval         = (float*)take((size_t)nbnd*64*sizeof(float));               // 4 MB
  int* bdst           = (int*)take((size_t)nbnd*sizeof(int));
  unsigned short* wpz = (unsigned short*)take((size_t)77824*sizeof(unsigned short));
  size_t need = (size_t)(wp_ - (char*)d_ws);

  // preswizzled-weight offsets (ushort elements)
  const size_t UW1 = 0, UW2 = 24576, PPJ = 36864, OW1 = 61440, MW2 = 65536;

  if (ws_size >= need) {
    (void)hipMemsetAsync(counts8, 0, (size_t)NSH*NN*sizeof(int), stream);
    (void)hipMemsetAsync(bdst, 0xFF, nbnd*sizeof(int), stream);   // dst = -1 sentinel

    enc_full_kernel<<<nodeBlocks, 256, 0, stream>>>(x, enc_w1, enc_b1, enc_w2, enc_b2, hbf);

    rank_kernel<<<rankBlocks, 256, 0, stream>>>(dstp, counts8, rank);
    scan1_kernel<<<scanBlocks, 1024, 0, stream>>>(counts8, counts, pfx, row_excl, part);
    scan2_kernel<<<1, 128, 0, stream>>>(part, scanBlocks);
    fill_kernel<<<edgeBlocks, 256, 0, stream>>>(srcp, dstp, row_excl, part, pfx, rank, sedge);
    prep_all_kernel<<<(77824 + 255)/256, 256, 0, stream>>>(upd_w1, upd_w2, msg_w1, msg_w2, out_w1, wpz);

    // layer-0 P projection (mode 2)
    node_fused_kernel<<<fusedBlocks, 256, 0, stream>>>(
        hbf, aggh, counts,
        nullptr, nullptr, nullptr, nullptr,
        wpz + PPJ, msg_b1, nullptr, nullptr,
        nullptr, P, nullptr, 2);

    for (int l=0; l<3; l++){
      msg_mfma_kernel<<<msgBlocks, MBT, 0, stream>>>(P, wpz + MW2 + (size_t)l*4096,
          msg_b2 + (size_t)l*H, sedge, aggh, bval, bdst);
      bnd_fixup_kernel<<<fixBlocks, 256, 0, stream>>>(bdst, bval, aggh, nbnd);
      if (l < 2){
        node_fused_kernel<<<fusedBlocks, 256, 0, stream>>>(
            hbf, aggh, counts,
            wpz + UW1 + (size_t)l*8192, upd_b1 + (size_t)l*H,
            wpz + UW2 + (size_t)l*4096, upd_b2 + (size_t)l*H,
            wpz + PPJ + (size_t)(l+1)*8192, msg_b1 + (size_t)(l+1)*H,
            nullptr, nullptr,
            hbf, P, nullptr, 0);
      } else {
        node_fused_kernel<<<fusedBlocks, 256, 0, stream>>>(
            hbf, aggh, counts,
            wpz + UW1 + (size_t)l*8192, upd_b1 + (size_t)l*H,
            wpz + UW2 + (size_t)l*4096, upd_b2 + (size_t)l*H,
            wpz + OW1, out_b1,
            out_w2, out_b2,
            nullptr, nullptr, out, 1);
      }
    }
  } else {
    // ======== fallback: legacy atomic path (fits in ~52 MB) ========
    char* fp = (char*)d_ws;
    float* fh   = (float*)fp;  fp += (size_t)NN*H*sizeof(float);
    float* fagg = (float*)fp;  fp += (size_t)NN*H*sizeof(float);
    int* fcnt   = (int*)fp;

    (void)hipMemsetAsync(fcnt, 0, NN*sizeof(int), stream);
    enc_kernel_legacy<<<nodeBlocks, 256, 0, stream>>>(x, enc_w1, enc_b1, enc_w2, enc_b2, fh);
    count_kernel<<<edgeBlocks, 256, 0, stream>>>(dstp, fcnt);
    for (int l=0; l<3; l++){
      (void)hipMemsetAsync(fagg, 0, (size_t)NN*H*sizeof(float), stream);
      msg_kernel_atomic<<<edgeBlocks, 256, 0, stream>>>(fh, srcp, dstp,
          msg_w1 + (size_t)l*128*H, msg_b1 + (size_t)l*H,
          msg_w2 + (size_t)l*H*H,   msg_b2 + (size_t)l*H, fagg);
      div_kernel<<<(NN*H/4 + 255)/256, 256, 0, stream>>>(fagg, fcnt);
      upd_kernel_legacy<<<nodeBlocks, 256, 0, stream>>>(fh, fagg,
          upd_w1 + (size_t)l*128*H, upd_b1 + (size_t)l*H,
          upd_w2 + (size_t)l*H*H,   upd_b2 + (size_t)l*H);
    }
    out_kernel2<<<nodeBlocks, 256, 0, stream>>>(fh, out_w1, out_b1, out_w2, out_b2, out);
  }
}

// Round 8
// 401.584 us; speedup vs baseline: 1.0003x; 1.0003x over previous
//
#include <hip/hip_runtime.h>
#include <math.h>

#define NN 100000
#define NE 1000000
#define H 64
#define EB 256        // edges per msg block (round-7: 128 -> 256, amortize fixed costs)
#define MBT 256       // msg block threads (4 waves; each wave does 64 edges)
#define MSTRIDE 258   // ushorts per channel row in msg LDS (256 edges + 2 pad)
#define NSH 8         // atomic shards for rank (round-6: line-contention fix)

typedef _Float16 f16x8 __attribute__((ext_vector_type(8)));
typedef _Float16 f16x2 __attribute__((ext_vector_type(2)));
typedef float f32x4  __attribute__((ext_vector_type(4)));

static __device__ __forceinline__ float relu_(float x){ return fmaxf(x, 0.0f); }

static __device__ __forceinline__ unsigned short f2h_(float f){
  union { _Float16 h; unsigned short u; } x; x.h = (_Float16)f; return x.u;
}
static __device__ __forceinline__ float h2f_(unsigned short u){
  union { unsigned short u; _Float16 h; } x; x.u = u; return (float)x.h;
}
static __device__ __forceinline__ unsigned int pkh_(float lo, float hi){
  union { f16x2 v; unsigned int u; } x;
  x.v[0] = (_Float16)lo; x.v[1] = (_Float16)hi;
  return x.u;
}
// packed fp16: relu(a + b) on 2 lanes (lowers to v_pk_add_f16 + v_pk_max_f16)
static __device__ __forceinline__ unsigned int addrelu2_(unsigned int a, unsigned int b){
  union { unsigned int u; f16x2 v; } x, y, r;
  x.u = a; y.u = b;
  f16x2 s = x.v + y.v;
  _Float16 z = (_Float16)0.0f;
  r.v[0] = (s[0] > z) ? s[0] : z;
  r.v[1] = (s[1] > z) ? s[1] : z;
  return r.u;
}
// packed fp16 multiply by broadcast scale (v_pk_mul_f16)
static __device__ __forceinline__ unsigned int mulpk_(unsigned int a, f16x2 s){
  union { unsigned int u; f16x2 v; } x;
  x.u = a; x.v = x.v * s;
  return x.u;
}
// fire-and-forget packed fp16 atomic add (gfx90a+/gfx950)
static __device__ __forceinline__ void atomic_pk_f16_(unsigned short* p, unsigned int pk){
  asm volatile("global_atomic_pk_add_f16 %0, %1, off" :: "v"(p), "v"(pk) : "memory");
}
static __device__ __forceinline__ void fma32(float* o, float a, const float* wr){
  #pragma unroll
  for (int j=0;j<32;j++) o[j] = fmaf(a, wr[j], o[j]);
}

// ---------------- fused encoder: hbf(fp16) = relu(relu(x@w1+b1)@w2+b2) ----------------
// Round 0 fix: hidden t[64] with runtime index -> scratch (51 MB traffic). Now the
// hidden unit t_k is recomputed inline per k (5 FMAs) and o[64] is static-indexed.
__global__ __launch_bounds__(256, 2) void enc_full_kernel(
    const float* __restrict__ x,
    const float* __restrict__ w1, const float* __restrict__ b1,
    const float* __restrict__ w2, const float* __restrict__ b2,
    unsigned short* __restrict__ hbf)
{
  int v = blockIdx.x*256 + threadIdx.x;
  if (v >= NN) return;
  float in0[5];
  #pragma unroll
  for (int k=0;k<5;k++) in0[k] = x[(size_t)v*5 + k];
  float o[64];
  #pragma unroll
  for (int j=0;j<64;j++) o[j] = b2[j];
  #pragma unroll 4
  for (int k=0;k<64;k++){
    float tk = b1[k];
    #pragma unroll
    for (int kk=0;kk<5;kk++) tk = fmaf(in0[kk], w1[kk*H + k], tk);
    tk = relu_(tk);
    const float* wr = w2 + k*H;
    #pragma unroll
    for (int j=0;j<64;j++) o[j] = fmaf(tk, wr[j], o[j]);
  }
  unsigned int u[32];
  #pragma unroll
  for (int j=0;j<32;j++) u[j] = pkh_(relu_(o[2*j]), relu_(o[2*j+1]));
  uint4* dp = (uint4*)(hbf + (size_t)v*H);
  #pragma unroll
  for (int j=0;j<8;j++) dp[j] = *(uint4*)&u[4*j];
}

// ---------------- sharded in-degree counts + per-edge shard-rank ----------------
// Round-6: shard counts 8 ways by blockIdx&7 (line-contention fix; rank dropped
// below top-5 cutoff). Block b covers edges [b*1024,(b+1)*1024) -> fill derives
// sh = (e>>10)&7.
__global__ __launch_bounds__(256) void rank_kernel(const int* __restrict__ dst,
                                                   int* __restrict__ counts8,
                                                   int* __restrict__ rank)
{
  int t = blockIdx.x*256 + threadIdx.x;
  int e0 = t*4;
  int* cs = counts8 + (size_t)(blockIdx.x & (NSH-1))*NN;
  if (e0 + 3 < NE){
    int4 d4 = *(const int4*)(dst + e0);
    int r0 = atomicAdd(&cs[d4.x], 1);
    int r1 = atomicAdd(&cs[d4.y], 1);
    int r2 = atomicAdd(&cs[d4.z], 1);
    int r3 = atomicAdd(&cs[d4.w], 1);
    *(int4*)(rank + e0) = make_int4(r0, r1, r2, r3);
  } else {
    for (int e = e0; e < NE; ++e) rank[e] = atomicAdd(&cs[dst[e]], 1);
  }
}

// ---------------- scan phase 1: shuffle-based; sums 8 shard copies ----------------
__global__ __launch_bounds__(1024) void scan1_kernel(const int* __restrict__ counts8,
                                                     int* __restrict__ counts,
                                                     int* __restrict__ pfx,
                                                     int* __restrict__ row_excl,
                                                     int* __restrict__ part)
{
  __shared__ int wsum[16];
  int tid = threadIdx.x;
  int i = blockIdx.x*1024 + tid;
  int v = 0;
  if (i < NN){
    int run = 0;
    #pragma unroll
    for (int sh=0; sh<NSH; sh++){
      int c = counts8[(size_t)sh*NN + i];
      pfx[(size_t)sh*NN + i] = run;
      run += c;
    }
    v = run;
    counts[i] = run;
  }
  int lane = tid & 63, w = tid >> 6;
  int s = v;                       // inclusive wave scan
  #pragma unroll
  for (int off=1; off<64; off<<=1){
    int t = __shfl_up(s, off, 64);
    if (lane >= off) s += t;
  }
  if (lane == 63) wsum[w] = s;
  __syncthreads();
  if (w == 0 && lane < 16){
    int t = wsum[lane];
    #pragma unroll
    for (int off=1; off<16; off<<=1){
      int u = __shfl_up(t, off, 64);
      if (lane >= off) t += u;
    }
    wsum[lane] = t;                // inclusive wave partials
  }
  __syncthreads();
  int base = (w > 0) ? wsum[w-1] : 0;
  int incl = base + s;
  if (i < NN) row_excl[i] = incl - v;
  if (tid == 1023) part[blockIdx.x] = incl;
}

// ---------------- scan phase 2 ----------------
__global__ __launch_bounds__(128) void scan2_kernel(int* __restrict__ part, int nparts)
{
  __shared__ int buf[128];
  int tid = threadIdx.x;
  int v = (tid < nparts) ? part[tid] : 0;
  buf[tid] = v;
  __syncthreads();
  for (int off=1; off<128; off<<=1){
    int t = (tid >= off) ? buf[tid-off] : 0;
    __syncthreads();
    buf[tid] += t;
    __syncthreads();
  }
  if (tid < nparts) part[tid] = buf[tid] - v;
}

// ---------------- fill sorted edge records (no atomics; shard-rank precomputed) ------
__global__ __launch_bounds__(256) void fill_kernel(
    const int* __restrict__ src, const int* __restrict__ dst,
    const int* __restrict__ row_excl, const int* __restrict__ part,
    const int* __restrict__ pfx,
    const int* __restrict__ rank, int2* __restrict__ sedge)
{
  int e = blockIdx.x*256 + threadIdx.x;
  if (e >= NE) return;
  int d = dst[e];
  int sh = (e >> 10) & (NSH-1);
  int p = row_excl[d] + part[d >> 10] + pfx[(size_t)sh*NN + d] + rank[e];
  sedge[p] = make_int2(src[e], d);
}

// ---------------- plain count (fallback path only) ----------------
__global__ __launch_bounds__(256) void count_kernel(const int* __restrict__ dst,
                                                    int* __restrict__ counts)
{
  int e = blockIdx.x*256 + threadIdx.x;
  if (e < NE) atomicAdd(&counts[dst[e]], 1);
}

// ---------------- preswizzle ALL weights to fp16 MFMA B-fragment order -------------
// frag index within a K x N weight: idx = ((kb*4+quad)*N + col)*8 + j,  k = kb*32+quad*8+j
// layout (ushort elems): [0,24576) uw1p | [24576,36864) uw2p |
// [36864,61440) pprojp | [61440,65536) ow1p | [65536,77824) msgw2p   (all fp16)
__global__ __launch_bounds__(256) void prep_all_kernel(
    const float* __restrict__ uw1, const float* __restrict__ uw2,
    const float* __restrict__ mw1, const float* __restrict__ mw2,
    const float* __restrict__ ow1, unsigned short* __restrict__ wp)
{
  int i = blockIdx.x*256 + threadIdx.x;
  if (i >= 77824) return;
  float val;
  if (i < 24576){
    int l = i / 8192, r = i & 8191;
    int j = r & 7, col = (r >> 3) & 63, g = r >> 9;
    int k = (g >> 2)*32 + (g & 3)*8 + j;
    val = uw1[(size_t)l*8192 + k*64 + col];
  } else if (i < 36864){
    int t = i - 24576; int l = t / 4096, r = t & 4095;
    int j = r & 7, col = (r >> 3) & 63, g = r >> 9;
    int k = (g >> 2)*32 + (g & 3)*8 + j;
    val = uw2[(size_t)l*4096 + k*64 + col];
  } else if (i < 61440){
    int t = i - 36864; int l = t / 8192, r = t & 8191;
    int j = r & 7, col = (r >> 3) & 127, g = r >> 10;
    int k = (g >> 2)*32 + (g & 3)*8 + j;
    val = mw1[(size_t)l*8192 + ((col >> 6)*64 + k)*64 + (col & 63)];
  } else if (i < 65536){
    int r = i - 61440;
    int j = r & 7, col = (r >> 3) & 63, g = r >> 9;
    int k = (g >> 2)*32 + (g & 3)*8 + j;
    val = ow1[k*64 + col];
  } else {
    int t = i - 65536; int l = t / 4096, r = t & 4095;
    int j = r & 7, col = (r >> 3) & 63, g = r >> 9;
    int k = (g >> 2)*32 + (g & 3)*8 + j;
    val = mw2[(size_t)l*4096 + k*64 + col];
  }
  wp[i] = f2h_(val);
}

// ---------------- MFMA message kernel v14: EB=256 + atomic boundary flush ----------
// Round-7: (a) EB 128->256 halves block count -> halves per-block fixed costs
// (B-fragment loads, staging, barriers, boundary runs). (b) head/tail runs flush
// via global_atomic_pk_add_f16 into zeroed aggh -> bnd_fixup kernel eliminated.
// Masks kept in named scalars m0..m3 (runtime-indexed array would go to scratch).
__global__ __launch_bounds__(MBT, 4) void msg_mfma_kernel(
    const unsigned short* __restrict__ P,
    const unsigned short* __restrict__ w2p,
    const float* __restrict__ b2,
    const int2* __restrict__ sedge,
    unsigned short* __restrict__ aggh)
{
  __shared__ unsigned short mlds[64*MSTRIDE];
  __shared__ int2 sdl[EB];
  const int tid  = threadIdx.x;
  const int wave = tid >> 6, lane = tid & 63, quad = lane >> 4, c = lane & 15;

  // XCD-contiguous swizzle
  int bid = blockIdx.x;
  int ng = gridDim.x >> 3;
  int lb = (bid < (ng << 3)) ? ((bid & 7)*ng + (bid >> 3)) : bid;
  const int base = lb*EB;

  if (tid < EB){
    int p = base + tid;
    int2 sv = make_int2(0, -1);
    if (p < NE) sv = sedge[p];
    sdl[tid] = sv;
  }

  // B fragments (fp16) + bias
  f16x8 bfr[4][2];
  #pragma unroll
  for (int n=0;n<4;n++)
    #pragma unroll
    for (int kb=0;kb<2;kb++)
      bfr[n][kb] = *(const f16x8*)(w2p + (((kb*4 + quad)*64 + n*16 + c) << 3));
  float bv[4];
  #pragma unroll
  for (int n=0;n<4;n++) bv[n] = b2[n*16 + c];

  __syncthreads();

  const int ebase = wave*64;
  #pragma unroll
  for (int t=0;t<4;t++){
    int2 sd = sdl[ebase + t*16 + c];
    int s = sd.x;
    int d = sd.y < 0 ? 0 : sd.y;
    const unsigned short* p1 = P + (size_t)s*128 + quad*8;
    const unsigned short* p2 = P + (size_t)d*128 + 64 + quad*8;
    f16x8 af[2];
    #pragma unroll
    for (int kb=0;kb<2;kb++){
      uint4 u1 = *(const uint4*)(p1 + kb*32);
      uint4 u2 = *(const uint4*)(p2 + kb*32);
      union { unsigned int u[4]; f16x8 v; } A;
      A.u[0] = addrelu2_(u1.x, u2.x);
      A.u[1] = addrelu2_(u1.y, u2.y);
      A.u[2] = addrelu2_(u1.z, u2.z);
      A.u[3] = addrelu2_(u1.w, u2.w);
      af[kb] = A.v;
    }

    f32x4 acc4[4];
    #pragma unroll
    for (int n=0;n<4;n++) acc4[n] = (f32x4){0.f, 0.f, 0.f, 0.f};
    #pragma unroll
    for (int n=0;n<4;n++){
      acc4[n] = __builtin_amdgcn_mfma_f32_16x16x32_f16(af[0], bfr[n][0], acc4[n], 0, 0, 0);
      acc4[n] = __builtin_amdgcn_mfma_f32_16x16x32_f16(af[1], bfr[n][1], acc4[n], 0, 0, 0);
    }

    int e0 = ebase + t*16 + quad*4;
    #pragma unroll
    for (int n=0;n<4;n++){
      int ch = n*16 + c;
      float v0 = relu_(acc4[n][0] + bv[n]);
      float v1 = relu_(acc4[n][1] + bv[n]);
      float v2 = relu_(acc4[n][2] + bv[n]);
      float v3 = relu_(acc4[n][3] + bv[n]);
      *(unsigned int*)&mlds[ch*MSTRIDE + e0]     = pkh_(v0, v1);
      *(unsigned int*)&mlds[ch*MSTRIDE + e0 + 2] = pkh_(v2, v3);
    }
  }
  __syncthreads();

  // ---- mask-driven segmented reduce (single owner per run) ----
  // wave g owns runs STARTING in [g*64,(g+1)*64). Boundary bitmasks in 4 named
  // 64-bit scalars (uniform across wave); scalar ctz per RUN; counted sum loop.
  {
    const int g = wave;
    const int ch = lane;
    unsigned long long m0, m1, m2, m3;
    {
      int dA, dAm;
      dA = sdl[lane].y;        dAm = (lane == 0) ? ~dA : sdl[lane-1].y;
      m0 = __ballot(dA != dAm);
      dA = sdl[64+lane].y;     dAm = sdl[63+lane].y;
      m1 = __ballot(dA != dAm);
      dA = sdl[128+lane].y;    dAm = sdl[127+lane].y;
      m2 = __ballot(dA != dAm);
      dA = sdl[192+lane].y;    dAm = sdl[191+lane].y;
      m3 = __ballot(dA != dAm);
    }

    auto isb = [&](int p)->bool{
      unsigned long long mm = (p < 64) ? m0 : (p < 128) ? m1 : (p < 192) ? m2 : m3;
      return (mm >> (p & 63)) & 1ull;
    };
    auto nextb = [&](int p)->int{
      int q = p + 1;
      if (q < 64){
        unsigned long long t = m0 >> q;
        if (t) return q + __builtin_ctzll(t);
        q = 64;
      }
      if (q < 128){
        unsigned long long t = m1 >> (q - 64);
        if (t) return q + __builtin_ctzll(t);
        q = 128;
      }
      if (q < 192){
        unsigned long long t = m2 >> (q - 128);
        if (t) return q + __builtin_ctzll(t);
        q = 192;
      }
      if (q < 256){
        unsigned long long t = m3 >> (q - 192);
        if (t) return q + __builtin_ctzll(t);
      }
      return EB;
    };

    int r = g*64;
    if (g > 0 && !isb(r)) r = nextb(r);   // skip run continuing from prev window
    const int myEnd = (g+1)*64;
    while (r < myEnd){
      int nb = nextb(r);                  // run end (exclusive), may cross windows
      int cur = sdl[r].y;
      float s2 = 0.f;
      for (int rr = r; rr < nb; ++rr)
        s2 += h2f_(mlds[ch*MSTRIDE + rr]);
      if (cur >= 0){
        bool bnd = (r == 0) || (nb == EB);   // may span block boundary
        if (bnd){
          // pack pairs (even,odd channel) and pk-atomic-add into zeroed aggh
          float other = __shfl_xor(s2, 1);
          if ((ch & 1) == 0){
            unsigned int pk = pkh_(s2, other);
            atomic_pk_f16_(aggh + (size_t)cur*H + ch, pk);
          }
        } else {
          aggh[(size_t)cur*H + ch] = f2h_(s2);
        }
      }
      r = nb;
    }
  }
}

// ---------------- fused node-side layer kernel (fp16 MFMA, fp16 agg in) -------------
// mode 0 (l=0,1): h' = relu-MLP2([h||agg/deg]) -> hout(fp16) ; P_next = h'@W3 (+b3 top) -> Pout
// mode 1 (l=2):   h' as above; out = 2pi*sigmoid(relu(h'@ow1+b3)@ow2+ob2) -> outp
// mode 2 (pproj only): P = hbf@W3 (+b3 top) -> Pout
// Zero-degree nodes: aggh zeroed per layer -> agg=0; invd=0 masking retained.
__global__ __launch_bounds__(256) void node_fused_kernel(
    const unsigned short* __restrict__ hbf,
    const unsigned short* __restrict__ aggh, const int* __restrict__ counts,
    const unsigned short* __restrict__ uw1p, const float* __restrict__ ub1,
    const unsigned short* __restrict__ uw2p, const float* __restrict__ ub2,
    const unsigned short* __restrict__ w3p,  const float* __restrict__ b3,
    const float* __restrict__ ow2, const float* __restrict__ ob2,
    unsigned short* __restrict__ hout,
    unsigned short* __restrict__ Pout,
    float* __restrict__ outp,
    int mode)
{
  __shared__ __align__(16) unsigned short act[64*72];
  __shared__ __align__(16) unsigned short pst[64*136];
  const int tid = threadIdx.x, wave = tid >> 6, lane = tid & 63;
  const int quad = lane >> 4, c = lane & 15;
  const int vb = blockIdx.x*64;
  int myv = vb + wave*16 + c;
  int vld = myv < NN ? myv : NN-1;

  if (mode != 2){
    int cntv = counts[vld];
    float invf = (cntv > 0) ? (1.0f / (float)cntv) : 0.0f;   // masks zero-degree
    f16x2 invd2; invd2[0] = (_Float16)invf; invd2[1] = (_Float16)invf;
    f16x8 a1[4];
    a1[0] = *(const f16x8*)(hbf + (size_t)vld*H + quad*8);
    a1[1] = *(const f16x8*)(hbf + (size_t)vld*H + 32 + quad*8);
    #pragma unroll
    for (int kb2=0; kb2<2; kb2++){
      uint4 u = *(const uint4*)(aggh + (size_t)vld*H + kb2*32 + quad*8);
      union { unsigned int u[4]; f16x8 v; } A;
      A.u[0] = mulpk_(u.x, invd2);
      A.u[1] = mulpk_(u.y, invd2);
      A.u[2] = mulpk_(u.z, invd2);
      A.u[3] = mulpk_(u.w, invd2);
      a1[2+kb2] = A.v;
    }
    f32x4 acc1[4];
    #pragma unroll
    for (int n=0;n<4;n++) acc1[n] = (f32x4){0.f,0.f,0.f,0.f};
    #pragma unroll
    for (int n=0;n<4;n++){
      #pragma unroll
      for (int kb=0;kb<4;kb++){
        f16x8 b = *(const f16x8*)(uw1p + (((kb*4 + quad)*64 + n*16 + c) << 3));
        acc1[n] = __builtin_amdgcn_mfma_f32_16x16x32_f16(a1[kb], b, acc1[n], 0, 0, 0);
      }
    }
    #pragma unroll
    for (int n=0;n<4;n++){
      float bb = ub1[n*16 + c];
      #pragma unroll
      for (int r=0;r<4;r++)
        act[(wave*16 + quad*4 + r)*72 + n*16 + c] = f2h_(relu_(acc1[n][r] + bb));
    }

    f16x8 a2[2];
    a2[0] = *(const f16x8*)(act + (wave*16 + c)*72 + quad*8);
    a2[1] = *(const f16x8*)(act + (wave*16 + c)*72 + 32 + quad*8);
    f32x4 acc2[4];
    #pragma unroll
    for (int n=0;n<4;n++) acc2[n] = (f32x4){0.f,0.f,0.f,0.f};
    #pragma unroll
    for (int n=0;n<4;n++){
      #pragma unroll
      for (int kb=0;kb<2;kb++){
        f16x8 b = *(const f16x8*)(uw2p + (((kb*4 + quad)*64 + n*16 + c) << 3));
        acc2[n] = __builtin_amdgcn_mfma_f32_16x16x32_f16(a2[kb], b, acc2[n], 0, 0, 0);
      }
    }
    #pragma unroll
    for (int n=0;n<4;n++){
      float bb = ub2[n*16 + c];
      #pragma unroll
      for (int r=0;r<4;r++)
        act[(wave*16 + quad*4 + r)*72 + n*16 + c] = f2h_(relu_(acc2[n][r] + bb));
    }
  }

  f16x8 a3[2];
  if (mode == 2){
    a3[0] = *(const f16x8*)(hbf + (size_t)vld*H + quad*8);
    a3[1] = *(const f16x8*)(hbf + (size_t)vld*H + 32 + quad*8);
  } else {
    a3[0] = *(const f16x8*)(act + (wave*16 + c)*72 + quad*8);
    a3[1] = *(const f16x8*)(act + (wave*16 + c)*72 + 32 + quad*8);
  }

  if (mode == 1){
    f32x4 acc3[4];
    #pragma unroll
    for (int n=0;n<4;n++) acc3[n] = (f32x4){0.f,0.f,0.f,0.f};
    #pragma unroll
    for (int n=0;n<4;n++){
      #pragma unroll
      for (int kb=0;kb<2;kb++){
        f16x8 b = *(const f16x8*)(w3p + (((kb*4 + quad)*64 + n*16 + c) << 3));
        acc3[n] = __builtin_amdgcn_mfma_f32_16x16x32_f16(a3[kb], b, acc3[n], 0, 0, 0);
      }
    }
    #pragma unroll
    for (int n=0;n<4;n++){
      float bb = b3[n*16 + c];
      #pragma unroll
      for (int r=0;r<4;r++)
        act[(wave*16 + quad*4 + r)*72 + n*16 + c] = f2h_(relu_(acc3[n][r] + bb));
    }
  } else {
    f32x4 acc3[8];
    #pragma unroll
    for (int n=0;n<8;n++) acc3[n] = (f32x4){0.f,0.f,0.f,0.f};
    #pragma unroll
    for (int n=0;n<8;n++){
      #pragma unroll
      for (int kb=0;kb<2;kb++){
        f16x8 b = *(const f16x8*)(w3p + (((kb*4 + quad)*128 + n*16 + c) << 3));
        acc3[n] = __builtin_amdgcn_mfma_f32_16x16x32_f16(a3[kb], b, acc3[n], 0, 0, 0);
      }
    }
    #pragma unroll
    for (int n=0;n<8;n++){
      int ch = n*16 + c;
      float bb = (ch >= 64) ? b3[ch - 64] : 0.0f;
      #pragma unroll
      for (int r=0;r<4;r++)
        pst[(wave*16 + quad*4 + r)*136 + ch] = f2h_(acc3[n][r] + bb);
    }
  }

  __syncthreads();

  if (mode == 0){
    #pragma unroll
    for (int rr=0; rr<2; rr++){
      int idx = tid + rr*256;
      int node = idx >> 3, ko = (idx & 7)*8;
      int v = vb + node;
      if (v < NN) *(uint4*)(hout + (size_t)v*H + ko) = *(const uint4*)(act + node*72 + ko);
    }
  }
  if (mode == 0 || mode == 2){
    #pragma unroll
    for (int rr=0; rr<4; rr++){
      int idx = tid + rr*256;
      int node = idx >> 4, cho = (idx & 15)*8;
      int v = vb + node;
      if (v < NN) *(uint4*)(Pout + (size_t)v*128 + cho) = *(const uint4*)(pst + node*136 + cho);
    }
  }
  if (mode == 1){
    if (tid < 192){
      int node = tid / 3;
      int v = vb + node;
      if (v < NN){
        int cm = tid - node*3;
        float s = ob2[cm];
        #pragma unroll 8
        for (int k=0;k<64;k++)
          s = fmaf(h2f_(act[node*72 + k]), ow2[k*3 + cm], s);
        outp[(size_t)v*3 + cm] = 6.283185307179586f / (1.0f + __expf(-s));
      }
    }
  }
}

// ================= legacy fallback kernels (known correct; small ws) =================
__global__ __launch_bounds__(256) void enc_kernel_legacy(
    const float* __restrict__ x,
    const float* __restrict__ w1, const float* __restrict__ b1,
    const float* __restrict__ w2, const float* __restrict__ b2,
    float* __restrict__ h)
{
  int v = blockIdx.x*256 + threadIdx.x;
  if (v >= NN) return;
  float in0[5];
  #pragma unroll
  for (int k=0;k<5;k++) in0[k] = x[v*5+k];
  float hid[H];
  #pragma unroll
  for (int j=0;j<H;j++) hid[j] = b1[j];
  #pragma unroll
  for (int k=0;k<5;k++){
    #pragma unroll
    for (int j=0;j<H;j++) hid[j] = fmaf(in0[k], w1[k*H+j], hid[j]);
  }
  float o[H];
  #pragma unroll
  for (int j=0;j<H;j++) o[j] = b2[j];
  #pragma unroll
  for (int k=0;k<H;k++){
    float hk = relu_(hid[k]);
    #pragma unroll
    for (int j=0;j<H;j++) o[j] = fmaf(hk, w2[k*H+j], o[j]);
  }
  float4* hw = (float4*)(h + (size_t)v*H);
  #pragma unroll
  for (int j4=0;j4<H/4;j4++){
    float4 t;
    t.x = relu_(o[4*j4+0]); t.y = relu_(o[4*j4+1]);
    t.z = relu_(o[4*j4+2]); t.w = relu_(o[4*j4+3]);
    hw[j4] = t;
  }
}

__global__ __launch_bounds__(256) void msg_kernel_atomic(
    const float* __restrict__ h,
    const int* __restrict__ src, const int* __restrict__ dst,
    const float* __restrict__ w1, const float* __restrict__ b1,
    const float* __restrict__ w2, const float* __restrict__ b2,
    float* __restrict__ agg)
{
  int e = blockIdx.x*256 + threadIdx.x;
  if (e >= NE) return;
  int s = src[e], d = dst[e];
  const float4* hs = (const float4*)(h + (size_t)s*H);
  const float4* hd = (const float4*)(h + (size_t)d*H);
  float hid[H];
  #pragma unroll
  for (int j=0;j<H;j++) hid[j] = b1[j];
  #pragma unroll 4
  for (int k4=0;k4<16;k4++){
    float4 a = hs[k4];
    const float* wr = w1 + (size_t)(4*k4)*H;
    #pragma unroll
    for (int j=0;j<H;j++) hid[j] = fmaf(a.x, wr[j], hid[j]);
    #pragma unroll
    for (int j=0;j<H;j++) hid[j] = fmaf(a.y, wr[H+j], hid[j]);
    #pragma unroll
    for (int j=0;j<H;j++) hid[j] = fmaf(a.z, wr[2*H+j], hid[j]);
    #pragma unroll
    for (int j=0;j<H;j++) hid[j] = fmaf(a.w, wr[3*H+j], hid[j]);
  }
  #pragma unroll 4
  for (int k4=0;k4<16;k4++){
    float4 a = hd[k4];
    const float* wr = w1 + (size_t)(64 + 4*k4)*H;
    #pragma unroll
    for (int j=0;j<H;j++) hid[j] = fmaf(a.x, wr[j], hid[j]);
    #pragma unroll
    for (int j=0;j<H;j++) hid[j] = fmaf(a.y, wr[H+j], hid[j]);
    #pragma unroll
    for (int j=0;j<H;j++) hid[j] = fmaf(a.z, wr[2*H+j], hid[j]);
    #pragma unroll
    for (int j=0;j<H;j++) hid[j] = fmaf(a.w, wr[3*H+j], hid[j]);
  }
  float o[H];
  #pragma unroll
  for (int j=0;j<H;j++) o[j] = b2[j];
  #pragma unroll
  for (int k=0;k<H;k++){
    float hk = relu_(hid[k]);
    #pragma unroll
    for (int j=0;j<H;j++) o[j] = fmaf(hk, w2[k*H+j], o[j]);
  }
  float* arow = agg + (size_t)d*H;
  #pragma unroll
  for (int j=0;j<H;j++) atomicAdd(arow + j, relu_(o[j]));
}

__global__ __launch_bounds__(256) void div_kernel(float* __restrict__ agg,
                                                  const int* __restrict__ counts)
{
  int i = blockIdx.x*256 + threadIdx.x;
  if (i >= NN*H/4) return;
  int v = i / (H/4);
  float invd = 1.0f / fmaxf((float)counts[v], 1.0f);
  float4* a = (float4*)agg + i;
  float4 t = *a;
  t.x *= invd; t.y *= invd; t.z *= invd; t.w *= invd;
  *a = t;
}

__global__ __launch_bounds__(256) void upd_kernel_legacy(
    float* __restrict__ h, const float* __restrict__ agg,
    const float* __restrict__ w1, const float* __restrict__ b1,
    const float* __restrict__ w2, const float* __restrict__ b2)
{
  int v = blockIdx.x*256 + threadIdx.x;
  if (v >= NN) return;
  const float4* hv = (const float4*)(h + (size_t)v*H);
  const float4* av = (const float4*)(agg + (size_t)v*H);
  float hid[H];
  #pragma unroll
  for (int j=0;j<H;j++) hid[j] = b1[j];
  #pragma unroll 4
  for (int k4=0;k4<16;k4++){
    float4 a = hv[k4];
    const float* wr = w1 + (size_t)(4*k4)*H;
    #pragma unroll
    for (int j=0;j<H;j++) hid[j] = fmaf(a.x, wr[j], hid[j]);
    #pragma unroll
    for (int j=0;j<H;j++) hid[j] = fmaf(a.y, wr[H+j], hid[j]);
    #pragma unroll
    for (int j=0;j<H;j++) hid[j] = fmaf(a.z, wr[2*H+j], hid[j]);
    #pragma unroll
    for (int j=0;j<H;j++) hid[j] = fmaf(a.w, wr[3*H+j], hid[j]);
  }
  #pragma unroll 4
  for (int k4=0;k4<16;k4++){
    float4 a = av[k4];
    const float* wr = w1 + (size_t)(64 + 4*k4)*H;
    #pragma unroll
    for (int j=0;j<H;j++) hid[j] = fmaf(a.x, wr[j], hid[j]);
    #pragma unroll
    for (int j=0;j<H;j++) hid[j] = fmaf(a.y, wr[H+j], hid[j]);
    #pragma unroll
    for (int j=0;j<H;j++) hid[j] = fmaf(a.z, wr[2*H+j], hid[j]);
    #pragma unroll
    for (int j=0;j<H;j++) hid[j] = fmaf(a.w, wr[3*H+j], hid[j]);
  }
  float o[H];
  #pragma unroll
  for (int j=0;j<H;j++) o[j] = b2[j];
  #pragma unroll
  for (int k=0;k<H;k++){
    float hk = relu_(hid[k]);
    #pragma unroll
    for (int j=0;j<H;j++) o[j] = fmaf(hk, w2[k*H+j], o[j]);
  }
  float4* hw = (float4*)(h + (size_t)v*H);
  #pragma unroll
  for (int j4=0;j4<H/4;j4++){
    float4 t;
    t.x = relu_(o[4*j4+0]); t.y = relu_(o[4*j4+1]);
    t.z = relu_(o[4*j4+2]); t.w = relu_(o[4*j4+3]);
    hw[j4] = t;
  }
}

__global__ __launch_bounds__(256) void out_kernel2(
    const float* __restrict__ h,
    const float* __restrict__ w1, const float* __restrict__ b1,
    const float* __restrict__ w2, const float* __restrict__ b2,
    float* __restrict__ out)
{
  int v = blockIdx.x*256 + threadIdx.x;
  if (v >= NN) return;
  const float4* hv = (const float4*)(h + (size_t)v*H);
  float pr[3] = { b2[0], b2[1], b2[2] };
  #pragma unroll 1
  for (int half=0; half<2; half++){
    float o[32];
    #pragma unroll
    for (int j=0;j<32;j++) o[j] = b1[half*32 + j];
    #pragma unroll 4
    for (int k4=0;k4<16;k4++){
      float4 a = hv[k4];
      const float* wr = w1 + (4*k4)*H + half*32;
      fma32(o, a.x, wr); fma32(o, a.y, wr+H); fma32(o, a.z, wr+2*H); fma32(o, a.w, wr+3*H);
    }
    #pragma unroll
    for (int j=0;j<32;j++){
      float hk = relu_(o[j]);
      int k = half*32 + j;
      pr[0] = fmaf(hk, w2[k*3+0], pr[0]);
      pr[1] = fmaf(hk, w2[k*3+1], pr[1]);
      pr[2] = fmaf(hk, w2[k*3+2], pr[2]);
    }
  }
  #pragma unroll
  for (int c=0;c<3;c++)
    out[(size_t)v*3 + c] = 6.283185307179586f / (1.0f + __expf(-pr[c]));
}

// =====================================================================

extern "C" void kernel_launch(void* const* d_in, const int* in_sizes, int n_in,
                              void* d_out, int out_size, void* d_ws, size_t ws_size,
                              hipStream_t stream)
{
  const float* x      = (const float*)d_in[0];
  const int*   ei     = (const int*)  d_in[1];
  const float* enc_w1 = (const float*)d_in[2];
  const float* enc_b1 = (const float*)d_in[3];
  const float* enc_w2 = (const float*)d_in[4];
  const float* enc_b2 = (const float*)d_in[5];
  const float* msg_w1 = (const float*)d_in[6];
  const float* msg_b1 = (const float*)d_in[7];
  const float* msg_w2 = (const float*)d_in[8];
  const float* msg_b2 = (const float*)d_in[9];
  const float* upd_w1 = (const float*)d_in[10];
  const float* upd_b1 = (const float*)d_in[11];
  const float* upd_w2 = (const float*)d_in[12];
  const float* upd_b2 = (const float*)d_in[13];
  const float* out_w1 = (const float*)d_in[14];
  const float* out_b1 = (const float*)d_in[15];
  const float* out_w2 = (const float*)d_in[16];
  const float* out_b2 = (const float*)d_in[17];
  float* out = (float*)d_out;

  const int* srcp = ei;
  const int* dstp = ei + NE;

  const int nodeBlocks  = (NN + 255)/256;
  const int edgeBlocks  = (NE + 255)/256;
  const int rankBlocks  = (NE + 1023)/1024;          // 4 edges/thread
  const int msgBlocks   = (NE + EB - 1)/EB;          // 3907
  const int scanBlocks  = (NN + 1023)/1024;
  const int fusedBlocks = (NN + 63)/64;              // 1563

  // ---- workspace layout ----
  char* wp_ = (char*)d_ws;
  auto take = [&wp_](size_t bytes) -> char* {
    char* r = wp_;
    wp_ += (bytes + 255) & ~(size_t)255;
    return r;
  };
  unsigned short* hbf = (unsigned short*)take((size_t)NN*H*sizeof(unsigned short)); // 12.8 MB fp16
  unsigned short* P   = (unsigned short*)take((size_t)NN*128*sizeof(unsigned short)); // 25.6 MB fp16
  unsigned short* aggh= (unsigned short*)take((size_t)NN*H*sizeof(unsigned short)); // 12.8 MB fp16
  int* counts         = (int*)take((size_t)NN*sizeof(int));
  int* counts8        = (int*)take((size_t)NSH*NN*sizeof(int));                    // 3.2 MB
  int* pfx            = (int*)take((size_t)NSH*NN*sizeof(int));                    // 3.2 MB
  int* row_excl       = (int*)take((size_t)NN*sizeof(int));
  int* part           = (int*)take(1024);
  int* rank           = (int*)take((size_t)NE*sizeof(int));                        // 4 MB
  int2* sedge         = (int2*)take((size_t)NE*sizeof(int2));                      // 8 MB
  unsigned short* wpz = (unsigned short*)take((size_t)77824*sizeof(unsigned short));
  size_t need = (size_t)(wp_ - (char*)d_ws);

  // preswizzled-weight offsets (ushort elements)
  const size_t UW1 = 0, UW2 = 24576, PPJ = 36864, OW1 = 61440, MW2 = 65536;

  if (ws_size >= need) {
    (void)hipMemsetAsync(counts8, 0, (size_t)NSH*NN*sizeof(int), stream);

    enc_full_kernel<<<nodeBlocks, 256, 0, stream>>>(x, enc_w1, enc_b1, enc_w2, enc_b2, hbf);

    rank_kernel<<<rankBlocks, 256, 0, stream>>>(dstp, counts8, rank);
    scan1_kernel<<<scanBlocks, 1024, 0, stream>>>(counts8, counts, pfx, row_excl, part);
    scan2_kernel<<<1, 128, 0, stream>>>(part, scanBlocks);
    fill_kernel<<<edgeBlocks, 256, 0, stream>>>(srcp, dstp, row_excl, part, pfx, rank, sedge);
    prep_all_kernel<<<(77824 + 255)/256, 256, 0, stream>>>(upd_w1, upd_w2, msg_w1, msg_w2, out_w1, wpz);

    // layer-0 P projection (mode 2)
    node_fused_kernel<<<fusedBlocks, 256, 0, stream>>>(
        hbf, aggh, counts,
        nullptr, nullptr, nullptr, nullptr,
        wpz + PPJ, msg_b1, nullptr, nullptr,
        nullptr, P, nullptr, 2);

    for (int l=0; l<3; l++){
      // aggh zeroed per layer: boundary runs accumulate via pk_add_f16 atomics
      (void)hipMemsetAsync(aggh, 0, (size_t)NN*H*sizeof(unsigned short), stream);
      msg_mfma_kernel<<<msgBlocks, MBT, 0, stream>>>(P, wpz + MW2 + (size_t)l*4096,
          msg_b2 + (size_t)l*H, sedge, aggh);
      if (l < 2){
        node_fused_kernel<<<fusedBlocks, 256, 0, stream>>>(
            hbf, aggh, counts,
            wpz + UW1 + (size_t)l*8192, upd_b1 + (size_t)l*H,
            wpz + UW2 + (size_t)l*4096, upd_b2 + (size_t)l*H,
            wpz + PPJ + (size_t)(l+1)*8192, msg_b1 + (size_t)(l+1)*H,
            nullptr, nullptr,
            hbf, P, nullptr, 0);
      } else {
        node_fused_kernel<<<fusedBlocks, 256, 0, stream>>>(
            hbf, aggh, counts,
            wpz + UW1 + (size_t)l*8192, upd_b1 + (size_t)l*H,
            wpz + UW2 + (size_t)l*4096, upd_b2 + (size_t)l*H,
            wpz + OW1, out_b1,
            out_w2, out_b2,
            nullptr, nullptr, out, 1);
      }
    }
  } else {
    // ======== fallback: legacy atomic path (fits in ~52 MB) ========
    char* fp = (char*)d_ws;
    float* fh   = (float*)fp;  fp += (size_t)NN*H*sizeof(float);
    float* fagg = (float*)fp;  fp += (size_t)NN*H*sizeof(float);
    int* fcnt   = (int*)fp;

    (void)hipMemsetAsync(fcnt, 0, NN*sizeof(int), stream);
    enc_kernel_legacy<<<nodeBlocks, 256, 0, stream>>>(x, enc_w1, enc_b1, enc_w2, enc_b2, fh);
    count_kernel<<<edgeBlocks, 256, 0, stream>>>(dstp, fcnt);
    for (int l=0; l<3; l++){
      (void)hipMemsetAsync(fagg, 0, (size_t)NN*H*sizeof(float), stream);
      msg_kernel_atomic<<<edgeBlocks, 256, 0, stream>>>(fh, srcp, dstp,
          msg_w1 + (size_t)l*128*H, msg_b1 + (size_t)l*H,
          msg_w2 + (size_t)l*H*H,   msg_b2 + (size_t)l*H, fagg);
      div_kernel<<<(NN*H/4 + 255)/256, 256, 0, stream>>>(fagg, fcnt);
      upd_kernel_legacy<<<nodeBlocks, 256, 0, stream>>>(fh, fagg,
          upd_w1 + (size_t)l*128*H, upd_b1 + (size_t)l*H,
          upd_w2 + (size_t)l*H*H,   upd_b2 + (size_t)l*H);
    }
    out_kernel2<<<nodeBlocks, 256, 0, stream>>>(fh, out_w1, out_b1, out_w2, out_b2, out);
  }
}

// Round 9
// 375.366 us; speedup vs baseline: 1.0702x; 1.0698x over previous
//
#include <hip/hip_runtime.h>
#include <math.h>

#define NN 100000
#define NE 1000000
#define H 64
#define EB 128        // edges per msg block (round-8: revert 256->128; EB=256 cost
                      // occupancy 50->32% and +25% bank conflicts, net worse)
#define MBT 256       // msg block threads (4 waves; each wave does 32 edges)
#define MSTRIDE 130   // ushorts per channel row in msg LDS (128 edges + 2 pad)
#define NSH 8         // atomic shards for rank (round-6: line-contention fix)

typedef _Float16 f16x8 __attribute__((ext_vector_type(8)));
typedef _Float16 f16x2 __attribute__((ext_vector_type(2)));
typedef float f32x4  __attribute__((ext_vector_type(4)));

static __device__ __forceinline__ float relu_(float x){ return fmaxf(x, 0.0f); }

static __device__ __forceinline__ unsigned short f2h_(float f){
  union { _Float16 h; unsigned short u; } x; x.h = (_Float16)f; return x.u;
}
static __device__ __forceinline__ float h2f_(unsigned short u){
  union { unsigned short u; _Float16 h; } x; x.u = u; return (float)x.h;
}
static __device__ __forceinline__ unsigned int pkh_(float lo, float hi){
  union { f16x2 v; unsigned int u; } x;
  x.v[0] = (_Float16)lo; x.v[1] = (_Float16)hi;
  return x.u;
}
// packed fp16: relu(a + b) on 2 lanes (lowers to v_pk_add_f16 + v_pk_max_f16)
static __device__ __forceinline__ unsigned int addrelu2_(unsigned int a, unsigned int b){
  union { unsigned int u; f16x2 v; } x, y, r;
  x.u = a; y.u = b;
  f16x2 s = x.v + y.v;
  _Float16 z = (_Float16)0.0f;
  r.v[0] = (s[0] > z) ? s[0] : z;
  r.v[1] = (s[1] > z) ? s[1] : z;
  return r.u;
}
// packed fp16 multiply by broadcast scale (v_pk_mul_f16)
static __device__ __forceinline__ unsigned int mulpk_(unsigned int a, f16x2 s){
  union { unsigned int u; f16x2 v; } x;
  x.u = a; x.v = x.v * s;
  return x.u;
}
// fire-and-forget packed fp16 atomic add (gfx90a+/gfx950)
static __device__ __forceinline__ void atomic_pk_f16_(unsigned short* p, unsigned int pk){
  asm volatile("global_atomic_pk_add_f16 %0, %1, off" :: "v"(p), "v"(pk) : "memory");
}
static __device__ __forceinline__ void fma32(float* o, float a, const float* wr){
  #pragma unroll
  for (int j=0;j<32;j++) o[j] = fmaf(a, wr[j], o[j]);
}

// ---------------- fused encoder: hbf(fp16) = relu(relu(x@w1+b1)@w2+b2) ----------------
// Round 0 fix: hidden t[64] with runtime index -> scratch (51 MB traffic). Now the
// hidden unit t_k is recomputed inline per k (5 FMAs) and o[64] is static-indexed.
__global__ __launch_bounds__(256, 2) void enc_full_kernel(
    const float* __restrict__ x,
    const float* __restrict__ w1, const float* __restrict__ b1,
    const float* __restrict__ w2, const float* __restrict__ b2,
    unsigned short* __restrict__ hbf)
{
  int v = blockIdx.x*256 + threadIdx.x;
  if (v >= NN) return;
  float in0[5];
  #pragma unroll
  for (int k=0;k<5;k++) in0[k] = x[(size_t)v*5 + k];
  float o[64];
  #pragma unroll
  for (int j=0;j<64;j++) o[j] = b2[j];
  #pragma unroll 4
  for (int k=0;k<64;k++){
    float tk = b1[k];
    #pragma unroll
    for (int kk=0;kk<5;kk++) tk = fmaf(in0[kk], w1[kk*H + k], tk);
    tk = relu_(tk);
    const float* wr = w2 + k*H;
    #pragma unroll
    for (int j=0;j<64;j++) o[j] = fmaf(tk, wr[j], o[j]);
  }
  unsigned int u[32];
  #pragma unroll
  for (int j=0;j<32;j++) u[j] = pkh_(relu_(o[2*j]), relu_(o[2*j+1]));
  uint4* dp = (uint4*)(hbf + (size_t)v*H);
  #pragma unroll
  for (int j=0;j<8;j++) dp[j] = *(uint4*)&u[4*j];
}

// ---------------- sharded in-degree counts + per-edge shard-rank ----------------
// Round-6: shard counts 8 ways by blockIdx&7 (line-contention fix). Block b covers
// edges [b*1024,(b+1)*1024) -> fill derives sh = (e>>10)&7.
__global__ __launch_bounds__(256) void rank_kernel(const int* __restrict__ dst,
                                                   int* __restrict__ counts8,
                                                   int* __restrict__ rank)
{
  int t = blockIdx.x*256 + threadIdx.x;
  int e0 = t*4;
  int* cs = counts8 + (size_t)(blockIdx.x & (NSH-1))*NN;
  if (e0 + 3 < NE){
    int4 d4 = *(const int4*)(dst + e0);
    int r0 = atomicAdd(&cs[d4.x], 1);
    int r1 = atomicAdd(&cs[d4.y], 1);
    int r2 = atomicAdd(&cs[d4.z], 1);
    int r3 = atomicAdd(&cs[d4.w], 1);
    *(int4*)(rank + e0) = make_int4(r0, r1, r2, r3);
  } else {
    for (int e = e0; e < NE; ++e) rank[e] = atomicAdd(&cs[dst[e]], 1);
  }
}

// ---------------- scan phase 1: shuffle-based; sums 8 shard copies ----------------
__global__ __launch_bounds__(1024) void scan1_kernel(const int* __restrict__ counts8,
                                                     int* __restrict__ counts,
                                                     int* __restrict__ pfx,
                                                     int* __restrict__ row_excl,
                                                     int* __restrict__ part)
{
  __shared__ int wsum[16];
  int tid = threadIdx.x;
  int i = blockIdx.x*1024 + tid;
  int v = 0;
  if (i < NN){
    int run = 0;
    #pragma unroll
    for (int sh=0; sh<NSH; sh++){
      int c = counts8[(size_t)sh*NN + i];
      pfx[(size_t)sh*NN + i] = run;
      run += c;
    }
    v = run;
    counts[i] = run;
  }
  int lane = tid & 63, w = tid >> 6;
  int s = v;                       // inclusive wave scan
  #pragma unroll
  for (int off=1; off<64; off<<=1){
    int t = __shfl_up(s, off, 64);
    if (lane >= off) s += t;
  }
  if (lane == 63) wsum[w] = s;
  __syncthreads();
  if (w == 0 && lane < 16){
    int t = wsum[lane];
    #pragma unroll
    for (int off=1; off<16; off<<=1){
      int u = __shfl_up(t, off, 64);
      if (lane >= off) t += u;
    }
    wsum[lane] = t;                // inclusive wave partials
  }
  __syncthreads();
  int base = (w > 0) ? wsum[w-1] : 0;
  int incl = base + s;
  if (i < NN) row_excl[i] = incl - v;
  if (tid == 1023) part[blockIdx.x] = incl;
}

// ---------------- scan phase 2 ----------------
__global__ __launch_bounds__(128) void scan2_kernel(int* __restrict__ part, int nparts)
{
  __shared__ int buf[128];
  int tid = threadIdx.x;
  int v = (tid < nparts) ? part[tid] : 0;
  buf[tid] = v;
  __syncthreads();
  for (int off=1; off<128; off<<=1){
    int t = (tid >= off) ? buf[tid-off] : 0;
    __syncthreads();
    buf[tid] += t;
    __syncthreads();
  }
  if (tid < nparts) part[tid] = buf[tid] - v;
}

// ---------------- fill sorted edge records (no atomics; shard-rank precomputed) ------
__global__ __launch_bounds__(256) void fill_kernel(
    const int* __restrict__ src, const int* __restrict__ dst,
    const int* __restrict__ row_excl, const int* __restrict__ part,
    const int* __restrict__ pfx,
    const int* __restrict__ rank, int2* __restrict__ sedge)
{
  int e = blockIdx.x*256 + threadIdx.x;
  if (e >= NE) return;
  int d = dst[e];
  int sh = (e >> 10) & (NSH-1);
  int p = row_excl[d] + part[d >> 10] + pfx[(size_t)sh*NN + d] + rank[e];
  sedge[p] = make_int2(src[e], d);
}

// ---------------- plain count (fallback path only) ----------------
__global__ __launch_bounds__(256) void count_kernel(const int* __restrict__ dst,
                                                    int* __restrict__ counts)
{
  int e = blockIdx.x*256 + threadIdx.x;
  if (e < NE) atomicAdd(&counts[dst[e]], 1);
}

// ---------------- preswizzle ALL weights to fp16 MFMA B-fragment order -------------
// frag index within a K x N weight: idx = ((kb*4+quad)*N + col)*8 + j,  k = kb*32+quad*8+j
// layout (ushort elems): [0,24576) uw1p | [24576,36864) uw2p |
// [36864,61440) pprojp | [61440,65536) ow1p | [65536,77824) msgw2p   (all fp16)
__global__ __launch_bounds__(256) void prep_all_kernel(
    const float* __restrict__ uw1, const float* __restrict__ uw2,
    const float* __restrict__ mw1, const float* __restrict__ mw2,
    const float* __restrict__ ow1, unsigned short* __restrict__ wp)
{
  int i = blockIdx.x*256 + threadIdx.x;
  if (i >= 77824) return;
  float val;
  if (i < 24576){
    int l = i / 8192, r = i & 8191;
    int j = r & 7, col = (r >> 3) & 63, g = r >> 9;
    int k = (g >> 2)*32 + (g & 3)*8 + j;
    val = uw1[(size_t)l*8192 + k*64 + col];
  } else if (i < 36864){
    int t = i - 24576; int l = t / 4096, r = t & 4095;
    int j = r & 7, col = (r >> 3) & 63, g = r >> 9;
    int k = (g >> 2)*32 + (g & 3)*8 + j;
    val = uw2[(size_t)l*4096 + k*64 + col];
  } else if (i < 61440){
    int t = i - 36864; int l = t / 8192, r = t & 8191;
    int j = r & 7, col = (r >> 3) & 127, g = r >> 10;
    int k = (g >> 2)*32 + (g & 3)*8 + j;
    val = mw1[(size_t)l*8192 + ((col >> 6)*64 + k)*64 + (col & 63)];
  } else if (i < 65536){
    int r = i - 61440;
    int j = r & 7, col = (r >> 3) & 63, g = r >> 9;
    int k = (g >> 2)*32 + (g & 3)*8 + j;
    val = ow1[k*64 + col];
  } else {
    int t = i - 65536; int l = t / 4096, r = t & 4095;
    int j = r & 7, col = (r >> 3) & 63, g = r >> 9;
    int k = (g >> 2)*32 + (g & 3)*8 + j;
    val = mw2[(size_t)l*4096 + k*64 + col];
  }
  wp[i] = f2h_(val);
}

// ---------------- MFMA message kernel v15: EB=128 (round-5 proven structure) +
// atomic boundary flush (round-7/8 proven: bnd_fixup kernel eliminated).
// Mask-driven walk: boundary bitmask via __ballot, scalar ctz per RUN, counted
// pipelineable sum loop. Interior runs: plain stores (exclusive owner). Runs
// touching block edges: global_atomic_pk_add_f16 into per-layer-zeroed aggh. ----
__global__ __launch_bounds__(MBT, 4) void msg_mfma_kernel(
    const unsigned short* __restrict__ P,
    const unsigned short* __restrict__ w2p,
    const float* __restrict__ b2,
    const int2* __restrict__ sedge,
    unsigned short* __restrict__ aggh)
{
  __shared__ unsigned short mlds[64*MSTRIDE];
  __shared__ int2 sdl[EB];
  const int tid  = threadIdx.x;
  const int wave = tid >> 6, lane = tid & 63, quad = lane >> 4, c = lane & 15;

  // XCD-contiguous swizzle
  int bid = blockIdx.x;
  int ng = gridDim.x >> 3;
  int lb = (bid < (ng << 3)) ? ((bid & 7)*ng + (bid >> 3)) : bid;
  const int base = lb*EB;

  if (tid < EB){
    int p = base + tid;
    int2 sv = make_int2(0, -1);
    if (p < NE) sv = sedge[p];
    sdl[tid] = sv;
  }

  // B fragments (fp16) + bias
  f16x8 bfr[4][2];
  #pragma unroll
  for (int n=0;n<4;n++)
    #pragma unroll
    for (int kb=0;kb<2;kb++)
      bfr[n][kb] = *(const f16x8*)(w2p + (((kb*4 + quad)*64 + n*16 + c) << 3));
  float bv[4];
  #pragma unroll
  for (int n=0;n<4;n++) bv[n] = b2[n*16 + c];

  __syncthreads();

  const int ebase = wave*32;
  #pragma unroll
  for (int t=0;t<2;t++){
    int2 sd = sdl[ebase + t*16 + c];
    int s = sd.x;
    int d = sd.y < 0 ? 0 : sd.y;
    const unsigned short* p1 = P + (size_t)s*128 + quad*8;
    const unsigned short* p2 = P + (size_t)d*128 + 64 + quad*8;
    f16x8 af[2];
    #pragma unroll
    for (int kb=0;kb<2;kb++){
      uint4 u1 = *(const uint4*)(p1 + kb*32);
      uint4 u2 = *(const uint4*)(p2 + kb*32);
      union { unsigned int u[4]; f16x8 v; } A;
      A.u[0] = addrelu2_(u1.x, u2.x);
      A.u[1] = addrelu2_(u1.y, u2.y);
      A.u[2] = addrelu2_(u1.z, u2.z);
      A.u[3] = addrelu2_(u1.w, u2.w);
      af[kb] = A.v;
    }

    f32x4 acc4[4];
    #pragma unroll
    for (int n=0;n<4;n++) acc4[n] = (f32x4){0.f, 0.f, 0.f, 0.f};
    #pragma unroll
    for (int n=0;n<4;n++){
      acc4[n] = __builtin_amdgcn_mfma_f32_16x16x32_f16(af[0], bfr[n][0], acc4[n], 0, 0, 0);
      acc4[n] = __builtin_amdgcn_mfma_f32_16x16x32_f16(af[1], bfr[n][1], acc4[n], 0, 0, 0);
    }

    int e0 = ebase + t*16 + quad*4;
    #pragma unroll
    for (int n=0;n<4;n++){
      int ch = n*16 + c;
      float v0 = relu_(acc4[n][0] + bv[n]);
      float v1 = relu_(acc4[n][1] + bv[n]);
      float v2 = relu_(acc4[n][2] + bv[n]);
      float v3 = relu_(acc4[n][3] + bv[n]);
      *(unsigned int*)&mlds[ch*MSTRIDE + e0]     = pkh_(v0, v1);
      *(unsigned int*)&mlds[ch*MSTRIDE + e0 + 2] = pkh_(v2, v3);
    }
  }
  __syncthreads();

  // ---- mask-driven segmented reduce (single owner per run) ----
  {
    const int g = wave;
    const int ch = lane;
    int dA  = sdl[lane].y;
    int dAm = (lane == 0) ? ~dA : sdl[lane-1].y;     // force boundary at 0
    unsigned long long m0 = __ballot(dA != dAm);
    int dB  = sdl[64+lane].y;
    int dBm = sdl[63+lane].y;
    unsigned long long m1 = __ballot(dB != dBm);

    auto isb = [&](int p)->bool{
      return (p < 64) ? ((m0 >> p) & 1ull) : ((m1 >> (p-64)) & 1ull);
    };
    auto nextb = [&](int p)->int{
      int q = p + 1;
      if (q < 64){
        unsigned long long t = m0 >> q;
        if (t) return q + __builtin_ctzll(t);
        q = 64;
      }
      int off = q - 64;
      if (off < 64){
        unsigned long long t = m1 >> off;
        if (t) return q + __builtin_ctzll(t);
      }
      return EB;
    };

    int r = g*32;
    if (g > 0 && !isb(r)) r = nextb(r);   // skip run continuing from prev window
    const int myEnd = (g+1)*32;
    while (r < myEnd){
      int nb = nextb(r);                  // run end (exclusive), may cross windows
      int cur = sdl[r].y;
      float s2 = 0.f;
      for (int rr = r; rr < nb; ++rr)
        s2 += h2f_(mlds[ch*MSTRIDE + rr]);
      if (cur >= 0){
        bool bnd = (r == 0) || (nb == EB);   // may span block boundary
        if (bnd){
          // pack pairs (even,odd channel) and pk-atomic-add into zeroed aggh
          float other = __shfl_xor(s2, 1);
          if ((ch & 1) == 0){
            unsigned int pk = pkh_(s2, other);
            atomic_pk_f16_(aggh + (size_t)cur*H + ch, pk);
          }
        } else {
          aggh[(size_t)cur*H + ch] = f2h_(s2);
        }
      }
      r = nb;
    }
  }
}

// ---------------- fused node-side layer kernel (fp16 MFMA, fp16 agg in) -------------
// mode 0 (l=0,1): h' = relu-MLP2([h||agg/deg]) -> hout(fp16) ; P_next = h'@W3 (+b3 top) -> Pout
// mode 1 (l=2):   h' as above; out = 2pi*sigmoid(relu(h'@ow1+b3)@ow2+ob2) -> outp
// mode 2 (pproj only): P = hbf@W3 (+b3 top) -> Pout
// Zero-degree nodes: aggh zeroed per layer -> agg=0; invd=0 masking retained.
__global__ __launch_bounds__(256) void node_fused_kernel(
    const unsigned short* __restrict__ hbf,
    const unsigned short* __restrict__ aggh, const int* __restrict__ counts,
    const unsigned short* __restrict__ uw1p, const float* __restrict__ ub1,
    const unsigned short* __restrict__ uw2p, const float* __restrict__ ub2,
    const unsigned short* __restrict__ w3p,  const float* __restrict__ b3,
    const float* __restrict__ ow2, const float* __restrict__ ob2,
    unsigned short* __restrict__ hout,
    unsigned short* __restrict__ Pout,
    float* __restrict__ outp,
    int mode)
{
  __shared__ __align__(16) unsigned short act[64*72];
  __shared__ __align__(16) unsigned short pst[64*136];
  const int tid = threadIdx.x, wave = tid >> 6, lane = tid & 63;
  const int quad = lane >> 4, c = lane & 15;
  const int vb = blockIdx.x*64;
  int myv = vb + wave*16 + c;
  int vld = myv < NN ? myv : NN-1;

  if (mode != 2){
    int cntv = counts[vld];
    float invf = (cntv > 0) ? (1.0f / (float)cntv) : 0.0f;   // masks zero-degree
    f16x2 invd2; invd2[0] = (_Float16)invf; invd2[1] = (_Float16)invf;
    f16x8 a1[4];
    a1[0] = *(const f16x8*)(hbf + (size_t)vld*H + quad*8);
    a1[1] = *(const f16x8*)(hbf + (size_t)vld*H + 32 + quad*8);
    #pragma unroll
    for (int kb2=0; kb2<2; kb2++){
      uint4 u = *(const uint4*)(aggh + (size_t)vld*H + kb2*32 + quad*8);
      union { unsigned int u[4]; f16x8 v; } A;
      A.u[0] = mulpk_(u.x, invd2);
      A.u[1] = mulpk_(u.y, invd2);
      A.u[2] = mulpk_(u.z, invd2);
      A.u[3] = mulpk_(u.w, invd2);
      a1[2+kb2] = A.v;
    }
    f32x4 acc1[4];
    #pragma unroll
    for (int n=0;n<4;n++) acc1[n] = (f32x4){0.f,0.f,0.f,0.f};
    #pragma unroll
    for (int n=0;n<4;n++){
      #pragma unroll
      for (int kb=0;kb<4;kb++){
        f16x8 b = *(const f16x8*)(uw1p + (((kb*4 + quad)*64 + n*16 + c) << 3));
        acc1[n] = __builtin_amdgcn_mfma_f32_16x16x32_f16(a1[kb], b, acc1[n], 0, 0, 0);
      }
    }
    #pragma unroll
    for (int n=0;n<4;n++){
      float bb = ub1[n*16 + c];
      #pragma unroll
      for (int r=0;r<4;r++)
        act[(wave*16 + quad*4 + r)*72 + n*16 + c] = f2h_(relu_(acc1[n][r] + bb));
    }

    f16x8 a2[2];
    a2[0] = *(const f16x8*)(act + (wave*16 + c)*72 + quad*8);
    a2[1] = *(const f16x8*)(act + (wave*16 + c)*72 + 32 + quad*8);
    f32x4 acc2[4];
    #pragma unroll
    for (int n=0;n<4;n++) acc2[n] = (f32x4){0.f,0.f,0.f,0.f};
    #pragma unroll
    for (int n=0;n<4;n++){
      #pragma unroll
      for (int kb=0;kb<2;kb++){
        f16x8 b = *(const f16x8*)(uw2p + (((kb*4 + quad)*64 + n*16 + c) << 3));
        acc2[n] = __builtin_amdgcn_mfma_f32_16x16x32_f16(a2[kb], b, acc2[n], 0, 0, 0);
      }
    }
    #pragma unroll
    for (int n=0;n<4;n++){
      float bb = ub2[n*16 + c];
      #pragma unroll
      for (int r=0;r<4;r++)
        act[(wave*16 + quad*4 + r)*72 + n*16 + c] = f2h_(relu_(acc2[n][r] + bb));
    }
  }

  f16x8 a3[2];
  if (mode == 2){
    a3[0] = *(const f16x8*)(hbf + (size_t)vld*H + quad*8);
    a3[1] = *(const f16x8*)(hbf + (size_t)vld*H + 32 + quad*8);
  } else {
    a3[0] = *(const f16x8*)(act + (wave*16 + c)*72 + quad*8);
    a3[1] = *(const f16x8*)(act + (wave*16 + c)*72 + 32 + quad*8);
  }

  if (mode == 1){
    f32x4 acc3[4];
    #pragma unroll
    for (int n=0;n<4;n++) acc3[n] = (f32x4){0.f,0.f,0.f,0.f};
    #pragma unroll
    for (int n=0;n<4;n++){
      #pragma unroll
      for (int kb=0;kb<2;kb++){
        f16x8 b = *(const f16x8*)(w3p + (((kb*4 + quad)*64 + n*16 + c) << 3));
        acc3[n] = __builtin_amdgcn_mfma_f32_16x16x32_f16(a3[kb], b, acc3[n], 0, 0, 0);
      }
    }
    #pragma unroll
    for (int n=0;n<4;n++){
      float bb = b3[n*16 + c];
      #pragma unroll
      for (int r=0;r<4;r++)
        act[(wave*16 + quad*4 + r)*72 + n*16 + c] = f2h_(relu_(acc3[n][r] + bb));
    }
  } else {
    f32x4 acc3[8];
    #pragma unroll
    for (int n=0;n<8;n++) acc3[n] = (f32x4){0.f,0.f,0.f,0.f};
    #pragma unroll
    for (int n=0;n<8;n++){
      #pragma unroll
      for (int kb=0;kb<2;kb++){
        f16x8 b = *(const f16x8*)(w3p + (((kb*4 + quad)*128 + n*16 + c) << 3));
        acc3[n] = __builtin_amdgcn_mfma_f32_16x16x32_f16(a3[kb], b, acc3[n], 0, 0, 0);
      }
    }
    #pragma unroll
    for (int n=0;n<8;n++){
      int ch = n*16 + c;
      float bb = (ch >= 64) ? b3[ch - 64] : 0.0f;
      #pragma unroll
      for (int r=0;r<4;r++)
        pst[(wave*16 + quad*4 + r)*136 + ch] = f2h_(acc3[n][r] + bb);
    }
  }

  __syncthreads();

  if (mode == 0){
    #pragma unroll
    for (int rr=0; rr<2; rr++){
      int idx = tid + rr*256;
      int node = idx >> 3, ko = (idx & 7)*8;
      int v = vb + node;
      if (v < NN) *(uint4*)(hout + (size_t)v*H + ko) = *(const uint4*)(act + node*72 + ko);
    }
  }
  if (mode == 0 || mode == 2){
    #pragma unroll
    for (int rr=0; rr<4; rr++){
      int idx = tid + rr*256;
      int node = idx >> 4, cho = (idx & 15)*8;
      int v = vb + node;
      if (v < NN) *(uint4*)(Pout + (size_t)v*128 + cho) = *(const uint4*)(pst + node*136 + cho);
    }
  }
  if (mode == 1){
    if (tid < 192){
      int node = tid / 3;
      int v = vb + node;
      if (v < NN){
        int cm = tid - node*3;
        float s = ob2[cm];
        #pragma unroll 8
        for (int k=0;k<64;k++)
          s = fmaf(h2f_(act[node*72 + k]), ow2[k*3 + cm], s);
        outp[(size_t)v*3 + cm] = 6.283185307179586f / (1.0f + __expf(-s));
      }
    }
  }
}

// ================= legacy fallback kernels (known correct; small ws) =================
__global__ __launch_bounds__(256) void enc_kernel_legacy(
    const float* __restrict__ x,
    const float* __restrict__ w1, const float* __restrict__ b1,
    const float* __restrict__ w2, const float* __restrict__ b2,
    float* __restrict__ h)
{
  int v = blockIdx.x*256 + threadIdx.x;
  if (v >= NN) return;
  float in0[5];
  #pragma unroll
  for (int k=0;k<5;k++) in0[k] = x[v*5+k];
  float hid[H];
  #pragma unroll
  for (int j=0;j<H;j++) hid[j] = b1[j];
  #pragma unroll
  for (int k=0;k<5;k++){
    #pragma unroll
    for (int j=0;j<H;j++) hid[j] = fmaf(in0[k], w1[k*H+j], hid[j]);
  }
  float o[H];
  #pragma unroll
  for (int j=0;j<H;j++) o[j] = b2[j];
  #pragma unroll
  for (int k=0;k<H;k++){
    float hk = relu_(hid[k]);
    #pragma unroll
    for (int j=0;j<H;j++) o[j] = fmaf(hk, w2[k*H+j], o[j]);
  }
  float4* hw = (float4*)(h + (size_t)v*H);
  #pragma unroll
  for (int j4=0;j4<H/4;j4++){
    float4 t;
    t.x = relu_(o[4*j4+0]); t.y = relu_(o[4*j4+1]);
    t.z = relu_(o[4*j4+2]); t.w = relu_(o[4*j4+3]);
    hw[j4] = t;
  }
}

__global__ __launch_bounds__(256) void msg_kernel_atomic(
    const float* __restrict__ h,
    const int* __restrict__ src, const int* __restrict__ dst,
    const float* __restrict__ w1, const float* __restrict__ b1,
    const float* __restrict__ w2, const float* __restrict__ b2,
    float* __restrict__ agg)
{
  int e = blockIdx.x*256 + threadIdx.x;
  if (e >= NE) return;
  int s = src[e], d = dst[e];
  const float4* hs = (const float4*)(h + (size_t)s*H);
  const float4* hd = (const float4*)(h + (size_t)d*H);
  float hid[H];
  #pragma unroll
  for (int j=0;j<H;j++) hid[j] = b1[j];
  #pragma unroll 4
  for (int k4=0;k4<16;k4++){
    float4 a = hs[k4];
    const float* wr = w1 + (size_t)(4*k4)*H;
    #pragma unroll
    for (int j=0;j<H;j++) hid[j] = fmaf(a.x, wr[j], hid[j]);
    #pragma unroll
    for (int j=0;j<H;j++) hid[j] = fmaf(a.y, wr[H+j], hid[j]);
    #pragma unroll
    for (int j=0;j<H;j++) hid[j] = fmaf(a.z, wr[2*H+j], hid[j]);
    #pragma unroll
    for (int j=0;j<H;j++) hid[j] = fmaf(a.w, wr[3*H+j], hid[j]);
  }
  #pragma unroll 4
  for (int k4=0;k4<16;k4++){
    float4 a = hd[k4];
    const float* wr = w1 + (size_t)(64 + 4*k4)*H;
    #pragma unroll
    for (int j=0;j<H;j++) hid[j] = fmaf(a.x, wr[j], hid[j]);
    #pragma unroll
    for (int j=0;j<H;j++) hid[j] = fmaf(a.y, wr[H+j], hid[j]);
    #pragma unroll
    for (int j=0;j<H;j++) hid[j] = fmaf(a.z, wr[2*H+j], hid[j]);
    #pragma unroll
    for (int j=0;j<H;j++) hid[j] = fmaf(a.w, wr[3*H+j], hid[j]);
  }
  float o[H];
  #pragma unroll
  for (int j=0;j<H;j++) o[j] = b2[j];
  #pragma unroll
  for (int k=0;k<H;k++){
    float hk = relu_(hid[k]);
    #pragma unroll
    for (int j=0;j<H;j++) o[j] = fmaf(hk, w2[k*H+j], o[j]);
  }
  float* arow = agg + (size_t)d*H;
  #pragma unroll
  for (int j=0;j<H;j++) atomicAdd(arow + j, relu_(o[j]));
}

__global__ __launch_bounds__(256) void div_kernel(float* __restrict__ agg,
                                                  const int* __restrict__ counts)
{
  int i = blockIdx.x*256 + threadIdx.x;
  if (i >= NN*H/4) return;
  int v = i / (H/4);
  float invd = 1.0f / fmaxf((float)counts[v], 1.0f);
  float4* a = (float4*)agg + i;
  float4 t = *a;
  t.x *= invd; t.y *= invd; t.z *= invd; t.w *= invd;
  *a = t;
}

__global__ __launch_bounds__(256) void upd_kernel_legacy(
    float* __restrict__ h, const float* __restrict__ agg,
    const float* __restrict__ w1, const float* __restrict__ b1,
    const float* __restrict__ w2, const float* __restrict__ b2)
{
  int v = blockIdx.x*256 + threadIdx.x;
  if (v >= NN) return;
  const float4* hv = (const float4*)(h + (size_t)v*H);
  const float4* av = (const float4*)(agg + (size_t)v*H);
  float hid[H];
  #pragma unroll
  for (int j=0;j<H;j++) hid[j] = b1[j];
  #pragma unroll 4
  for (int k4=0;k4<16;k4++){
    float4 a = hv[k4];
    const float* wr = w1 + (size_t)(4*k4)*H;
    #pragma unroll
    for (int j=0;j<H;j++) hid[j] = fmaf(a.x, wr[j], hid[j]);
    #pragma unroll
    for (int j=0;j<H;j++) hid[j] = fmaf(a.y, wr[H+j], hid[j]);
    #pragma unroll
    for (int j=0;j<H;j++) hid[j] = fmaf(a.z, wr[2*H+j], hid[j]);
    #pragma unroll
    for (int j=0;j<H;j++) hid[j] = fmaf(a.w, wr[3*H+j], hid[j]);
  }
  #pragma unroll 4
  for (int k4=0;k4<16;k4++){
    float4 a = av[k4];
    const float* wr = w1 + (size_t)(64 + 4*k4)*H;
    #pragma unroll
    for (int j=0;j<H;j++) hid[j] = fmaf(a.x, wr[j], hid[j]);
    #pragma unroll
    for (int j=0;j<H;j++) hid[j] = fmaf(a.y, wr[H+j], hid[j]);
    #pragma unroll
    for (int j=0;j<H;j++) hid[j] = fmaf(a.z, wr[2*H+j], hid[j]);
    #pragma unroll
    for (int j=0;j<H;j++) hid[j] = fmaf(a.w, wr[3*H+j], hid[j]);
  }
  float o[H];
  #pragma unroll
  for (int j=0;j<H;j++) o[j] = b2[j];
  #pragma unroll
  for (int k=0;k<H;k++){
    float hk = relu_(hid[k]);
    #pragma unroll
    for (int j=0;j<H;j++) o[j] = fmaf(hk, w2[k*H+j], o[j]);
  }
  float4* hw = (float4*)(h + (size_t)v*H);
  #pragma unroll
  for (int j4=0;j4<H/4;j4++){
    float4 t;
    t.x = relu_(o[4*j4+0]); t.y = relu_(o[4*j4+1]);
    t.z = relu_(o[4*j4+2]); t.w = relu_(o[4*j4+3]);
    hw[j4] = t;
  }
}

__global__ __launch_bounds__(256) void out_kernel2(
    const float* __restrict__ h,
    const float* __restrict__ w1, const float* __restrict__ b1,
    const float* __restrict__ w2, const float* __restrict__ b2,
    float* __restrict__ out)
{
  int v = blockIdx.x*256 + threadIdx.x;
  if (v >= NN) return;
  const float4* hv = (const float4*)(h + (size_t)v*H);
  float pr[3] = { b2[0], b2[1], b2[2] };
  #pragma unroll 1
  for (int half=0; half<2; half++){
    float o[32];
    #pragma unroll
    for (int j=0;j<32;j++) o[j] = b1[half*32 + j];
    #pragma unroll 4
    for (int k4=0;k4<16;k4++){
      float4 a = hv[k4];
      const float* wr = w1 + (4*k4)*H + half*32;
      fma32(o, a.x, wr); fma32(o, a.y, wr+H); fma32(o, a.z, wr+2*H); fma32(o, a.w, wr+3*H);
    }
    #pragma unroll
    for (int j=0;j<32;j++){
      float hk = relu_(o[j]);
      int k = half*32 + j;
      pr[0] = fmaf(hk, w2[k*3+0], pr[0]);
      pr[1] = fmaf(hk, w2[k*3+1], pr[1]);
      pr[2] = fmaf(hk, w2[k*3+2], pr[2]);
    }
  }
  #pragma unroll
  for (int c=0;c<3;c++)
    out[(size_t)v*3 + c] = 6.283185307179586f / (1.0f + __expf(-pr[c]));
}

// =====================================================================

extern "C" void kernel_launch(void* const* d_in, const int* in_sizes, int n_in,
                              void* d_out, int out_size, void* d_ws, size_t ws_size,
                              hipStream_t stream)
{
  const float* x      = (const float*)d_in[0];
  const int*   ei     = (const int*)  d_in[1];
  const float* enc_w1 = (const float*)d_in[2];
  const float* enc_b1 = (const float*)d_in[3];
  const float* enc_w2 = (const float*)d_in[4];
  const float* enc_b2 = (const float*)d_in[5];
  const float* msg_w1 = (const float*)d_in[6];
  const float* msg_b1 = (const float*)d_in[7];
  const float* msg_w2 = (const float*)d_in[8];
  const float* msg_b2 = (const float*)d_in[9];
  const float* upd_w1 = (const float*)d_in[10];
  const float* upd_b1 = (const float*)d_in[11];
  const float* upd_w2 = (const float*)d_in[12];
  const float* upd_b2 = (const float*)d_in[13];
  const float* out_w1 = (const float*)d_in[14];
  const float* out_b1 = (const float*)d_in[15];
  const float* out_w2 = (const float*)d_in[16];
  const float* out_b2 = (const float*)d_in[17];
  float* out = (float*)d_out;

  const int* srcp = ei;
  const int* dstp = ei + NE;

  const int nodeBlocks  = (NN + 255)/256;
  const int edgeBlocks  = (NE + 255)/256;
  const int rankBlocks  = (NE + 1023)/1024;          // 4 edges/thread
  const int msgBlocks   = (NE + EB - 1)/EB;          // 7813
  const int scanBlocks  = (NN + 1023)/1024;
  const int fusedBlocks = (NN + 63)/64;              // 1563

  // ---- workspace layout ----
  char* wp_ = (char*)d_ws;
  auto take = [&wp_](size_t bytes) -> char* {
    char* r = wp_;
    wp_ += (bytes + 255) & ~(size_t)255;
    return r;
  };
  unsigned short* hbf = (unsigned short*)take((size_t)NN*H*sizeof(unsigned short)); // 12.8 MB fp16
  unsigned short* P   = (unsigned short*)take((size_t)NN*128*sizeof(unsigned short)); // 25.6 MB fp16
  unsigned short* aggh= (unsigned short*)take((size_t)NN*H*sizeof(unsigned short)); // 12.8 MB fp16
  int* counts         = (int*)take((size_t)NN*sizeof(int));
  int* counts8        = (int*)take((size_t)NSH*NN*sizeof(int));                    // 3.2 MB
  int* pfx            = (int*)take((size_t)NSH*NN*sizeof(int));                    // 3.2 MB
  int* row_excl       = (int*)take((size_t)NN*sizeof(int));
  int* part           = (int*)take(1024);
  int* rank           = (int*)take((size_t)NE*sizeof(int));                        // 4 MB
  int2* sedge         = (int2*)take((size_t)NE*sizeof(int2));                      // 8 MB
  unsigned short* wpz = (unsigned short*)take((size_t)77824*sizeof(unsigned short));
  size_t need = (size_t)(wp_ - (char*)d_ws);

  // preswizzled-weight offsets (ushort elements)
  const size_t UW1 = 0, UW2 = 24576, PPJ = 36864, OW1 = 61440, MW2 = 65536;

  if (ws_size >= need) {
    (void)hipMemsetAsync(counts8, 0, (size_t)NSH*NN*sizeof(int), stream);

    enc_full_kernel<<<nodeBlocks, 256, 0, stream>>>(x, enc_w1, enc_b1, enc_w2, enc_b2, hbf);

    rank_kernel<<<rankBlocks, 256, 0, stream>>>(dstp, counts8, rank);
    scan1_kernel<<<scanBlocks, 1024, 0, stream>>>(counts8, counts, pfx, row_excl, part);
    scan2_kernel<<<1, 128, 0, stream>>>(part, scanBlocks);
    fill_kernel<<<edgeBlocks, 256, 0, stream>>>(srcp, dstp, row_excl, part, pfx, rank, sedge);
    prep_all_kernel<<<(77824 + 255)/256, 256, 0, stream>>>(upd_w1, upd_w2, msg_w1, msg_w2, out_w1, wpz);

    // layer-0 P projection (mode 2)
    node_fused_kernel<<<fusedBlocks, 256, 0, stream>>>(
        hbf, aggh, counts,
        nullptr, nullptr, nullptr, nullptr,
        wpz + PPJ, msg_b1, nullptr, nullptr,
        nullptr, P, nullptr, 2);

    for (int l=0; l<3; l++){
      // aggh zeroed per layer: boundary runs accumulate via pk_add_f16 atomics
      (void)hipMemsetAsync(aggh, 0, (size_t)NN*H*sizeof(unsigned short), stream);
      msg_mfma_kernel<<<msgBlocks, MBT, 0, stream>>>(P, wpz + MW2 + (size_t)l*4096,
          msg_b2 + (size_t)l*H, sedge, aggh);
      if (l < 2){
        node_fused_kernel<<<fusedBlocks, 256, 0, stream>>>(
            hbf, aggh, counts,
            wpz + UW1 + (size_t)l*8192, upd_b1 + (size_t)l*H,
            wpz + UW2 + (size_t)l*4096, upd_b2 + (size_t)l*H,
            wpz + PPJ + (size_t)(l+1)*8192, msg_b1 + (size_t)(l+1)*H,
            nullptr, nullptr,
            hbf, P, nullptr, 0);
      } else {
        node_fused_kernel<<<fusedBlocks, 256, 0, stream>>>(
            hbf, aggh, counts,
            wpz + UW1 + (size_t)l*8192, upd_b1 + (size_t)l*H,
            wpz + UW2 + (size_t)l*4096, upd_b2 + (size_t)l*H,
            wpz + OW1, out_b1,
            out_w2, out_b2,
            nullptr, nullptr, out, 1);
      }
    }
  } else {
    // ======== fallback: legacy atomic path (fits in ~52 MB) ========
    char* fp = (char*)d_ws;
    float* fh   = (float*)fp;  fp += (size_t)NN*H*sizeof(float);
    float* fagg = (float*)fp;  fp += (size_t)NN*H*sizeof(float);
    int* fcnt   = (int*)fp;

    (void)hipMemsetAsync(fcnt, 0, NN*sizeof(int), stream);
    enc_kernel_legacy<<<nodeBlocks, 256, 0, stream>>>(x, enc_w1, enc_b1, enc_w2, enc_b2, fh);
    count_kernel<<<edgeBlocks, 256, 0, stream>>>(dstp, fcnt);
    for (int l=0; l<3; l++){
      (void)hipMemsetAsync(fagg, 0, (size_t)NN*H*sizeof(float), stream);
      msg_kernel_atomic<<<edgeBlocks, 256, 0, stream>>>(fh, srcp, dstp,
          msg_w1 + (size_t)l*128*H, msg_b1 + (size_t)l*H,
          msg_w2 + (size_t)l*H*H,   msg_b2 + (size_t)l*H, fagg);
      div_kernel<<<(NN*H/4 + 255)/256, 256, 0, stream>>>(fagg, fcnt);
      upd_kernel_legacy<<<nodeBlocks, 256, 0, stream>>>(fh, fagg,
          upd_w1 + (size_t)l*128*H, upd_b1 + (size_t)l*H,
          upd_w2 + (size_t)l*H*H,   upd_b2 + (size_t)l*H);
    }
    out_kernel2<<<nodeBlocks, 256, 0, stream>>>(fh, out_w1, out_b1, out_w2, out_b2, out);
  }
}

// Round 11
// 366.802 us; speedup vs baseline: 1.0952x; 1.0233x over previous
//
#include <hip/hip_runtime.h>
#include <math.h>

#define NN 100000
#define NE 1000000
#define H 64
#define EB 128        // edges per msg block (round-8: EB=256 cost occupancy, reverted)
#define MBT 256       // msg block threads (4 waves; each wave does 32 edges)
#define MSTRIDE 130   // ushorts per channel row in msg LDS (128 edges + 2 pad)
#define NSH 8         // atomic shards for rank (round-6: line-contention fix)

typedef _Float16 f16x8 __attribute__((ext_vector_type(8)));
typedef _Float16 f16x2 __attribute__((ext_vector_type(2)));
typedef float f32x4  __attribute__((ext_vector_type(4)));

static __device__ __forceinline__ float relu_(float x){ return fmaxf(x, 0.0f); }

static __device__ __forceinline__ unsigned short f2h_(float f){
  union { _Float16 h; unsigned short u; } x; x.h = (_Float16)f; return x.u;
}
static __device__ __forceinline__ float h2f_(unsigned short u){
  union { unsigned short u; _Float16 h; } x; x.u = u; return (float)x.h;
}
static __device__ __forceinline__ unsigned int pkh_(float lo, float hi){
  union { f16x2 v; unsigned int u; } x;
  x.v[0] = (_Float16)lo; x.v[1] = (_Float16)hi;
  return x.u;
}
// packed fp16: relu(a + b) on 2 lanes (lowers to v_pk_add_f16 + v_pk_max_f16)
static __device__ __forceinline__ unsigned int addrelu2_(unsigned int a, unsigned int b){
  union { unsigned int u; f16x2 v; } x, y, r;
  x.u = a; y.u = b;
  f16x2 s = x.v + y.v;
  _Float16 z = (_Float16)0.0f;
  r.v[0] = (s[0] > z) ? s[0] : z;
  r.v[1] = (s[1] > z) ? s[1] : z;
  return r.u;
}
// packed fp16 multiply by broadcast scale (v_pk_mul_f16)
static __device__ __forceinline__ unsigned int mulpk_(unsigned int a, f16x2 s){
  union { unsigned int u; f16x2 v; } x;
  x.u = a; x.v = x.v * s;
  return x.u;
}
// fire-and-forget packed fp16 atomic add (gfx90a+/gfx950)
static __device__ __forceinline__ void atomic_pk_f16_(unsigned short* p, unsigned int pk){
  asm volatile("global_atomic_pk_add_f16 %0, %1, off" :: "v"(p), "v"(pk) : "memory");
}
static __device__ __forceinline__ void fma32(float* o, float a, const float* wr){
  #pragma unroll
  for (int j=0;j<32;j++) o[j] = fmaf(a, wr[j], o[j]);
}

// ---------------- fused encoder: hbf(fp16) = relu(relu(x@w1+b1)@w2+b2) ----------------
// Round 0 fix: hidden t[64] with runtime index -> scratch (51 MB traffic). Now the
// hidden unit t_k is recomputed inline per k (5 FMAs) and o[64] is static-indexed.
__global__ __launch_bounds__(256, 2) void enc_full_kernel(
    const float* __restrict__ x,
    const float* __restrict__ w1, const float* __restrict__ b1,
    const float* __restrict__ w2, const float* __restrict__ b2,
    unsigned short* __restrict__ hbf)
{
  int v = blockIdx.x*256 + threadIdx.x;
  if (v >= NN) return;
  float in0[5];
  #pragma unroll
  for (int k=0;k<5;k++) in0[k] = x[(size_t)v*5 + k];
  float o[64];
  #pragma unroll
  for (int j=0;j<64;j++) o[j] = b2[j];
  #pragma unroll 4
  for (int k=0;k<64;k++){
    float tk = b1[k];
    #pragma unroll
    for (int kk=0;kk<5;kk++) tk = fmaf(in0[kk], w1[kk*H + k], tk);
    tk = relu_(tk);
    const float* wr = w2 + k*H;
    #pragma unroll
    for (int j=0;j<64;j++) o[j] = fmaf(tk, wr[j], o[j]);
  }
  unsigned int u[32];
  #pragma unroll
  for (int j=0;j<32;j++) u[j] = pkh_(relu_(o[2*j]), relu_(o[2*j+1]));
  uint4* dp = (uint4*)(hbf + (size_t)v*H);
  #pragma unroll
  for (int j=0;j<8;j++) dp[j] = *(uint4*)&u[4*j];
}

// ---------------- sharded in-degree counts + per-edge shard-rank ----------------
// Round-6: shard counts 8 ways by blockIdx&7 (line-contention fix). Block b covers
// edges [b*1024,(b+1)*1024) -> fill derives sh = (e>>10)&7.
__global__ __launch_bounds__(256) void rank_kernel(const int* __restrict__ dst,
                                                   int* __restrict__ counts8,
                                                   int* __restrict__ rank)
{
  int t = blockIdx.x*256 + threadIdx.x;
  int e0 = t*4;
  int* cs = counts8 + (size_t)(blockIdx.x & (NSH-1))*NN;
  if (e0 + 3 < NE){
    int4 d4 = *(const int4*)(dst + e0);
    int r0 = atomicAdd(&cs[d4.x], 1);
    int r1 = atomicAdd(&cs[d4.y], 1);
    int r2 = atomicAdd(&cs[d4.z], 1);
    int r3 = atomicAdd(&cs[d4.w], 1);
    *(int4*)(rank + e0) = make_int4(r0, r1, r2, r3);
  } else {
    for (int e = e0; e < NE; ++e) rank[e] = atomicAdd(&cs[dst[e]], 1);
  }
}

// ---------------- scan phase 1: shuffle-based; sums 8 shard copies ----------------
__global__ __launch_bounds__(1024) void scan1_kernel(const int* __restrict__ counts8,
                                                     int* __restrict__ counts,
                                                     int* __restrict__ pfx,
                                                     int* __restrict__ row_excl,
                                                     int* __restrict__ part)
{
  __shared__ int wsum[16];
  int tid = threadIdx.x;
  int i = blockIdx.x*1024 + tid;
  int v = 0;
  if (i < NN){
    int run = 0;
    #pragma unroll
    for (int sh=0; sh<NSH; sh++){
      int c = counts8[(size_t)sh*NN + i];
      pfx[(size_t)sh*NN + i] = run;
      run += c;
    }
    v = run;
    counts[i] = run;
  }
  int lane = tid & 63, w = tid >> 6;
  int s = v;                       // inclusive wave scan
  #pragma unroll
  for (int off=1; off<64; off<<=1){
    int t = __shfl_up(s, off, 64);
    if (lane >= off) s += t;
  }
  if (lane == 63) wsum[w] = s;
  __syncthreads();
  if (w == 0 && lane < 16){
    int t = wsum[lane];
    #pragma unroll
    for (int off=1; off<16; off<<=1){
      int u = __shfl_up(t, off, 64);
      if (lane >= off) t += u;
    }
    wsum[lane] = t;                // inclusive wave partials
  }
  __syncthreads();
  int base = (w > 0) ? wsum[w-1] : 0;
  int incl = base + s;
  if (i < NN) row_excl[i] = incl - v;
  if (tid == 1023) part[blockIdx.x] = incl;
}

// ---------------- scan phase 2 ----------------
__global__ __launch_bounds__(128) void scan2_kernel(int* __restrict__ part, int nparts)
{
  __shared__ int buf[128];
  int tid = threadIdx.x;
  int v = (tid < nparts) ? part[tid] : 0;
  buf[tid] = v;
  __syncthreads();
  for (int off=1; off<128; off<<=1){
    int t = (tid >= off) ? buf[tid-off] : 0;
    __syncthreads();
    buf[tid] += t;
    __syncthreads();
  }
  if (tid < nparts) part[tid] = buf[tid] - v;
}

// ---------------- fill sorted edge records (no atomics; shard-rank precomputed) ------
__global__ __launch_bounds__(256) void fill_kernel(
    const int* __restrict__ src, const int* __restrict__ dst,
    const int* __restrict__ row_excl, const int* __restrict__ part,
    const int* __restrict__ pfx,
    const int* __restrict__ rank, int2* __restrict__ sedge)
{
  int e = blockIdx.x*256 + threadIdx.x;
  if (e >= NE) return;
  int d = dst[e];
  int sh = (e >> 10) & (NSH-1);
  int p = row_excl[d] + part[d >> 10] + pfx[(size_t)sh*NN + d] + rank[e];
  sedge[p] = make_int2(src[e], d);
}

// ---------------- plain count (fallback path only) ----------------
__global__ __launch_bounds__(256) void count_kernel(const int* __restrict__ dst,
                                                    int* __restrict__ counts)
{
  int e = blockIdx.x*256 + threadIdx.x;
  if (e < NE) atomicAdd(&counts[dst[e]], 1);
}

// ---------------- preswizzle ALL weights to fp16 MFMA B-fragment order -------------
// frag index within a K x N weight: idx = ((kb*4+quad)*N + col)*8 + j,  k = kb*32+quad*8+j
// layout (ushort elems): [0,24576) uw1p | [24576,36864) uw2p |
// [36864,61440) pprojp | [61440,65536) ow1p | [65536,77824) msgw2p   (all fp16)
__global__ __launch_bounds__(256) void prep_all_kernel(
    const float* __restrict__ uw1, const float* __restrict__ uw2,
    const float* __restrict__ mw1, const float* __restrict__ mw2,
    const float* __restrict__ ow1, unsigned short* __restrict__ wp)
{
  int i = blockIdx.x*256 + threadIdx.x;
  if (i >= 77824) return;
  float val;
  if (i < 24576){
    int l = i / 8192, r = i & 8191;
    int j = r & 7, col = (r >> 3) & 63, g = r >> 9;
    int k = (g >> 2)*32 + (g & 3)*8 + j;
    val = uw1[(size_t)l*8192 + k*64 + col];
  } else if (i < 36864){
    int t = i - 24576; int l = t / 4096, r = t & 4095;
    int j = r & 7, col = (r >> 3) & 63, g = r >> 9;
    int k = (g >> 2)*32 + (g & 3)*8 + j;
    val = uw2[(size_t)l*4096 + k*64 + col];
  } else if (i < 61440){
    int t = i - 36864; int l = t / 8192, r = t & 8191;
    int j = r & 7, col = (r >> 3) & 127, g = r >> 10;
    int k = (g >> 2)*32 + (g & 3)*8 + j;
    val = mw1[(size_t)l*8192 + ((col >> 6)*64 + k)*64 + (col & 63)];
  } else if (i < 65536){
    int r = i - 61440;
    int j = r & 7, col = (r >> 3) & 63, g = r >> 9;
    int k = (g >> 2)*32 + (g & 3)*8 + j;
    val = ow1[k*64 + col];
  } else {
    int t = i - 65536; int l = t / 4096, r = t & 4095;
    int j = r & 7, col = (r >> 3) & 63, g = r >> 9;
    int k = (g >> 2)*32 + (g & 3)*8 + j;
    val = mw2[(size_t)l*4096 + k*64 + col];
  }
  wp[i] = f2h_(val);
}

// ---------------- MFMA message kernel v15: EB=128 + atomic boundary flush ----------
// Mask-driven walk (round-4); int2 staging (round-5); pk-atomic boundary flush into
// per-layer-zeroed aggh (round-7/9) -- bnd_fixup kernel eliminated.
__global__ __launch_bounds__(MBT, 4) void msg_mfma_kernel(
    const unsigned short* __restrict__ P,
    const unsigned short* __restrict__ w2p,
    const float* __restrict__ b2,
    const int2* __restrict__ sedge,
    unsigned short* __restrict__ aggh)
{
  __shared__ unsigned short mlds[64*MSTRIDE];
  __shared__ int2 sdl[EB];
  const int tid  = threadIdx.x;
  const int wave = tid >> 6, lane = tid & 63, quad = lane >> 4, c = lane & 15;

  // XCD-contiguous swizzle
  int bid = blockIdx.x;
  int ng = gridDim.x >> 3;
  int lb = (bid < (ng << 3)) ? ((bid & 7)*ng + (bid >> 3)) : bid;
  const int base = lb*EB;

  if (tid < EB){
    int p = base + tid;
    int2 sv = make_int2(0, -1);
    if (p < NE) sv = sedge[p];
    sdl[tid] = sv;
  }

  // B fragments (fp16) + bias
  f16x8 bfr[4][2];
  #pragma unroll
  for (int n=0;n<4;n++)
    #pragma unroll
    for (int kb=0;kb<2;kb++)
      bfr[n][kb] = *(const f16x8*)(w2p + (((kb*4 + quad)*64 + n*16 + c) << 3));
  float bv[4];
  #pragma unroll
  for (int n=0;n<4;n++) bv[n] = b2[n*16 + c];

  __syncthreads();

  const int ebase = wave*32;
  #pragma unroll
  for (int t=0;t<2;t++){
    int2 sd = sdl[ebase + t*16 + c];
    int s = sd.x;
    int d = sd.y < 0 ? 0 : sd.y;
    const unsigned short* p1 = P + (size_t)s*128 + quad*8;
    const unsigned short* p2 = P + (size_t)d*128 + 64 + quad*8;
    f16x8 af[2];
    #pragma unroll
    for (int kb=0;kb<2;kb++){
      uint4 u1 = *(const uint4*)(p1 + kb*32);
      uint4 u2 = *(const uint4*)(p2 + kb*32);
      union { unsigned int u[4]; f16x8 v; } A;
      A.u[0] = addrelu2_(u1.x, u2.x);
      A.u[1] = addrelu2_(u1.y, u2.y);
      A.u[2] = addrelu2_(u1.z, u2.z);
      A.u[3] = addrelu2_(u1.w, u2.w);
      af[kb] = A.v;
    }

    f32x4 acc4[4];
    #pragma unroll
    for (int n=0;n<4;n++) acc4[n] = (f32x4){0.f, 0.f, 0.f, 0.f};
    #pragma unroll
    for (int n=0;n<4;n++){
      acc4[n] = __builtin_amdgcn_mfma_f32_16x16x32_f16(af[0], bfr[n][0], acc4[n], 0, 0, 0);
      acc4[n] = __builtin_amdgcn_mfma_f32_16x16x32_f16(af[1], bfr[n][1], acc4[n], 0, 0, 0);
    }

    int e0 = ebase + t*16 + quad*4;
    #pragma unroll
    for (int n=0;n<4;n++){
      int ch = n*16 + c;
      float v0 = relu_(acc4[n][0] + bv[n]);
      float v1 = relu_(acc4[n][1] + bv[n]);
      float v2 = relu_(acc4[n][2] + bv[n]);
      float v3 = relu_(acc4[n][3] + bv[n]);
      *(unsigned int*)&mlds[ch*MSTRIDE + e0]     = pkh_(v0, v1);
      *(unsigned int*)&mlds[ch*MSTRIDE + e0 + 2] = pkh_(v2, v3);
    }
  }
  __syncthreads();

  // ---- mask-driven segmented reduce (single owner per run) ----
  {
    const int g = wave;
    const int ch = lane;
    int dA  = sdl[lane].y;
    int dAm = (lane == 0) ? ~dA : sdl[lane-1].y;     // force boundary at 0
    unsigned long long m0 = __ballot(dA != dAm);
    int dB  = sdl[64+lane].y;
    int dBm = sdl[63+lane].y;
    unsigned long long m1 = __ballot(dB != dBm);

    auto isb = [&](int p)->bool{
      return (p < 64) ? ((m0 >> p) & 1ull) : ((m1 >> (p-64)) & 1ull);
    };
    auto nextb = [&](int p)->int{
      int q = p + 1;
      if (q < 64){
        unsigned long long t = m0 >> q;
        if (t) return q + __builtin_ctzll(t);
        q = 64;
      }
      int off = q - 64;
      if (off < 64){
        unsigned long long t = m1 >> off;
        if (t) return q + __builtin_ctzll(t);
      }
      return EB;
    };

    int r = g*32;
    if (g > 0 && !isb(r)) r = nextb(r);   // skip run continuing from prev window
    const int myEnd = (g+1)*32;
    while (r < myEnd){
      int nb = nextb(r);                  // run end (exclusive), may cross windows
      int cur = sdl[r].y;
      float s2 = 0.f;
      for (int rr = r; rr < nb; ++rr)
        s2 += h2f_(mlds[ch*MSTRIDE + rr]);
      if (cur >= 0){
        bool bnd = (r == 0) || (nb == EB);   // may span block boundary
        if (bnd){
          // pack pairs (even,odd channel) and pk-atomic-add into zeroed aggh
          float other = __shfl_xor(s2, 1);
          if ((ch & 1) == 0){
            unsigned int pk = pkh_(s2, other);
            atomic_pk_f16_(aggh + (size_t)cur*H + ch, pk);
          }
        } else {
          aggh[(size_t)cur*H + ch] = f2h_(s2);
        }
      }
      r = nb;
    }
  }
}

// ---------------- fused node-side layer kernel (fp16 MFMA, fp16 agg in) -------------
// Round-9/10: 64-thread / 16-node blocks (was 256/64). The old 1563-block grid at
// 26.6KB LDS was FULLY co-resident (~6 blocks/CU x 256 CU) -> no block queue to
// hide global-load latency. 6250 one-wave blocks at 6.7KB LDS give the scheduler
// a continuous stream. Round-10: __syncthreads retained before the output copies
// (free for 1-wave blocks; guarantees LDS write->read ordering).
// mode 0 (l=0,1): h' = relu-MLP2([h||agg/deg]) -> hout ; P_next = h'@W3 -> Pout
// mode 1 (l=2):   h' as above; out = 2pi*sigmoid(relu(h'@ow1+b3)@ow2+ob2)
// mode 2: P = hbf@W3 (+b3 top) -> Pout
__global__ __launch_bounds__(64) void node_fused_kernel(
    const unsigned short* __restrict__ hbf,
    const unsigned short* __restrict__ aggh, const int* __restrict__ counts,
    const unsigned short* __restrict__ uw1p, const float* __restrict__ ub1,
    const unsigned short* __restrict__ uw2p, const float* __restrict__ ub2,
    const unsigned short* __restrict__ w3p,  const float* __restrict__ b3,
    const float* __restrict__ ow2, const float* __restrict__ ob2,
    unsigned short* __restrict__ hout,
    unsigned short* __restrict__ Pout,
    float* __restrict__ outp,
    int mode)
{
  __shared__ __align__(16) unsigned short act[16*72];
  __shared__ __align__(16) unsigned short pst[16*136];
  const int lane = threadIdx.x;
  const int quad = lane >> 4, c = lane & 15;
  const int vb = blockIdx.x*16;
  int myv = vb + c;
  int vld = myv < NN ? myv : NN-1;

  if (mode != 2){
    int cntv = counts[vld];
    float invf = (cntv > 0) ? (1.0f / (float)cntv) : 0.0f;   // masks zero-degree
    f16x2 invd2; invd2[0] = (_Float16)invf; invd2[1] = (_Float16)invf;
    f16x8 a1[4];
    a1[0] = *(const f16x8*)(hbf + (size_t)vld*H + quad*8);
    a1[1] = *(const f16x8*)(hbf + (size_t)vld*H + 32 + quad*8);
    #pragma unroll
    for (int kb2=0; kb2<2; kb2++){
      uint4 u = *(const uint4*)(aggh + (size_t)vld*H + kb2*32 + quad*8);
      union { unsigned int u[4]; f16x8 v; } A;
      A.u[0] = mulpk_(u.x, invd2);
      A.u[1] = mulpk_(u.y, invd2);
      A.u[2] = mulpk_(u.z, invd2);
      A.u[3] = mulpk_(u.w, invd2);
      a1[2+kb2] = A.v;
    }
    f32x4 acc1[4];
    #pragma unroll
    for (int n=0;n<4;n++) acc1[n] = (f32x4){0.f,0.f,0.f,0.f};
    #pragma unroll
    for (int n=0;n<4;n++){
      #pragma unroll
      for (int kb=0;kb<4;kb++){
        f16x8 b = *(const f16x8*)(uw1p + (((kb*4 + quad)*64 + n*16 + c) << 3));
        acc1[n] = __builtin_amdgcn_mfma_f32_16x16x32_f16(a1[kb], b, acc1[n], 0, 0, 0);
      }
    }
    #pragma unroll
    for (int n=0;n<4;n++){
      float bb = ub1[n*16 + c];
      #pragma unroll
      for (int r=0;r<4;r++)
        act[(quad*4 + r)*72 + n*16 + c] = f2h_(relu_(acc1[n][r] + bb));
    }
    __syncthreads();

    f16x8 a2[2];
    a2[0] = *(const f16x8*)(act + c*72 + quad*8);
    a2[1] = *(const f16x8*)(act + c*72 + 32 + quad*8);
    f32x4 acc2[4];
    #pragma unroll
    for (int n=0;n<4;n++) acc2[n] = (f32x4){0.f,0.f,0.f,0.f};
    #pragma unroll
    for (int n=0;n<4;n++){
      #pragma unroll
      for (int kb=0;kb<2;kb++){
        f16x8 b = *(const f16x8*)(uw2p + (((kb*4 + quad)*64 + n*16 + c) << 3));
        acc2[n] = __builtin_amdgcn_mfma_f32_16x16x32_f16(a2[kb], b, acc2[n], 0, 0, 0);
      }
    }
    __syncthreads();
    #pragma unroll
    for (int n=0;n<4;n++){
      float bb = ub2[n*16 + c];
      #pragma unroll
      for (int r=0;r<4;r++)
        act[(quad*4 + r)*72 + n*16 + c] = f2h_(relu_(acc2[n][r] + bb));
    }
    __syncthreads();
  }

  f16x8 a3[2];
  if (mode == 2){
    a3[0] = *(const f16x8*)(hbf + (size_t)vld*H + quad*8);
    a3[1] = *(const f16x8*)(hbf + (size_t)vld*H + 32 + quad*8);
  } else {
    a3[0] = *(const f16x8*)(act + c*72 + quad*8);
    a3[1] = *(const f16x8*)(act + c*72 + 32 + quad*8);
  }

  if (mode == 1){
    f32x4 acc3[4];
    #pragma unroll
    for (int n=0;n<4;n++) acc3[n] = (f32x4){0.f,0.f,0.f,0.f};
    #pragma unroll
    for (int n=0;n<4;n++){
      #pragma unroll
      for (int kb=0;kb<2;kb++){
        f16x8 b = *(const f16x8*)(w3p + (((kb*4 + quad)*64 + n*16 + c) << 3));
        acc3[n] = __builtin_amdgcn_mfma_f32_16x16x32_f16(a3[kb], b, acc3[n], 0, 0, 0);
      }
    }
    __syncthreads();
    #pragma unroll
    for (int n=0;n<4;n++){
      float bb = b3[n*16 + c];
      #pragma unroll
      for (int r=0;r<4;r++)
        act[(quad*4 + r)*72 + n*16 + c] = f2h_(relu_(acc3[n][r] + bb));
    }
  } else {
    f32x4 acc3[8];
    #pragma unroll
    for (int n=0;n<8;n++) acc3[n] = (f32x4){0.f,0.f,0.f,0.f};
    #pragma unroll
    for (int n=0;n<8;n++){
      #pragma unroll
      for (int kb=0;kb<2;kb++){
        f16x8 b = *(const f16x8*)(w3p + (((kb*4 + quad)*128 + n*16 + c) << 3));
        acc3[n] = __builtin_amdgcn_mfma_f32_16x16x32_f16(a3[kb], b, acc3[n], 0, 0, 0);
      }
    }
    #pragma unroll
    for (int n=0;n<8;n++){
      int ch = n*16 + c;
      float bb = (ch >= 64) ? b3[ch - 64] : 0.0f;
      #pragma unroll
      for (int r=0;r<4;r++)
        pst[(quad*4 + r)*136 + ch] = f2h_(acc3[n][r] + bb);
    }
  }

  __syncthreads();   // 1-wave block: ~free; orders LDS writes before copy reads

  if (mode == 0){
    #pragma unroll
    for (int rr=0; rr<2; rr++){
      int idx = lane + rr*64;
      int node = idx >> 3, ko = (idx & 7)*8;
      int v = vb + node;
      if (v < NN) *(uint4*)(hout + (size_t)v*H + ko) = *(const uint4*)(act + node*72 + ko);
    }
  }
  if (mode == 0 || mode == 2){
    #pragma unroll
    for (int rr=0; rr<4; rr++){
      int idx = lane + rr*64;
      int node = idx >> 4, cho = (idx & 15)*8;
      int v = vb + node;
      if (v < NN) *(uint4*)(Pout + (size_t)v*128 + cho) = *(const uint4*)(pst + node*136 + cho);
    }
  }
  if (mode == 1){
    if (lane < 48){
      int node = lane / 3;
      int v = vb + node;
      if (v < NN){
        int cm = lane - node*3;
        float s = ob2[cm];
        #pragma unroll 8
        for (int k=0;k<64;k++)
          s = fmaf(h2f_(act[node*72 + k]), ow2[k*3 + cm], s);
        outp[(size_t)v*3 + cm] = 6.283185307179586f / (1.0f + __expf(-s));
      }
    }
  }
}

// ================= legacy fallback kernels (known correct; small ws) =================
__global__ __launch_bounds__(256) void enc_kernel_legacy(
    const float* __restrict__ x,
    const float* __restrict__ w1, const float* __restrict__ b1,
    const float* __restrict__ w2, const float* __restrict__ b2,
    float* __restrict__ h)
{
  int v = blockIdx.x*256 + threadIdx.x;
  if (v >= NN) return;
  float in0[5];
  #pragma unroll
  for (int k=0;k<5;k++) in0[k] = x[v*5+k];
  float hid[H];
  #pragma unroll
  for (int j=0;j<H;j++) hid[j] = b1[j];
  #pragma unroll
  for (int k=0;k<5;k++){
    #pragma unroll
    for (int j=0;j<H;j++) hid[j] = fmaf(in0[k], w1[k*H+j], hid[j]);
  }
  float o[H];
  #pragma unroll
  for (int j=0;j<H;j++) o[j] = b2[j];
  #pragma unroll
  for (int k=0;k<H;k++){
    float hk = relu_(hid[k]);
    #pragma unroll
    for (int j=0;j<H;j++) o[j] = fmaf(hk, w2[k*H+j], o[j]);
  }
  float4* hw = (float4*)(h + (size_t)v*H);
  #pragma unroll
  for (int j4=0;j4<H/4;j4++){
    float4 t;
    t.x = relu_(o[4*j4+0]); t.y = relu_(o[4*j4+1]);
    t.z = relu_(o[4*j4+2]); t.w = relu_(o[4*j4+3]);
    hw[j4] = t;
  }
}

__global__ __launch_bounds__(256) void msg_kernel_atomic(
    const float* __restrict__ h,
    const int* __restrict__ src, const int* __restrict__ dst,
    const float* __restrict__ w1, const float* __restrict__ b1,
    const float* __restrict__ w2, const float* __restrict__ b2,
    float* __restrict__ agg)
{
  int e = blockIdx.x*256 + threadIdx.x;
  if (e >= NE) return;
  int s = src[e], d = dst[e];
  const float4* hs = (const float4*)(h + (size_t)s*H);
  const float4* hd = (const float4*)(h + (size_t)d*H);
  float hid[H];
  #pragma unroll
  for (int j=0;j<H;j++) hid[j] = b1[j];
  #pragma unroll 4
  for (int k4=0;k4<16;k4++){
    float4 a = hs[k4];
    const float* wr = w1 + (size_t)(4*k4)*H;
    #pragma unroll
    for (int j=0;j<H;j++) hid[j] = fmaf(a.x, wr[j], hid[j]);
    #pragma unroll
    for (int j=0;j<H;j++) hid[j] = fmaf(a.y, wr[H+j], hid[j]);
    #pragma unroll
    for (int j=0;j<H;j++) hid[j] = fmaf(a.z, wr[2*H+j], hid[j]);
    #pragma unroll
    for (int j=0;j<H;j++) hid[j] = fmaf(a.w, wr[3*H+j], hid[j]);
  }
  #pragma unroll 4
  for (int k4=0;k4<16;k4++){
    float4 a = hd[k4];
    const float* wr = w1 + (size_t)(64 + 4*k4)*H;
    #pragma unroll
    for (int j=0;j<H;j++) hid[j] = fmaf(a.x, wr[j], hid[j]);
    #pragma unroll
    for (int j=0;j<H;j++) hid[j] = fmaf(a.y, wr[H+j], hid[j]);
    #pragma unroll
    for (int j=0;j<H;j++) hid[j] = fmaf(a.z, wr[2*H+j], hid[j]);
    #pragma unroll
    for (int j=0;j<H;j++) hid[j] = fmaf(a.w, wr[3*H+j], hid[j]);
  }
  float o[H];
  #pragma unroll
  for (int j=0;j<H;j++) o[j] = b2[j];
  #pragma unroll
  for (int k=0;k<H;k++){
    float hk = relu_(hid[k]);
    #pragma unroll
    for (int j=0;j<H;j++) o[j] = fmaf(hk, w2[k*H+j], o[j]);
  }
  float* arow = agg + (size_t)d*H;
  #pragma unroll
  for (int j=0;j<H;j++) atomicAdd(arow + j, relu_(o[j]));
}

__global__ __launch_bounds__(256) void div_kernel(float* __restrict__ agg,
                                                  const int* __restrict__ counts)
{
  int i = blockIdx.x*256 + threadIdx.x;
  if (i >= NN*H/4) return;
  int v = i / (H/4);
  float invd = 1.0f / fmaxf((float)counts[v], 1.0f);
  float4* a = (float4*)agg + i;
  float4 t = *a;
  t.x *= invd; t.y *= invd; t.z *= invd; t.w *= invd;
  *a = t;
}

__global__ __launch_bounds__(256) void upd_kernel_legacy(
    float* __restrict__ h, const float* __restrict__ agg,
    const float* __restrict__ w1, const float* __restrict__ b1,
    const float* __restrict__ w2, const float* __restrict__ b2)
{
  int v = blockIdx.x*256 + threadIdx.x;
  if (v >= NN) return;
  const float4* hv = (const float4*)(h + (size_t)v*H);
  const float4* av = (const float4*)(agg + (size_t)v*H);
  float hid[H];
  #pragma unroll
  for (int j=0;j<H;j++) hid[j] = b1[j];
  #pragma unroll 4
  for (int k4=0;k4<16;k4++){
    float4 a = hv[k4];
    const float* wr = w1 + (size_t)(4*k4)*H;
    #pragma unroll
    for (int j=0;j<H;j++) hid[j] = fmaf(a.x, wr[j], hid[j]);
    #pragma unroll
    for (int j=0;j<H;j++) hid[j] = fmaf(a.y, wr[H+j], hid[j]);
    #pragma unroll
    for (int j=0;j<H;j++) hid[j] = fmaf(a.z, wr[2*H+j], hid[j]);
    #pragma unroll
    for (int j=0;j<H;j++) hid[j] = fmaf(a.w, wr[3*H+j], hid[j]);
  }
  #pragma unroll 4
  for (int k4=0;k4<16;k4++){
    float4 a = av[k4];
    const float* wr = w1 + (size_t)(64 + 4*k4)*H;
    #pragma unroll
    for (int j=0;j<H;j++) hid[j] = fmaf(a.x, wr[j], hid[j]);
    #pragma unroll
    for (int j=0;j<H;j++) hid[j] = fmaf(a.y, wr[H+j], hid[j]);
    #pragma unroll
    for (int j=0;j<H;j++) hid[j] = fmaf(a.z, wr[2*H+j], hid[j]);
    #pragma unroll
    for (int j=0;j<H;j++) hid[j] = fmaf(a.w, wr[3*H+j], hid[j]);
  }
  float o[H];
  #pragma unroll
  for (int j=0;j<H;j++) o[j] = b2[j];
  #pragma unroll
  for (int k=0;k<H;k++){
    float hk = relu_(hid[k]);
    #pragma unroll
    for (int j=0;j<H;j++) o[j] = fmaf(hk, w2[k*H+j], o[j]);
  }
  float4* hw = (float4*)(h + (size_t)v*H);
  #pragma unroll
  for (int j4=0;j4<H/4;j4++){
    float4 t;
    t.x = relu_(o[4*j4+0]); t.y = relu_(o[4*j4+1]);
    t.z = relu_(o[4*j4+2]); t.w = relu_(o[4*j4+3]);
    hw[j4] = t;
  }
}

__global__ __launch_bounds__(256) void out_kernel2(
    const float* __restrict__ h,
    const float* __restrict__ w1, const float* __restrict__ b1,
    const float* __restrict__ w2, const float* __restrict__ b2,
    float* __restrict__ out)
{
  int v = blockIdx.x*256 + threadIdx.x;
  if (v >= NN) return;
  const float4* hv = (const float4*)(h + (size_t)v*H);
  float pr[3] = { b2[0], b2[1], b2[2] };
  #pragma unroll 1
  for (int half=0; half<2; half++){
    float o[32];
    #pragma unroll
    for (int j=0;j<32;j++) o[j] = b1[half*32 + j];
    #pragma unroll 4
    for (int k4=0;k4<16;k4++){
      float4 a = hv[k4];
      const float* wr = w1 + (4*k4)*H + half*32;
      fma32(o, a.x, wr); fma32(o, a.y, wr+H); fma32(o, a.z, wr+2*H); fma32(o, a.w, wr+3*H);
    }
    #pragma unroll
    for (int j=0;j<32;j++){
      float hk = relu_(o[j]);
      int k = half*32 + j;
      pr[0] = fmaf(hk, w2[k*3+0], pr[0]);
      pr[1] = fmaf(hk, w2[k*3+1], pr[1]);
      pr[2] = fmaf(hk, w2[k*3+2], pr[2]);
    }
  }
  #pragma unroll
  for (int c=0;c<3;c++)
    out[(size_t)v*3 + c] = 6.283185307179586f / (1.0f + __expf(-pr[c]));
}

// =====================================================================

extern "C" void kernel_launch(void* const* d_in, const int* in_sizes, int n_in,
                              void* d_out, int out_size, void* d_ws, size_t ws_size,
                              hipStream_t stream)
{
  const float* x      = (const float*)d_in[0];
  const int*   ei     = (const int*)  d_in[1];
  const float* enc_w1 = (const float*)d_in[2];
  const float* enc_b1 = (const float*)d_in[3];
  const float* enc_w2 = (const float*)d_in[4];
  const float* enc_b2 = (const float*)d_in[5];
  const float* msg_w1 = (const float*)d_in[6];
  const float* msg_b1 = (const float*)d_in[7];
  const float* msg_w2 = (const float*)d_in[8];
  const float* msg_b2 = (const float*)d_in[9];
  const float* upd_w1 = (const float*)d_in[10];
  const float* upd_b1 = (const float*)d_in[11];
  const float* upd_w2 = (const float*)d_in[12];
  const float* upd_b2 = (const float*)d_in[13];
  const float* out_w1 = (const float*)d_in[14];
  const float* out_b1 = (const float*)d_in[15];
  const float* out_w2 = (const float*)d_in[16];
  const float* out_b2 = (const float*)d_in[17];
  float* out = (float*)d_out;

  const int* srcp = ei;
  const int* dstp = ei + NE;

  const int nodeBlocks  = (NN + 255)/256;
  const int edgeBlocks  = (NE + 255)/256;
  const int rankBlocks  = (NE + 1023)/1024;          // 4 edges/thread
  const int msgBlocks   = (NE + EB - 1)/EB;          // 7813
  const int scanBlocks  = (NN + 1023)/1024;
  const int fusedBlocks = (NN + 15)/16;              // 6250 (64-thread blocks)

  // ---- workspace layout ----
  char* wp_ = (char*)d_ws;
  auto take = [&wp_](size_t bytes) -> char* {
    char* r = wp_;
    wp_ += (bytes + 255) & ~(size_t)255;
    return r;
  };
  unsigned short* hbf = (unsigned short*)take((size_t)NN*H*sizeof(unsigned short)); // 12.8 MB fp16
  unsigned short* P   = (unsigned short*)take((size_t)NN*128*sizeof(unsigned short)); // 25.6 MB fp16
  int* counts         = (int*)take((size_t)NN*sizeof(int));
  // counts8 + 3x aggh contiguous (sizes are exact multiples of 256B -> no pad):
  // one memset zeroes both.
  int* counts8        = (int*)take((size_t)NSH*NN*sizeof(int));                    // 3.2 MB
  unsigned short* aggh3 = (unsigned short*)take((size_t)3*NN*H*sizeof(unsigned short)); // 38.4 MB
  int* pfx            = (int*)take((size_t)NSH*NN*sizeof(int));                    // 3.2 MB
  int* row_excl       = (int*)take((size_t)NN*sizeof(int));
  int* part           = (int*)take(1024);
  int* rank           = (int*)take((size_t)NE*sizeof(int));                        // 4 MB
  int2* sedge         = (int2*)take((size_t)NE*sizeof(int2));                      // 8 MB
  unsigned short* wpz = (unsigned short*)take((size_t)77824*sizeof(unsigned short));
  size_t need = (size_t)(wp_ - (char*)d_ws);

  // preswizzled-weight offsets (ushort elements)
  const size_t UW1 = 0, UW2 = 24576, PPJ = 36864, OW1 = 61440, MW2 = 65536;

  if (ws_size >= need) {
    // single upfront zero: counts8 (3.2MB) + aggh3 (38.4MB), contiguous
    (void)hipMemsetAsync(counts8, 0,
        (size_t)NSH*NN*sizeof(int) + (size_t)3*NN*H*sizeof(unsigned short), stream);

    enc_full_kernel<<<nodeBlocks, 256, 0, stream>>>(x, enc_w1, enc_b1, enc_w2, enc_b2, hbf);

    rank_kernel<<<rankBlocks, 256, 0, stream>>>(dstp, counts8, rank);
    scan1_kernel<<<scanBlocks, 1024, 0, stream>>>(counts8, counts, pfx, row_excl, part);
    scan2_kernel<<<1, 128, 0, stream>>>(part, scanBlocks);
    fill_kernel<<<edgeBlocks, 256, 0, stream>>>(srcp, dstp, row_excl, part, pfx, rank, sedge);
    prep_all_kernel<<<(77824 + 255)/256, 256, 0, stream>>>(upd_w1, upd_w2, msg_w1, msg_w2, out_w1, wpz);

    // layer-0 P projection (mode 2)
    node_fused_kernel<<<fusedBlocks, 64, 0, stream>>>(
        hbf, aggh3, counts,
        nullptr, nullptr, nullptr, nullptr,
        wpz + PPJ, msg_b1, nullptr, nullptr,
        nullptr, P, nullptr, 2);

    for (int l=0; l<3; l++){
      unsigned short* agghl = aggh3 + (size_t)l*NN*H;   // per-layer pre-zeroed buffer
      msg_mfma_kernel<<<msgBlocks, MBT, 0, stream>>>(P, wpz + MW2 + (size_t)l*4096,
          msg_b2 + (size_t)l*H, sedge, agghl);
      if (l < 2){
        node_fused_kernel<<<fusedBlocks, 64, 0, stream>>>(
            hbf, agghl, counts,
            wpz + UW1 + (size_t)l*8192, upd_b1 + (size_t)l*H,
            wpz + UW2 + (size_t)l*4096, upd_b2 + (size_t)l*H,
            wpz + PPJ + (size_t)(l+1)*8192, msg_b1 + (size_t)(l+1)*H,
            nullptr, nullptr,
            hbf, P, nullptr, 0);
      } else {
        node_fused_kernel<<<fusedBlocks, 64, 0, stream>>>(
            hbf, agghl, counts,
            wpz + UW1 + (size_t)l*8192, upd_b1 + (size_t)l*H,
            wpz + UW2 + (size_t)l*4096, upd_b2 + (size_t)l*H,
            wpz + OW1, out_b1,
            out_w2, out_b2,
            nullptr, nullptr, out, 1);
      }
    }
  } else {
    // ======== fallback: legacy atomic path (fits in ~52 MB) ========
    char* fp = (char*)d_ws;
    float* fh   = (float*)fp;  fp += (size_t)NN*H*sizeof(float);
    float* fagg = (float*)fp;  fp += (size_t)NN*H*sizeof(float);
    int* fcnt   = (int*)fp;

    (void)hipMemsetAsync(fcnt, 0, NN*sizeof(int), stream);
    enc_kernel_legacy<<<nodeBlocks, 256, 0, stream>>>(x, enc_w1, enc_b1, enc_w2, enc_b2, fh);
    count_kernel<<<edgeBlocks, 256, 0, stream>>>(dstp, fcnt);
    for (int l=0; l<3; l++){
      (void)hipMemsetAsync(fagg, 0, (size_t)NN*H*sizeof(float), stream);
      msg_kernel_atomic<<<edgeBlocks, 256, 0, stream>>>(fh, srcp, dstp,
          msg_w1 + (size_t)l*128*H, msg_b1 + (size_t)l*H,
          msg_w2 + (size_t)l*H*H,   msg_b2 + (size_t)l*H, fagg);
      div_kernel<<<(NN*H/4 + 255)/256, 256, 0, stream>>>(fagg, fcnt);
      upd_kernel_legacy<<<nodeBlocks, 256, 0, stream>>>(fh, fagg,
          upd_w1 + (size_t)l*128*H, upd_b1 + (size_t)l*H,
          upd_w2 + (size_t)l*H*H,   upd_b2 + (size_t)l*H);
    }
    out_kernel2<<<nodeBlocks, 256, 0, stream>>>(fh, out_w1, out_b1, out_w2, out_b2, out);
  }
}

// Round 12
// 366.535 us; speedup vs baseline: 1.0960x; 1.0007x over previous
//
#include <hip/hip_runtime.h>
#include <math.h>

#define NN 100000
#define NE 1000000
#define H 64
#define EB 128        // edges per msg block (round-8: EB=256 cost occupancy, reverted)
#define MBT 256       // msg block threads (4 waves; each wave does 32 edges)
#define MSTRIDE 130   // ushorts per channel row in msg LDS (128 edges + 2 pad)
#define NSH 8         // atomic shards for rank (round-6: line-contention fix)

typedef _Float16 f16x8 __attribute__((ext_vector_type(8)));
typedef _Float16 f16x2 __attribute__((ext_vector_type(2)));
typedef float f32x4  __attribute__((ext_vector_type(4)));

static __device__ __forceinline__ float relu_(float x){ return fmaxf(x, 0.0f); }

static __device__ __forceinline__ unsigned short f2h_(float f){
  union { _Float16 h; unsigned short u; } x; x.h = (_Float16)f; return x.u;
}
static __device__ __forceinline__ float h2f_(unsigned short u){
  union { unsigned short u; _Float16 h; } x; x.u = u; return (float)x.h;
}
static __device__ __forceinline__ unsigned int pkh_(float lo, float hi){
  union { f16x2 v; unsigned int u; } x;
  x.v[0] = (_Float16)lo; x.v[1] = (_Float16)hi;
  return x.u;
}
// packed fp16: relu(a + b) on 2 lanes (lowers to v_pk_add_f16 + v_pk_max_f16)
static __device__ __forceinline__ unsigned int addrelu2_(unsigned int a, unsigned int b){
  union { unsigned int u; f16x2 v; } x, y, r;
  x.u = a; y.u = b;
  f16x2 s = x.v + y.v;
  _Float16 z = (_Float16)0.0f;
  r.v[0] = (s[0] > z) ? s[0] : z;
  r.v[1] = (s[1] > z) ? s[1] : z;
  return r.u;
}
// packed fp16 multiply by broadcast scale (v_pk_mul_f16)
static __device__ __forceinline__ unsigned int mulpk_(unsigned int a, f16x2 s){
  union { unsigned int u; f16x2 v; } x;
  x.u = a; x.v = x.v * s;
  return x.u;
}
// fire-and-forget packed fp16 atomic add (gfx90a+/gfx950)
static __device__ __forceinline__ void atomic_pk_f16_(unsigned short* p, unsigned int pk){
  asm volatile("global_atomic_pk_add_f16 %0, %1, off" :: "v"(p), "v"(pk) : "memory");
}
static __device__ __forceinline__ void fma32(float* o, float a, const float* wr){
  #pragma unroll
  for (int j=0;j<32;j++) o[j] = fmaf(a, wr[j], o[j]);
}

// ---------------- fused encoder: hbf(fp16) = relu(relu(x@w1+b1)@w2+b2) ----------------
// Round 0 fix: hidden t[64] with runtime index -> scratch (51 MB traffic). Now the
// hidden unit t_k is recomputed inline per k (5 FMAs) and o[64] is static-indexed.
__global__ __launch_bounds__(256, 2) void enc_full_kernel(
    const float* __restrict__ x,
    const float* __restrict__ w1, const float* __restrict__ b1,
    const float* __restrict__ w2, const float* __restrict__ b2,
    unsigned short* __restrict__ hbf)
{
  int v = blockIdx.x*256 + threadIdx.x;
  if (v >= NN) return;
  float in0[5];
  #pragma unroll
  for (int k=0;k<5;k++) in0[k] = x[(size_t)v*5 + k];
  float o[64];
  #pragma unroll
  for (int j=0;j<64;j++) o[j] = b2[j];
  #pragma unroll 4
  for (int k=0;k<64;k++){
    float tk = b1[k];
    #pragma unroll
    for (int kk=0;kk<5;kk++) tk = fmaf(in0[kk], w1[kk*H + k], tk);
    tk = relu_(tk);
    const float* wr = w2 + k*H;
    #pragma unroll
    for (int j=0;j<64;j++) o[j] = fmaf(tk, wr[j], o[j]);
  }
  unsigned int u[32];
  #pragma unroll
  for (int j=0;j<32;j++) u[j] = pkh_(relu_(o[2*j]), relu_(o[2*j+1]));
  uint4* dp = (uint4*)(hbf + (size_t)v*H);
  #pragma unroll
  for (int j=0;j<8;j++) dp[j] = *(uint4*)&u[4*j];
}

// ---------------- sharded in-degree counts + per-edge shard-rank ----------------
// Round-6: shard counts 8 ways by blockIdx&7 (line-contention fix). Block b covers
// edges [b*1024,(b+1)*1024) -> fill derives sh = (e>>10)&7.
__global__ __launch_bounds__(256) void rank_kernel(const int* __restrict__ dst,
                                                   int* __restrict__ counts8,
                                                   int* __restrict__ rank)
{
  int t = blockIdx.x*256 + threadIdx.x;
  int e0 = t*4;
  int* cs = counts8 + (size_t)(blockIdx.x & (NSH-1))*NN;
  if (e0 + 3 < NE){
    int4 d4 = *(const int4*)(dst + e0);
    int r0 = atomicAdd(&cs[d4.x], 1);
    int r1 = atomicAdd(&cs[d4.y], 1);
    int r2 = atomicAdd(&cs[d4.z], 1);
    int r3 = atomicAdd(&cs[d4.w], 1);
    *(int4*)(rank + e0) = make_int4(r0, r1, r2, r3);
  } else {
    for (int e = e0; e < NE; ++e) rank[e] = atomicAdd(&cs[dst[e]], 1);
  }
}

// ---------------- scan phase 1: shuffle-based; sums 8 shard copies ----------------
__global__ __launch_bounds__(1024) void scan1_kernel(const int* __restrict__ counts8,
                                                     int* __restrict__ counts,
                                                     int* __restrict__ pfx,
                                                     int* __restrict__ row_excl,
                                                     int* __restrict__ part)
{
  __shared__ int wsum[16];
  int tid = threadIdx.x;
  int i = blockIdx.x*1024 + tid;
  int v = 0;
  if (i < NN){
    int run = 0;
    #pragma unroll
    for (int sh=0; sh<NSH; sh++){
      int c = counts8[(size_t)sh*NN + i];
      pfx[(size_t)sh*NN + i] = run;
      run += c;
    }
    v = run;
    counts[i] = run;
  }
  int lane = tid & 63, w = tid >> 6;
  int s = v;                       // inclusive wave scan
  #pragma unroll
  for (int off=1; off<64; off<<=1){
    int t = __shfl_up(s, off, 64);
    if (lane >= off) s += t;
  }
  if (lane == 63) wsum[w] = s;
  __syncthreads();
  if (w == 0 && lane < 16){
    int t = wsum[lane];
    #pragma unroll
    for (int off=1; off<16; off<<=1){
      int u = __shfl_up(t, off, 64);
      if (lane >= off) t += u;
    }
    wsum[lane] = t;                // inclusive wave partials
  }
  __syncthreads();
  int base = (w > 0) ? wsum[w-1] : 0;
  int incl = base + s;
  if (i < NN) row_excl[i] = incl - v;
  if (tid == 1023) part[blockIdx.x] = incl;
}

// ---------------- scan phase 2 ----------------
__global__ __launch_bounds__(128) void scan2_kernel(int* __restrict__ part, int nparts)
{
  __shared__ int buf[128];
  int tid = threadIdx.x;
  int v = (tid < nparts) ? part[tid] : 0;
  buf[tid] = v;
  __syncthreads();
  for (int off=1; off<128; off<<=1){
    int t = (tid >= off) ? buf[tid-off] : 0;
    __syncthreads();
    buf[tid] += t;
    __syncthreads();
  }
  if (tid < nparts) part[tid] = buf[tid] - v;
}

// ---------------- fill sorted edge records (no atomics; shard-rank precomputed) ------
__global__ __launch_bounds__(256) void fill_kernel(
    const int* __restrict__ src, const int* __restrict__ dst,
    const int* __restrict__ row_excl, const int* __restrict__ part,
    const int* __restrict__ pfx,
    const int* __restrict__ rank, int2* __restrict__ sedge)
{
  int e = blockIdx.x*256 + threadIdx.x;
  if (e >= NE) return;
  int d = dst[e];
  int sh = (e >> 10) & (NSH-1);
  int p = row_excl[d] + part[d >> 10] + pfx[(size_t)sh*NN + d] + rank[e];
  sedge[p] = make_int2(src[e], d);
}

// ---------------- plain count (fallback path only) ----------------
__global__ __launch_bounds__(256) void count_kernel(const int* __restrict__ dst,
                                                    int* __restrict__ counts)
{
  int e = blockIdx.x*256 + threadIdx.x;
  if (e < NE) atomicAdd(&counts[dst[e]], 1);
}

// ---------------- preswizzle ALL weights to fp16 MFMA B-fragment order -------------
// frag index within a K x N weight: idx = ((kb*4+quad)*N + col)*8 + j,  k = kb*32+quad*8+j
// layout (ushort elems): [0,24576) uw1p | [24576,36864) uw2p |
// [36864,61440) pprojp | [61440,65536) ow1p | [65536,77824) msgw2p   (all fp16)
__global__ __launch_bounds__(256) void prep_all_kernel(
    const float* __restrict__ uw1, const float* __restrict__ uw2,
    const float* __restrict__ mw1, const float* __restrict__ mw2,
    const float* __restrict__ ow1, unsigned short* __restrict__ wp)
{
  int i = blockIdx.x*256 + threadIdx.x;
  if (i >= 77824) return;
  float val;
  if (i < 24576){
    int l = i / 8192, r = i & 8191;
    int j = r & 7, col = (r >> 3) & 63, g = r >> 9;
    int k = (g >> 2)*32 + (g & 3)*8 + j;
    val = uw1[(size_t)l*8192 + k*64 + col];
  } else if (i < 36864){
    int t = i - 24576; int l = t / 4096, r = t & 4095;
    int j = r & 7, col = (r >> 3) & 63, g = r >> 9;
    int k = (g >> 2)*32 + (g & 3)*8 + j;
    val = uw2[(size_t)l*4096 + k*64 + col];
  } else if (i < 61440){
    int t = i - 36864; int l = t / 8192, r = t & 8191;
    int j = r & 7, col = (r >> 3) & 127, g = r >> 10;
    int k = (g >> 2)*32 + (g & 3)*8 + j;
    val = mw1[(size_t)l*8192 + ((col >> 6)*64 + k)*64 + (col & 63)];
  } else if (i < 65536){
    int r = i - 61440;
    int j = r & 7, col = (r >> 3) & 63, g = r >> 9;
    int k = (g >> 2)*32 + (g & 3)*8 + j;
    val = ow1[k*64 + col];
  } else {
    int t = i - 65536; int l = t / 4096, r = t & 4095;
    int j = r & 7, col = (r >> 3) & 63, g = r >> 9;
    int k = (g >> 2)*32 + (g & 3)*8 + j;
    val = mw2[(size_t)l*4096 + k*64 + col];
  }
  wp[i] = f2h_(val);
}

// ---------------- MFMA message kernel v16: bound 4 -> 6 (clean occupancy probe).
// v15 structure unchanged: mask-driven walk (round-4), int2 staging (round-5),
// pk-atomic boundary flush (round-7/9). Round-2's bound-8 failed via VGPR squeeze
// (cap 64 -> spill); round-3's bound-6 was confounded by the two-pass walk. At
// bound 6 the VGPR cap is ~85 >> the 40 this kernel uses (spill-free, proven),
// LDS 17.9KB*6 = 107.5KB <= 160KB. Kernel is latency-bound (VALU 52%, Mfma 6%,
// HBM 18%) -> 1.5x wave pool is the matching lever. ----
__global__ __launch_bounds__(MBT, 6) void msg_mfma_kernel(
    const unsigned short* __restrict__ P,
    const unsigned short* __restrict__ w2p,
    const float* __restrict__ b2,
    const int2* __restrict__ sedge,
    unsigned short* __restrict__ aggh)
{
  __shared__ unsigned short mlds[64*MSTRIDE];
  __shared__ int2 sdl[EB];
  const int tid  = threadIdx.x;
  const int wave = tid >> 6, lane = tid & 63, quad = lane >> 4, c = lane & 15;

  // XCD-contiguous swizzle
  int bid = blockIdx.x;
  int ng = gridDim.x >> 3;
  int lb = (bid < (ng << 3)) ? ((bid & 7)*ng + (bid >> 3)) : bid;
  const int base = lb*EB;

  if (tid < EB){
    int p = base + tid;
    int2 sv = make_int2(0, -1);
    if (p < NE) sv = sedge[p];
    sdl[tid] = sv;
  }

  // B fragments (fp16) + bias
  f16x8 bfr[4][2];
  #pragma unroll
  for (int n=0;n<4;n++)
    #pragma unroll
    for (int kb=0;kb<2;kb++)
      bfr[n][kb] = *(const f16x8*)(w2p + (((kb*4 + quad)*64 + n*16 + c) << 3));
  float bv[4];
  #pragma unroll
  for (int n=0;n<4;n++) bv[n] = b2[n*16 + c];

  __syncthreads();

  const int ebase = wave*32;
  #pragma unroll
  for (int t=0;t<2;t++){
    int2 sd = sdl[ebase + t*16 + c];
    int s = sd.x;
    int d = sd.y < 0 ? 0 : sd.y;
    const unsigned short* p1 = P + (size_t)s*128 + quad*8;
    const unsigned short* p2 = P + (size_t)d*128 + 64 + quad*8;
    f16x8 af[2];
    #pragma unroll
    for (int kb=0;kb<2;kb++){
      uint4 u1 = *(const uint4*)(p1 + kb*32);
      uint4 u2 = *(const uint4*)(p2 + kb*32);
      union { unsigned int u[4]; f16x8 v; } A;
      A.u[0] = addrelu2_(u1.x, u2.x);
      A.u[1] = addrelu2_(u1.y, u2.y);
      A.u[2] = addrelu2_(u1.z, u2.z);
      A.u[3] = addrelu2_(u1.w, u2.w);
      af[kb] = A.v;
    }

    f32x4 acc4[4];
    #pragma unroll
    for (int n=0;n<4;n++) acc4[n] = (f32x4){0.f, 0.f, 0.f, 0.f};
    #pragma unroll
    for (int n=0;n<4;n++){
      acc4[n] = __builtin_amdgcn_mfma_f32_16x16x32_f16(af[0], bfr[n][0], acc4[n], 0, 0, 0);
      acc4[n] = __builtin_amdgcn_mfma_f32_16x16x32_f16(af[1], bfr[n][1], acc4[n], 0, 0, 0);
    }

    int e0 = ebase + t*16 + quad*4;
    #pragma unroll
    for (int n=0;n<4;n++){
      int ch = n*16 + c;
      float v0 = relu_(acc4[n][0] + bv[n]);
      float v1 = relu_(acc4[n][1] + bv[n]);
      float v2 = relu_(acc4[n][2] + bv[n]);
      float v3 = relu_(acc4[n][3] + bv[n]);
      *(unsigned int*)&mlds[ch*MSTRIDE + e0]     = pkh_(v0, v1);
      *(unsigned int*)&mlds[ch*MSTRIDE + e0 + 2] = pkh_(v2, v3);
    }
  }
  __syncthreads();

  // ---- mask-driven segmented reduce (single owner per run) ----
  {
    const int g = wave;
    const int ch = lane;
    int dA  = sdl[lane].y;
    int dAm = (lane == 0) ? ~dA : sdl[lane-1].y;     // force boundary at 0
    unsigned long long m0 = __ballot(dA != dAm);
    int dB  = sdl[64+lane].y;
    int dBm = sdl[63+lane].y;
    unsigned long long m1 = __ballot(dB != dBm);

    auto isb = [&](int p)->bool{
      return (p < 64) ? ((m0 >> p) & 1ull) : ((m1 >> (p-64)) & 1ull);
    };
    auto nextb = [&](int p)->int{
      int q = p + 1;
      if (q < 64){
        unsigned long long t = m0 >> q;
        if (t) return q + __builtin_ctzll(t);
        q = 64;
      }
      int off = q - 64;
      if (off < 64){
        unsigned long long t = m1 >> off;
        if (t) return q + __builtin_ctzll(t);
      }
      return EB;
    };

    int r = g*32;
    if (g > 0 && !isb(r)) r = nextb(r);   // skip run continuing from prev window
    const int myEnd = (g+1)*32;
    while (r < myEnd){
      int nb = nextb(r);                  // run end (exclusive), may cross windows
      int cur = sdl[r].y;
      float s2 = 0.f;
      for (int rr = r; rr < nb; ++rr)
        s2 += h2f_(mlds[ch*MSTRIDE + rr]);
      if (cur >= 0){
        bool bnd = (r == 0) || (nb == EB);   // may span block boundary
        if (bnd){
          // pack pairs (even,odd channel) and pk-atomic-add into zeroed aggh
          float other = __shfl_xor(s2, 1);
          if ((ch & 1) == 0){
            unsigned int pk = pkh_(s2, other);
            atomic_pk_f16_(aggh + (size_t)cur*H + ch, pk);
          }
        } else {
          aggh[(size_t)cur*H + ch] = f2h_(s2);
        }
      }
      r = nb;
    }
  }
}

// ---------------- fused node-side layer kernel (fp16 MFMA, fp16 agg in) -------------
// Round-9/10: 64-thread / 16-node blocks; 6250 one-wave blocks at 6.7KB LDS give
// the scheduler a continuous stream (old 1563-block grid was fully co-resident).
// __syncthreads retained (free for 1-wave blocks; guarantees LDS ordering).
// mode 0 (l=0,1): h' = relu-MLP2([h||agg/deg]) -> hout ; P_next = h'@W3 -> Pout
// mode 1 (l=2):   h' as above; out = 2pi*sigmoid(relu(h'@ow1+b3)@ow2+ob2)
// mode 2: P = hbf@W3 (+b3 top) -> Pout
__global__ __launch_bounds__(64) void node_fused_kernel(
    const unsigned short* __restrict__ hbf,
    const unsigned short* __restrict__ aggh, const int* __restrict__ counts,
    const unsigned short* __restrict__ uw1p, const float* __restrict__ ub1,
    const unsigned short* __restrict__ uw2p, const float* __restrict__ ub2,
    const unsigned short* __restrict__ w3p,  const float* __restrict__ b3,
    const float* __restrict__ ow2, const float* __restrict__ ob2,
    unsigned short* __restrict__ hout,
    unsigned short* __restrict__ Pout,
    float* __restrict__ outp,
    int mode)
{
  __shared__ __align__(16) unsigned short act[16*72];
  __shared__ __align__(16) unsigned short pst[16*136];
  const int lane = threadIdx.x;
  const int quad = lane >> 4, c = lane & 15;
  const int vb = blockIdx.x*16;
  int myv = vb + c;
  int vld = myv < NN ? myv : NN-1;

  if (mode != 2){
    int cntv = counts[vld];
    float invf = (cntv > 0) ? (1.0f / (float)cntv) : 0.0f;   // masks zero-degree
    f16x2 invd2; invd2[0] = (_Float16)invf; invd2[1] = (_Float16)invf;
    f16x8 a1[4];
    a1[0] = *(const f16x8*)(hbf + (size_t)vld*H + quad*8);
    a1[1] = *(const f16x8*)(hbf + (size_t)vld*H + 32 + quad*8);
    #pragma unroll
    for (int kb2=0; kb2<2; kb2++){
      uint4 u = *(const uint4*)(aggh + (size_t)vld*H + kb2*32 + quad*8);
      union { unsigned int u[4]; f16x8 v; } A;
      A.u[0] = mulpk_(u.x, invd2);
      A.u[1] = mulpk_(u.y, invd2);
      A.u[2] = mulpk_(u.z, invd2);
      A.u[3] = mulpk_(u.w, invd2);
      a1[2+kb2] = A.v;
    }
    f32x4 acc1[4];
    #pragma unroll
    for (int n=0;n<4;n++) acc1[n] = (f32x4){0.f,0.f,0.f,0.f};
    #pragma unroll
    for (int n=0;n<4;n++){
      #pragma unroll
      for (int kb=0;kb<4;kb++){
        f16x8 b = *(const f16x8*)(uw1p + (((kb*4 + quad)*64 + n*16 + c) << 3));
        acc1[n] = __builtin_amdgcn_mfma_f32_16x16x32_f16(a1[kb], b, acc1[n], 0, 0, 0);
      }
    }
    #pragma unroll
    for (int n=0;n<4;n++){
      float bb = ub1[n*16 + c];
      #pragma unroll
      for (int r=0;r<4;r++)
        act[(quad*4 + r)*72 + n*16 + c] = f2h_(relu_(acc1[n][r] + bb));
    }
    __syncthreads();

    f16x8 a2[2];
    a2[0] = *(const f16x8*)(act + c*72 + quad*8);
    a2[1] = *(const f16x8*)(act + c*72 + 32 + quad*8);
    f32x4 acc2[4];
    #pragma unroll
    for (int n=0;n<4;n++) acc2[n] = (f32x4){0.f,0.f,0.f,0.f};
    #pragma unroll
    for (int n=0;n<4;n++){
      #pragma unroll
      for (int kb=0;kb<2;kb++){
        f16x8 b = *(const f16x8*)(uw2p + (((kb*4 + quad)*64 + n*16 + c) << 3));
        acc2[n] = __builtin_amdgcn_mfma_f32_16x16x32_f16(a2[kb], b, acc2[n], 0, 0, 0);
      }
    }
    __syncthreads();
    #pragma unroll
    for (int n=0;n<4;n++){
      float bb = ub2[n*16 + c];
      #pragma unroll
      for (int r=0;r<4;r++)
        act[(quad*4 + r)*72 + n*16 + c] = f2h_(relu_(acc2[n][r] + bb));
    }
    __syncthreads();
  }

  f16x8 a3[2];
  if (mode == 2){
    a3[0] = *(const f16x8*)(hbf + (size_t)vld*H + quad*8);
    a3[1] = *(const f16x8*)(hbf + (size_t)vld*H + 32 + quad*8);
  } else {
    a3[0] = *(const f16x8*)(act + c*72 + quad*8);
    a3[1] = *(const f16x8*)(act + c*72 + 32 + quad*8);
  }

  if (mode == 1){
    f32x4 acc3[4];
    #pragma unroll
    for (int n=0;n<4;n++) acc3[n] = (f32x4){0.f,0.f,0.f,0.f};
    #pragma unroll
    for (int n=0;n<4;n++){
      #pragma unroll
      for (int kb=0;kb<2;kb++){
        f16x8 b = *(const f16x8*)(w3p + (((kb*4 + quad)*64 + n*16 + c) << 3));
        acc3[n] = __builtin_amdgcn_mfma_f32_16x16x32_f16(a3[kb], b, acc3[n], 0, 0, 0);
      }
    }
    __syncthreads();
    #pragma unroll
    for (int n=0;n<4;n++){
      float bb = b3[n*16 + c];
      #pragma unroll
      for (int r=0;r<4;r++)
        act[(quad*4 + r)*72 + n*16 + c] = f2h_(relu_(acc3[n][r] + bb));
    }
  } else {
    f32x4 acc3[8];
    #pragma unroll
    for (int n=0;n<8;n++) acc3[n] = (f32x4){0.f,0.f,0.f,0.f};
    #pragma unroll
    for (int n=0;n<8;n++){
      #pragma unroll
      for (int kb=0;kb<2;kb++){
        f16x8 b = *(const f16x8*)(w3p + (((kb*4 + quad)*128 + n*16 + c) << 3));
        acc3[n] = __builtin_amdgcn_mfma_f32_16x16x32_f16(a3[kb], b, acc3[n], 0, 0, 0);
      }
    }
    #pragma unroll
    for (int n=0;n<8;n++){
      int ch = n*16 + c;
      float bb = (ch >= 64) ? b3[ch - 64] : 0.0f;
      #pragma unroll
      for (int r=0;r<4;r++)
        pst[(quad*4 + r)*136 + ch] = f2h_(acc3[n][r] + bb);
    }
  }

  __syncthreads();   // 1-wave block: ~free; orders LDS writes before copy reads

  if (mode == 0){
    #pragma unroll
    for (int rr=0; rr<2; rr++){
      int idx = lane + rr*64;
      int node = idx >> 3, ko = (idx & 7)*8;
      int v = vb + node;
      if (v < NN) *(uint4*)(hout + (size_t)v*H + ko) = *(const uint4*)(act + node*72 + ko);
    }
  }
  if (mode == 0 || mode == 2){
    #pragma unroll
    for (int rr=0; rr<4; rr++){
      int idx = lane + rr*64;
      int node = idx >> 4, cho = (idx & 15)*8;
      int v = vb + node;
      if (v < NN) *(uint4*)(Pout + (size_t)v*128 + cho) = *(const uint4*)(pst + node*136 + cho);
    }
  }
  if (mode == 1){
    if (lane < 48){
      int node = lane / 3;
      int v = vb + node;
      if (v < NN){
        int cm = lane - node*3;
        float s = ob2[cm];
        #pragma unroll 8
        for (int k=0;k<64;k++)
          s = fmaf(h2f_(act[node*72 + k]), ow2[k*3 + cm], s);
        outp[(size_t)v*3 + cm] = 6.283185307179586f / (1.0f + __expf(-s));
      }
    }
  }
}

// ================= legacy fallback kernels (known correct; small ws) =================
__global__ __launch_bounds__(256) void enc_kernel_legacy(
    const float* __restrict__ x,
    const float* __restrict__ w1, const float* __restrict__ b1,
    const float* __restrict__ w2, const float* __restrict__ b2,
    float* __restrict__ h)
{
  int v = blockIdx.x*256 + threadIdx.x;
  if (v >= NN) return;
  float in0[5];
  #pragma unroll
  for (int k=0;k<5;k++) in0[k] = x[v*5+k];
  float hid[H];
  #pragma unroll
  for (int j=0;j<H;j++) hid[j] = b1[j];
  #pragma unroll
  for (int k=0;k<5;k++){
    #pragma unroll
    for (int j=0;j<H;j++) hid[j] = fmaf(in0[k], w1[k*H+j], hid[j]);
  }
  float o[H];
  #pragma unroll
  for (int j=0;j<H;j++) o[j] = b2[j];
  #pragma unroll
  for (int k=0;k<H;k++){
    float hk = relu_(hid[k]);
    #pragma unroll
    for (int j=0;j<H;j++) o[j] = fmaf(hk, w2[k*H+j], o[j]);
  }
  float4* hw = (float4*)(h + (size_t)v*H);
  #pragma unroll
  for (int j4=0;j4<H/4;j4++){
    float4 t;
    t.x = relu_(o[4*j4+0]); t.y = relu_(o[4*j4+1]);
    t.z = relu_(o[4*j4+2]); t.w = relu_(o[4*j4+3]);
    hw[j4] = t;
  }
}

__global__ __launch_bounds__(256) void msg_kernel_atomic(
    const float* __restrict__ h,
    const int* __restrict__ src, const int* __restrict__ dst,
    const float* __restrict__ w1, const float* __restrict__ b1,
    const float* __restrict__ w2, const float* __restrict__ b2,
    float* __restrict__ agg)
{
  int e = blockIdx.x*256 + threadIdx.x;
  if (e >= NE) return;
  int s = src[e], d = dst[e];
  const float4* hs = (const float4*)(h + (size_t)s*H);
  const float4* hd = (const float4*)(h + (size_t)d*H);
  float hid[H];
  #pragma unroll
  for (int j=0;j<H;j++) hid[j] = b1[j];
  #pragma unroll 4
  for (int k4=0;k4<16;k4++){
    float4 a = hs[k4];
    const float* wr = w1 + (size_t)(4*k4)*H;
    #pragma unroll
    for (int j=0;j<H;j++) hid[j] = fmaf(a.x, wr[j], hid[j]);
    #pragma unroll
    for (int j=0;j<H;j++) hid[j] = fmaf(a.y, wr[H+j], hid[j]);
    #pragma unroll
    for (int j=0;j<H;j++) hid[j] = fmaf(a.z, wr[2*H+j], hid[j]);
    #pragma unroll
    for (int j=0;j<H;j++) hid[j] = fmaf(a.w, wr[3*H+j], hid[j]);
  }
  #pragma unroll 4
  for (int k4=0;k4<16;k4++){
    float4 a = hd[k4];
    const float* wr = w1 + (size_t)(64 + 4*k4)*H;
    #pragma unroll
    for (int j=0;j<H;j++) hid[j] = fmaf(a.x, wr[j], hid[j]);
    #pragma unroll
    for (int j=0;j<H;j++) hid[j] = fmaf(a.y, wr[H+j], hid[j]);
    #pragma unroll
    for (int j=0;j<H;j++) hid[j] = fmaf(a.z, wr[2*H+j], hid[j]);
    #pragma unroll
    for (int j=0;j<H;j++) hid[j] = fmaf(a.w, wr[3*H+j], hid[j]);
  }
  float o[H];
  #pragma unroll
  for (int j=0;j<H;j++) o[j] = b2[j];
  #pragma unroll
  for (int k=0;k<H;k++){
    float hk = relu_(hid[k]);
    #pragma unroll
    for (int j=0;j<H;j++) o[j] = fmaf(hk, w2[k*H+j], o[j]);
  }
  float* arow = agg + (size_t)d*H;
  #pragma unroll
  for (int j=0;j<H;j++) atomicAdd(arow + j, relu_(o[j]));
}

__global__ __launch_bounds__(256) void div_kernel(float* __restrict__ agg,
                                                  const int* __restrict__ counts)
{
  int i = blockIdx.x*256 + threadIdx.x;
  if (i >= NN*H/4) return;
  int v = i / (H/4);
  float invd = 1.0f / fmaxf((float)counts[v], 1.0f);
  float4* a = (float4*)agg + i;
  float4 t = *a;
  t.x *= invd; t.y *= invd; t.z *= invd; t.w *= invd;
  *a = t;
}

__global__ __launch_bounds__(256) void upd_kernel_legacy(
    float* __restrict__ h, const float* __restrict__ agg,
    const float* __restrict__ w1, const float* __restrict__ b1,
    const float* __restrict__ w2, const float* __restrict__ b2)
{
  int v = blockIdx.x*256 + threadIdx.x;
  if (v >= NN) return;
  const float4* hv = (const float4*)(h + (size_t)v*H);
  const float4* av = (const float4*)(agg + (size_t)v*H);
  float hid[H];
  #pragma unroll
  for (int j=0;j<H;j++) hid[j] = b1[j];
  #pragma unroll 4
  for (int k4=0;k4<16;k4++){
    float4 a = hv[k4];
    const float* wr = w1 + (size_t)(4*k4)*H;
    #pragma unroll
    for (int j=0;j<H;j++) hid[j] = fmaf(a.x, wr[j], hid[j]);
    #pragma unroll
    for (int j=0;j<H;j++) hid[j] = fmaf(a.y, wr[H+j], hid[j]);
    #pragma unroll
    for (int j=0;j<H;j++) hid[j] = fmaf(a.z, wr[2*H+j], hid[j]);
    #pragma unroll
    for (int j=0;j<H;j++) hid[j] = fmaf(a.w, wr[3*H+j], hid[j]);
  }
  #pragma unroll 4
  for (int k4=0;k4<16;k4++){
    float4 a = av[k4];
    const float* wr = w1 + (size_t)(64 + 4*k4)*H;
    #pragma unroll
    for (int j=0;j<H;j++) hid[j] = fmaf(a.x, wr[j], hid[j]);
    #pragma unroll
    for (int j=0;j<H;j++) hid[j] = fmaf(a.y, wr[H+j], hid[j]);
    #pragma unroll
    for (int j=0;j<H;j++) hid[j] = fmaf(a.z, wr[2*H+j], hid[j]);
    #pragma unroll
    for (int j=0;j<H;j++) hid[j] = fmaf(a.w, wr[3*H+j], hid[j]);
  }
  float o[H];
  #pragma unroll
  for (int j=0;j<H;j++) o[j] = b2[j];
  #pragma unroll
  for (int k=0;k<H;k++){
    float hk = relu_(hid[k]);
    #pragma unroll
    for (int j=0;j<H;j++) o[j] = fmaf(hk, w2[k*H+j], o[j]);
  }
  float4* hw = (float4*)(h + (size_t)v*H);
  #pragma unroll
  for (int j4=0;j4<H/4;j4++){
    float4 t;
    t.x = relu_(o[4*j4+0]); t.y = relu_(o[4*j4+1]);
    t.z = relu_(o[4*j4+2]); t.w = relu_(o[4*j4+3]);
    hw[j4] = t;
  }
}

__global__ __launch_bounds__(256) void out_kernel2(
    const float* __restrict__ h,
    const float* __restrict__ w1, const float* __restrict__ b1,
    const float* __restrict__ w2, const float* __restrict__ b2,
    float* __restrict__ out)
{
  int v = blockIdx.x*256 + threadIdx.x;
  if (v >= NN) return;
  const float4* hv = (const float4*)(h + (size_t)v*H);
  float pr[3] = { b2[0], b2[1], b2[2] };
  #pragma unroll 1
  for (int half=0; half<2; half++){
    float o[32];
    #pragma unroll
    for (int j=0;j<32;j++) o[j] = b1[half*32 + j];
    #pragma unroll 4
    for (int k4=0;k4<16;k4++){
      float4 a = hv[k4];
      const float* wr = w1 + (4*k4)*H + half*32;
      fma32(o, a.x, wr); fma32(o, a.y, wr+H); fma32(o, a.z, wr+2*H); fma32(o, a.w, wr+3*H);
    }
    #pragma unroll
    for (int j=0;j<32;j++){
      float hk = relu_(o[j]);
      int k = half*32 + j;
      pr[0] = fmaf(hk, w2[k*3+0], pr[0]);
      pr[1] = fmaf(hk, w2[k*3+1], pr[1]);
      pr[2] = fmaf(hk, w2[k*3+2], pr[2]);
    }
  }
  #pragma unroll
  for (int c=0;c<3;c++)
    out[(size_t)v*3 + c] = 6.283185307179586f / (1.0f + __expf(-pr[c]));
}

// =====================================================================

extern "C" void kernel_launch(void* const* d_in, const int* in_sizes, int n_in,
                              void* d_out, int out_size, void* d_ws, size_t ws_size,
                              hipStream_t stream)
{
  const float* x      = (const float*)d_in[0];
  const int*   ei     = (const int*)  d_in[1];
  const float* enc_w1 = (const float*)d_in[2];
  const float* enc_b1 = (const float*)d_in[3];
  const float* enc_w2 = (const float*)d_in[4];
  const float* enc_b2 = (const float*)d_in[5];
  const float* msg_w1 = (const float*)d_in[6];
  const float* msg_b1 = (const float*)d_in[7];
  const float* msg_w2 = (const float*)d_in[8];
  const float* msg_b2 = (const float*)d_in[9];
  const float* upd_w1 = (const float*)d_in[10];
  const float* upd_b1 = (const float*)d_in[11];
  const float* upd_w2 = (const float*)d_in[12];
  const float* upd_b2 = (const float*)d_in[13];
  const float* out_w1 = (const float*)d_in[14];
  const float* out_b1 = (const float*)d_in[15];
  const float* out_w2 = (const float*)d_in[16];
  const float* out_b2 = (const float*)d_in[17];
  float* out = (float*)d_out;

  const int* srcp = ei;
  const int* dstp = ei + NE;

  const int nodeBlocks  = (NN + 255)/256;
  const int edgeBlocks  = (NE + 255)/256;
  const int rankBlocks  = (NE + 1023)/1024;          // 4 edges/thread
  const int msgBlocks   = (NE + EB - 1)/EB;          // 7813
  const int scanBlocks  = (NN + 1023)/1024;
  const int fusedBlocks = (NN + 15)/16;              // 6250 (64-thread blocks)

  // ---- workspace layout ----
  char* wp_ = (char*)d_ws;
  auto take = [&wp_](size_t bytes) -> char* {
    char* r = wp_;
    wp_ += (bytes + 255) & ~(size_t)255;
    return r;
  };
  unsigned short* hbf = (unsigned short*)take((size_t)NN*H*sizeof(unsigned short)); // 12.8 MB fp16
  unsigned short* P   = (unsigned short*)take((size_t)NN*128*sizeof(unsigned short)); // 25.6 MB fp16
  int* counts         = (int*)take((size_t)NN*sizeof(int));
  // counts8 + 3x aggh contiguous (sizes are exact multiples of 256B -> no pad):
  // one memset zeroes both.
  int* counts8        = (int*)take((size_t)NSH*NN*sizeof(int));                    // 3.2 MB
  unsigned short* aggh3 = (unsigned short*)take((size_t)3*NN*H*sizeof(unsigned short)); // 38.4 MB
  int* pfx            = (int*)take((size_t)NSH*NN*sizeof(int));                    // 3.2 MB
  int* row_excl       = (int*)take((size_t)NN*sizeof(int));
  int* part           = (int*)take(1024);
  int* rank           = (int*)take((size_t)NE*sizeof(int));                        // 4 MB
  int2* sedge         = (int2*)take((size_t)NE*sizeof(int2));                      // 8 MB
  unsigned short* wpz = (unsigned short*)take((size_t)77824*sizeof(unsigned short));
  size_t need = (size_t)(wp_ - (char*)d_ws);

  // preswizzled-weight offsets (ushort elements)
  const size_t UW1 = 0, UW2 = 24576, PPJ = 36864, OW1 = 61440, MW2 = 65536;

  if (ws_size >= need) {
    // single upfront zero: counts8 (3.2MB) + aggh3 (38.4MB), contiguous
    (void)hipMemsetAsync(counts8, 0,
        (size_t)NSH*NN*sizeof(int) + (size_t)3*NN*H*sizeof(unsigned short), stream);

    enc_full_kernel<<<nodeBlocks, 256, 0, stream>>>(x, enc_w1, enc_b1, enc_w2, enc_b2, hbf);

    rank_kernel<<<rankBlocks, 256, 0, stream>>>(dstp, counts8, rank);
    scan1_kernel<<<scanBlocks, 1024, 0, stream>>>(counts8, counts, pfx, row_excl, part);
    scan2_kernel<<<1, 128, 0, stream>>>(part, scanBlocks);
    fill_kernel<<<edgeBlocks, 256, 0, stream>>>(srcp, dstp, row_excl, part, pfx, rank, sedge);
    prep_all_kernel<<<(77824 + 255)/256, 256, 0, stream>>>(upd_w1, upd_w2, msg_w1, msg_w2, out_w1, wpz);

    // layer-0 P projection (mode 2)
    node_fused_kernel<<<fusedBlocks, 64, 0, stream>>>(
        hbf, aggh3, counts,
        nullptr, nullptr, nullptr, nullptr,
        wpz + PPJ, msg_b1, nullptr, nullptr,
        nullptr, P, nullptr, 2);

    for (int l=0; l<3; l++){
      unsigned short* agghl = aggh3 + (size_t)l*NN*H;   // per-layer pre-zeroed buffer
      msg_mfma_kernel<<<msgBlocks, MBT, 0, stream>>>(P, wpz + MW2 + (size_t)l*4096,
          msg_b2 + (size_t)l*H, sedge, agghl);
      if (l < 2){
        node_fused_kernel<<<fusedBlocks, 64, 0, stream>>>(
            hbf, agghl, counts,
            wpz + UW1 + (size_t)l*8192, upd_b1 + (size_t)l*H,
            wpz + UW2 + (size_t)l*4096, upd_b2 + (size_t)l*H,
            wpz + PPJ + (size_t)(l+1)*8192, msg_b1 + (size_t)(l+1)*H,
            nullptr, nullptr,
            hbf, P, nullptr, 0);
      } else {
        node_fused_kernel<<<fusedBlocks, 64, 0, stream>>>(
            hbf, agghl, counts,
            wpz + UW1 + (size_t)l*8192, upd_b1 + (size_t)l*H,
            wpz + UW2 + (size_t)l*4096, upd_b2 + (size_t)l*H,
            wpz + OW1, out_b1,
            out_w2, out_b2,
            nullptr, nullptr, out, 1);
      }
    }
  } else {
    // ======== fallback: legacy atomic path (fits in ~52 MB) ========
    char* fp = (char*)d_ws;
    float* fh   = (float*)fp;  fp += (size_t)NN*H*sizeof(float);
    float* fagg = (float*)fp;  fp += (size_t)NN*H*sizeof(float);
    int* fcnt   = (int*)fp;

    (void)hipMemsetAsync(fcnt, 0, NN*sizeof(int), stream);
    enc_kernel_legacy<<<nodeBlocks, 256, 0, stream>>>(x, enc_w1, enc_b1, enc_w2, enc_b2, fh);
    count_kernel<<<edgeBlocks, 256, 0, stream>>>(dstp, fcnt);
    for (int l=0; l<3; l++){
      (void)hipMemsetAsync(fagg, 0, (size_t)NN*H*sizeof(float), stream);
      msg_kernel_atomic<<<edgeBlocks, 256, 0, stream>>>(fh, srcp, dstp,
          msg_w1 + (size_t)l*128*H, msg_b1 + (size_t)l*H,
          msg_w2 + (size_t)l*H*H,   msg_b2 + (size_t)l*H, fagg);
      div_kernel<<<(NN*H/4 + 255)/256, 256, 0, stream>>>(fagg, fcnt);
      upd_kernel_legacy<<<nodeBlocks, 256, 0, stream>>>(fh, fagg,
          upd_w1 + (size_t)l*128*H, upd_b1 + (size_t)l*H,
          upd_w2 + (size_t)l*H*H,   upd_b2 + (size_t)l*H);
    }
    out_kernel2<<<nodeBlocks, 256, 0, stream>>>(fh, out_w1, out_b1, out_w2, out_b2, out);
  }
}